// Round 1
// baseline (1580.531 us; speedup 1.0000x reference)
//
#include <hip/hip_runtime.h>
#include <hip/hip_bf16.h>

// Problem constants
#define Bb 4
#define Ss 2048
#define DIMc 128
#define Hh 8
#define DHc 128
#define Mf 128
#define CH 128
#define NCc 16         // S / CHUNK
#define INNERc 1024    // H*DH
#define FFc 512
#define NROW 8192      // B*S
#define NFR 65536      // B*S*H feature rows

union F4 { float4 v; float f[4]; };

__device__ __forceinline__ unsigned fkey(float f){
  unsigned b = __float_as_uint(f);
  return (b & 0x80000000u) ? ~b : (b | 0x80000000u);
}
__device__ __forceinline__ float funkey(unsigned u){
  unsigned b = (u & 0x80000000u) ? (u & 0x7fffffffu) : ~u;
  return __uint_as_float(b);
}
__device__ __forceinline__ float gelu_f(float x){
  return 0.5f*x*(1.0f + tanhf(0.7978845608028654f*(x + 0.044715f*x*x*x)));
}

// ---------------- init (zero the kstab atomic-max slots) ----------------
__global__ __launch_bounds__(64) void k_init(unsigned* kstab){
  if(threadIdx.x < 64) kstab[threadIdx.x] = 0u;   // DEPTH*B*H = 64
}

// ---------------- embedding: h = x*lin_w + lin_b + pe ----------------
__global__ __launch_bounds__(256) void k_embed(const float* __restrict__ x,
    const float* __restrict__ lw, const float* __restrict__ lb,
    const float* __restrict__ pe, float* __restrict__ h){
  int idx = blockIdx.x*256 + threadIdx.x;   // over B*S*DIM = 1,048,576
  int d = idx & 127; int bs = idx >> 7; int s = bs & (Ss-1);
  h[idx] = x[bs]*lw[d] + lb[d] + pe[s*DIMc + d];
}

// ---------------- layernorm (one wave per row of 128) ----------------
__global__ __launch_bounds__(256) void k_ln(const float* __restrict__ in,
    const float* __restrict__ g, const float* __restrict__ bta,
    float* __restrict__ out){
  int wave = threadIdx.x >> 6; int lane = threadIdx.x & 63;
  int row = blockIdx.x*4 + wave;
  const float* r = in + row*DIMc;
  float x1 = r[lane], x2 = r[lane+64];
  float s = x1+x2, sq = x1*x1 + x2*x2;
  #pragma unroll
  for(int m=1;m<64;m<<=1){ s += __shfl_xor(s,m,64); sq += __shfl_xor(sq,m,64); }
  float mu = s * (1.0f/128.0f);
  float var = sq*(1.0f/128.0f) - mu*mu;
  float rs = rsqrtf(var + 1e-5f);
  out[row*DIMc+lane]    = (x1-mu)*rs*g[lane]+bta[lane];
  out[row*DIMc+lane+64] = (x2-mu)*rs*g[lane+64]+bta[lane+64];
}

// ---------------- generic fp32 GEMM: C = [resid +] act(A@B + bias) -------------
// 64x64 tile, 256 threads, 4x4 micro-tile, BK=32
template<bool BIAS, bool GELU, bool RES>
__global__ __launch_bounds__(256) void k_gemm(const float* __restrict__ A,
    const float* __restrict__ Bw, const float* __restrict__ bias,
    const float* __restrict__ resid, float* __restrict__ C, int N, int K){
  __shared__ float As[32][68];   // [k][m] padded (68 floats = 17 float4, 16B aligned)
  __shared__ float Bs[32][68];   // [k][n]
  int m0 = blockIdx.y*64, n0 = blockIdx.x*64;
  int t = threadIdx.x; int ti = t>>4, tj = t&15;
  float acc[4][4] = {};
  for(int k0=0;k0<K;k0+=32){
    { // stage A tile (64 rows x 32 cols), transposed into As[k][m]
      int dc4 = t & 7, r = t >> 3;  // r 0..31
      #pragma unroll
      for(int it=0; it<2; ++it){
        int rr = r + it*32;
        F4 va; va.v = *(const float4*)(A + (m0+rr)*K + k0 + dc4*4);
        As[dc4*4+0][rr] = va.f[0]; As[dc4*4+1][rr] = va.f[1];
        As[dc4*4+2][rr] = va.f[2]; As[dc4*4+3][rr] = va.f[3];
      }
      int nc4 = t & 15, kr = t >> 4; // kr 0..15
      #pragma unroll
      for(int it=0; it<2; ++it){
        int kk = kr + it*16;
        *(float4*)&Bs[kk][nc4*4] = *(const float4*)(Bw + (k0+kk)*N + n0 + nc4*4);
      }
    }
    __syncthreads();
    #pragma unroll
    for(int kk=0; kk<32; ++kk){
      F4 a4; a4.v = *(const float4*)&As[kk][ti*4];
      F4 b4; b4.v = *(const float4*)&Bs[kk][tj*4];
      #pragma unroll
      for(int i=0;i<4;i++){
        #pragma unroll
        for(int j=0;j<4;j++) acc[i][j] += a4.f[i]*b4.f[j];
      }
    }
    __syncthreads();
  }
  #pragma unroll
  for(int i=0;i<4;i++){
    int row = m0 + ti*4 + i;
    #pragma unroll
    for(int j=0;j<4;j++){
      int col = n0 + tj*4 + j;
      float val = acc[i][j];
      if(BIAS) val += bias[col];
      if(GELU) val = gelu_f(val);
      if(RES)  val += resid[row*N+col];
      C[row*N+col] = val;
    }
  }
}

// ------------- FAVOR+ query features (in place over q) --------------------
// 64 rows/block; dd = (q*norm)@proj^T; out = ratio*(exp(dd - diag - rowmax)+eps)
__global__ __launch_bounds__(256) void k_qfeat(float* __restrict__ q,
    const float* __restrict__ proj){
  __shared__ float x_s[64][36];
  __shared__ float p_s[32][132];
  __shared__ float diag_s[64];
  int r0 = blockIdx.x*64;
  int t = threadIdx.x; int ti = t>>4, tj = t&15;
  const float norm  = 0.29730177875068026f;   // 128^-0.25
  const float ratio = 0.08838834764831845f;   // 128^-0.5
  { // diag pre-pass: 4 threads per row
    int r = t>>2, qt = t&3;
    const float* rp = q + (r0+r)*128 + qt*32;
    float ss = 0.f;
    #pragma unroll
    for(int u=0;u<32;u+=4){ F4 v4; v4.v = *(const float4*)(rp+u);
      ss += v4.f[0]*v4.f[0]+v4.f[1]*v4.f[1]+v4.f[2]*v4.f[2]+v4.f[3]*v4.f[3]; }
    ss *= norm*norm;
    ss += __shfl_xor(ss,1,64); ss += __shfl_xor(ss,2,64);
    if(qt==0) diag_s[r] = 0.5f*ss;
  }
  float dd[4][8] = {};
  for(int ds=0; ds<4; ++ds){
    #pragma unroll
    for(int it=0; it<2; ++it){  // stage 64x32 q slice, scaled
      int idx = t + it*256; int r = idx>>3, dc4 = idx&7;
      F4 v4; v4.v = *(const float4*)(q + (r0+r)*128 + ds*32 + dc4*4);
      v4.f[0]*=norm; v4.f[1]*=norm; v4.f[2]*=norm; v4.f[3]*=norm;
      *(float4*)&x_s[r][dc4*4] = v4.v;
    }
    #pragma unroll
    for(int it=0; it<4; ++it){  // stage proj^T slice p_s[d][m]
      int idx = t + it*256; int m = idx>>3, dc4 = idx&7;
      F4 v4; v4.v = *(const float4*)(proj + m*128 + ds*32 + dc4*4);
      p_s[dc4*4+0][m]=v4.f[0]; p_s[dc4*4+1][m]=v4.f[1];
      p_s[dc4*4+2][m]=v4.f[2]; p_s[dc4*4+3][m]=v4.f[3];
    }
    __syncthreads();
    #pragma unroll
    for(int d4=0;d4<8;d4++){
      F4 a[4];
      #pragma unroll
      for(int r=0;r<4;r++) a[r].v = *(const float4*)&x_s[ti*4+r][d4*4];
      #pragma unroll
      for(int dj=0;dj<4;dj++){
        F4 p0,p1;
        p0.v = *(const float4*)&p_s[d4*4+dj][tj*8];
        p1.v = *(const float4*)&p_s[d4*4+dj][tj*8+4];
        #pragma unroll
        for(int r=0;r<4;r++){
          float av = a[r].f[dj];
          dd[r][0]+=av*p0.f[0]; dd[r][1]+=av*p0.f[1]; dd[r][2]+=av*p0.f[2]; dd[r][3]+=av*p0.f[3];
          dd[r][4]+=av*p1.f[0]; dd[r][5]+=av*p1.f[1]; dd[r][6]+=av*p1.f[2]; dd[r][7]+=av*p1.f[3];
        }
      }
    }
    __syncthreads();
  }
  #pragma unroll
  for(int r=0;r<4;r++){
    float m8 = dd[r][0];
    #pragma unroll
    for(int mm=1;mm<8;mm++) m8 = fmaxf(m8, dd[r][mm]);
    #pragma unroll
    for(int msk=1;msk<16;msk<<=1) m8 = fmaxf(m8, __shfl_xor(m8, msk, 64));
    float dg = diag_s[ti*4+r];
    int row = r0 + ti*4 + r;
    float o_[8];
    #pragma unroll
    for(int mm=0;mm<8;mm++) o_[mm] = ratio*(expf(dd[r][mm]-dg-m8) + 1e-4f);
    *(float4*)(q + row*128 + tj*8)   = make_float4(o_[0],o_[1],o_[2],o_[3]);
    *(float4*)(q + row*128 + tj*8+4) = make_float4(o_[4],o_[5],o_[6],o_[7]);
  }
}

// ------------- FAVOR+ key features pass A: t = dd - diag, track max(dd) ----
__global__ __launch_bounds__(256) void k_kfeatA(float* __restrict__ k,
    const float* __restrict__ proj, unsigned* __restrict__ kstab){
  __shared__ float x_s[64][36];
  __shared__ float p_s[32][132];
  __shared__ float diag_s[64];
  __shared__ unsigned hmax[8];
  int r0 = blockIdx.x*64;
  int t = threadIdx.x; int ti = t>>4, tj = t&15;
  const float norm = 0.29730177875068026f;
  if(t<8) hmax[t] = 0u;
  {
    int r = t>>2, qt = t&3;
    const float* rp = k + (r0+r)*128 + qt*32;
    float ss = 0.f;
    #pragma unroll
    for(int u=0;u<32;u+=4){ F4 v4; v4.v = *(const float4*)(rp+u);
      ss += v4.f[0]*v4.f[0]+v4.f[1]*v4.f[1]+v4.f[2]*v4.f[2]+v4.f[3]*v4.f[3]; }
    ss *= norm*norm;
    ss += __shfl_xor(ss,1,64); ss += __shfl_xor(ss,2,64);
    if(qt==0) diag_s[r] = 0.5f*ss;
  }
  float dd[4][8] = {};
  for(int ds=0; ds<4; ++ds){
    #pragma unroll
    for(int it=0; it<2; ++it){
      int idx = t + it*256; int r = idx>>3, dc4 = idx&7;
      F4 v4; v4.v = *(const float4*)(k + (r0+r)*128 + ds*32 + dc4*4);
      v4.f[0]*=norm; v4.f[1]*=norm; v4.f[2]*=norm; v4.f[3]*=norm;
      *(float4*)&x_s[r][dc4*4] = v4.v;
    }
    #pragma unroll
    for(int it=0; it<4; ++it){
      int idx = t + it*256; int m = idx>>3, dc4 = idx&7;
      F4 v4; v4.v = *(const float4*)(proj + m*128 + ds*32 + dc4*4);
      p_s[dc4*4+0][m]=v4.f[0]; p_s[dc4*4+1][m]=v4.f[1];
      p_s[dc4*4+2][m]=v4.f[2]; p_s[dc4*4+3][m]=v4.f[3];
    }
    __syncthreads();
    #pragma unroll
    for(int d4=0;d4<8;d4++){
      F4 a[4];
      #pragma unroll
      for(int r=0;r<4;r++) a[r].v = *(const float4*)&x_s[ti*4+r][d4*4];
      #pragma unroll
      for(int dj=0;dj<4;dj++){
        F4 p0,p1;
        p0.v = *(const float4*)&p_s[d4*4+dj][tj*8];
        p1.v = *(const float4*)&p_s[d4*4+dj][tj*8+4];
        #pragma unroll
        for(int r=0;r<4;r++){
          float av = a[r].f[dj];
          dd[r][0]+=av*p0.f[0]; dd[r][1]+=av*p0.f[1]; dd[r][2]+=av*p0.f[2]; dd[r][3]+=av*p0.f[3];
          dd[r][4]+=av*p1.f[0]; dd[r][5]+=av*p1.f[1]; dd[r][6]+=av*p1.f[2]; dd[r][7]+=av*p1.f[3];
        }
      }
    }
    __syncthreads();
  }
  #pragma unroll
  for(int r=0;r<4;r++){
    float m8 = dd[r][0];
    #pragma unroll
    for(int mm=1;mm<8;mm++) m8 = fmaxf(m8, dd[r][mm]);
    #pragma unroll
    for(int msk=1;msk<16;msk<<=1) m8 = fmaxf(m8, __shfl_xor(m8, msk, 64));
    int row = r0 + ti*4 + r;
    if(tj==0) atomicMax(&hmax[row & 7], fkey(m8));
    float dg = diag_s[ti*4+r];
    float o_[8];
    #pragma unroll
    for(int mm=0;mm<8;mm++) o_[mm] = dd[r][mm]-dg;
    *(float4*)(k + row*128 + tj*8)   = make_float4(o_[0],o_[1],o_[2],o_[3]);
    *(float4*)(k + row*128 + tj*8+4) = make_float4(o_[4],o_[5],o_[6],o_[7]);
  }
  __syncthreads();
  int b = r0 >> 14;  // row / (S*H)
  if(t<8) atomicMax(&kstab[b*8 + t], hmax[t]);
}

// ------------- key features pass B: kp = ratio*(exp(t - stab)+eps) --------
__global__ __launch_bounds__(256) void k_kfeatB(float* __restrict__ k,
    const unsigned* __restrict__ kstab){
  const float ratio = 0.08838834764831845f;
  int idx4 = blockIdx.x*256 + threadIdx.x;   // f4 index, grid 8192
  int e = idx4*4;
  int row = e >> 7; int bh = ((row>>14)<<3) | (row & 7);
  float stab = funkey(kstab[bh]);
  F4 v4; v4.v = *(float4*)(k+e);
  #pragma unroll
  for(int u=0;u<4;u++) v4.f[u] = ratio*(expf(v4.f[u] - stab)+1e-4f);
  *(float4*)(k+e) = v4.v;
}

// ------------- attention phase 1: per-chunk kv = k^T v, ksum = sum k ------
__global__ __launch_bounds__(256) void k_attn1(const float* __restrict__ kp,
    const float* __restrict__ v, float* __restrict__ kvc, float* __restrict__ ksc){
  __shared__ float kp_s[32][132];
  __shared__ float v_s[32][132];
  int bc = blockIdx.x; int c = bc & 15; int bh = bc >> 4; int b = bh >> 3; int hh = bh & 7;
  int t = threadIdx.x; int tm = t>>4, td = t&15;
  float acc[8][8] = {};
  float ks = 0.f;
  for(int js=0; js<4; ++js){
    #pragma unroll
    for(int it=0; it<4; ++it){
      int idx = t + it*256; int jj = idx>>5, mc4 = idx&31;
      int s = c*128 + js*32 + jj;
      int base = ((b*Ss + s)*Hh + hh)*128;
      *(float4*)&kp_s[jj][mc4*4] = *(const float4*)(kp + base + mc4*4);
      *(float4*)&v_s[jj][mc4*4]  = *(const float4*)(v  + base + mc4*4);
    }
    __syncthreads();
    #pragma unroll 4
    for(int jj=0; jj<32; ++jj){
      F4 a0,a1,b0,b1;
      a0.v = *(const float4*)&kp_s[jj][tm*8];  a1.v = *(const float4*)&kp_s[jj][tm*8+4];
      b0.v = *(const float4*)&v_s[jj][td*8];   b1.v = *(const float4*)&v_s[jj][td*8+4];
      float av[8]={a0.f[0],a0.f[1],a0.f[2],a0.f[3],a1.f[0],a1.f[1],a1.f[2],a1.f[3]};
      float bv[8]={b0.f[0],b0.f[1],b0.f[2],b0.f[3],b1.f[0],b1.f[1],b1.f[2],b1.f[3]};
      #pragma unroll
      for(int i=0;i<8;i++){
        #pragma unroll
        for(int j=0;j<8;j++) acc[i][j] += av[i]*bv[j];
      }
    }
    if(t<128){
      #pragma unroll 8
      for(int jj=0;jj<32;++jj) ks += kp_s[jj][t];
    }
    __syncthreads();
  }
  int obase = bc*16384;
  #pragma unroll
  for(int r=0;r<8;r++){
    *(float4*)(kvc + obase + (tm*8+r)*128 + td*8)   = make_float4(acc[r][0],acc[r][1],acc[r][2],acc[r][3]);
    *(float4*)(kvc + obase + (tm*8+r)*128 + td*8+4) = make_float4(acc[r][4],acc[r][5],acc[r][6],acc[r][7]);
  }
  if(t<128) ksc[bc*128 + t] = ks;
}

// ------------- phase 1.5: in-place exclusive prefix over chunks ----------
__global__ __launch_bounds__(256) void k_prefix(float* __restrict__ kvc,
    float* __restrict__ ksc){
  int bh = blockIdx.x; int t = threadIdx.x;
  float acc[64];
  #pragma unroll
  for(int i=0;i<64;i++) acc[i]=0.f;
  for(int c=0;c<16;c++){
    int base = (bh*16+c)*16384;
    #pragma unroll
    for(int i=0;i<64;i++){
      int a = base + t + i*256;
      float xv = kvc[a]; kvc[a] = acc[i]; acc[i] += xv;
    }
  }
  if(t<128){
    float a2 = 0.f;
    for(int c=0;c<16;c++){ int a = (bh*16+c)*128 + t; float xv = ksc[a]; ksc[a]=a2; a2+=xv; }
  }
}

// ------------- attention phase 2: per-chunk output -----------------------
__global__ __launch_bounds__(256) void k_attn2(const float* __restrict__ qp,
    const float* __restrict__ kp, const float* __restrict__ v,
    const float* __restrict__ kvc, const float* __restrict__ ksc,
    float* __restrict__ o){
  __shared__ float qp_s[128][36];
  __shared__ float kp_s[32][36];
  __shared__ float sv_s[32][132];
  __shared__ float attn_s[128][36];
  __shared__ float den_s[128];
  __shared__ float ksum_s[128];
  int bc = blockIdx.x; int c = bc&15, bh = bc>>4, b = bh>>3, hh = bh&7;
  int t = threadIdx.x; int ti = t>>4, tj = t&15;
  if(t<128){ den_s[t]=0.f; ksum_s[t] = ksc[bc*128+t]; }
  float acc[8][8] = {};
  int s0 = c*128;
  for(int js=0; js<4; ++js){
    float ar[8][2] = {};
    for(int ms=0; ms<4; ++ms){
      #pragma unroll
      for(int it=0; it<4; ++it){   // stage qp_s[128][32]
        int idx = t + it*256; int r = idx>>3, mc4 = idx&7;
        *(float4*)&qp_s[r][mc4*4] =
          *(const float4*)(qp + ((b*Ss+s0+r)*Hh+hh)*128 + ms*32 + mc4*4);
      }
      {                            // stage kp_s[32][32]
        int r = t>>3, mc4 = t&7;
        *(float4*)&kp_s[r][mc4*4] =
          *(const float4*)(kp + ((b*Ss+s0+js*32+r)*Hh+hh)*128 + ms*32 + mc4*4);
      }
      __syncthreads();
      #pragma unroll
      for(int m4=0;m4<8;m4++){
        F4 b0,b1;
        b0.v = *(const float4*)&kp_s[tj*2+0][m4*4];
        b1.v = *(const float4*)&kp_s[tj*2+1][m4*4];
        #pragma unroll
        for(int r=0;r<8;r++){
          F4 a; a.v = *(const float4*)&qp_s[ti*8+r][m4*4];
          #pragma unroll
          for(int u=0;u<4;u++){
            ar[r][0] += a.f[u]*b0.f[u];
            ar[r][1] += a.f[u]*b1.f[u];
          }
        }
      }
      __syncthreads();
    }
    // mask + den partial + store attn slice
    #pragma unroll
    for(int r=0;r<8;r++){
      int i = ti*8+r;
      int j0 = js*32 + tj*2;
      float p0 = (j0   > i) ? 0.f : ar[r][0];
      float p1 = (j0+1 > i) ? 0.f : ar[r][1];
      attn_s[i][tj*2+0] = p0;
      attn_s[i][tj*2+1] = p1;
      float ps = p0+p1;
      #pragma unroll
      for(int msk=1;msk<16;msk<<=1) ps += __shfl_xor(ps,msk,64);
      if(tj==0) den_s[i] += ps;
    }
    #pragma unroll
    for(int it=0; it<4; ++it){   // stage v slice [32][128]
      int idx = t+it*256; int jj = idx>>5, mc4 = idx&31;
      *(float4*)&sv_s[jj][mc4*4] =
        *(const float4*)(v + ((b*Ss+s0+js*32+jj)*Hh+hh)*128 + mc4*4);
    }
    __syncthreads();
    // PV for this j-slice
    #pragma unroll
    for(int j4=0;j4<8;j4++){
      F4 a[8];
      #pragma unroll
      for(int r=0;r<8;r++) a[r].v = *(const float4*)&attn_s[ti*8+r][j4*4];
      #pragma unroll
      for(int jj=0;jj<4;jj++){
        F4 v0,v1;
        v0.v = *(const float4*)&sv_s[j4*4+jj][tj*8];
        v1.v = *(const float4*)&sv_s[j4*4+jj][tj*8+4];
        #pragma unroll
        for(int r=0;r<8;r++){
          float av = a[r].f[jj];
          acc[r][0]+=av*v0.f[0]; acc[r][1]+=av*v0.f[1]; acc[r][2]+=av*v0.f[2]; acc[r][3]+=av*v0.f[3];
          acc[r][4]+=av*v1.f[0]; acc[r][5]+=av*v1.f[1]; acc[r][6]+=av*v1.f[2]; acc[r][7]+=av*v1.f[3];
        }
      }
    }
    __syncthreads();
  }
  // qp @ kv_excl term
  for(int ms=0; ms<4; ++ms){
    #pragma unroll
    for(int it=0; it<4; ++it){
      int idx = t + it*256; int r = idx>>3, mc4 = idx&7;
      *(float4*)&qp_s[r][mc4*4] =
        *(const float4*)(qp + ((b*Ss+s0+r)*Hh+hh)*128 + ms*32 + mc4*4);
    }
    #pragma unroll
    for(int it=0; it<4; ++it){
      int idx = t+it*256; int mm = idx>>5, dc4 = idx&31;
      *(float4*)&sv_s[mm][dc4*4] =
        *(const float4*)(kvc + bc*16384 + (ms*32+mm)*128 + dc4*4);
    }
    __syncthreads();
    #pragma unroll
    for(int m4=0;m4<8;m4++){
      F4 a[8];
      #pragma unroll
      for(int r=0;r<8;r++) a[r].v = *(const float4*)&qp_s[ti*8+r][m4*4];
      #pragma unroll
      for(int mm=0;mm<4;mm++){
        F4 v0,v1;
        v0.v = *(const float4*)&sv_s[m4*4+mm][tj*8];
        v1.v = *(const float4*)&sv_s[m4*4+mm][tj*8+4];
        #pragma unroll
        for(int r=0;r<8;r++){
          float av = a[r].f[mm];
          acc[r][0]+=av*v0.f[0]; acc[r][1]+=av*v0.f[1]; acc[r][2]+=av*v0.f[2]; acc[r][3]+=av*v0.f[3];
          acc[r][4]+=av*v1.f[0]; acc[r][5]+=av*v1.f[1]; acc[r][6]+=av*v1.f[2]; acc[r][7]+=av*v1.f[3];
        }
      }
    }
    __syncthreads();
  }
  // den: + qp . ksum_excl
  if(t<128){
    int i = t;
    const float* qrow = qp + ((b*Ss+s0+i)*Hh+hh)*128;
    float d2 = 0.f;
    #pragma unroll 8
    for(int m=0;m<128;m+=4){
      F4 a; a.v = *(const float4*)(qrow+m);
      d2 += a.f[0]*ksum_s[m]+a.f[1]*ksum_s[m+1]+a.f[2]*ksum_s[m+2]+a.f[3]*ksum_s[m+3];
    }
    den_s[i] += d2;
  }
  __syncthreads();
  #pragma unroll
  for(int r=0;r<8;r++){
    int i = ti*8+r;
    float inv = 1.0f/(den_s[i]+1e-6f);
    int base = ((b*Ss+s0+i)*Hh+hh)*128 + tj*8;
    *(float4*)(o+base)   = make_float4(acc[r][0]*inv, acc[r][1]*inv, acc[r][2]*inv, acc[r][3]*inv);
    *(float4*)(o+base+4) = make_float4(acc[r][4]*inv, acc[r][5]*inv, acc[r][6]*inv, acc[r][7]*inv);
  }
}

// ------------- final: mean-pool over S + classifier ----------------------
__global__ __launch_bounds__(256) void k_final(const float* __restrict__ h,
    const float* __restrict__ fw, const float* __restrict__ fb,
    float* __restrict__ out){
  __shared__ float part[256];
  __shared__ float pool_s[128];
  int b = blockIdx.x; int t = threadIdx.x;
  int d = t&127, half = t>>7;
  float s = 0.f;
  for(int si = half*1024; si < half*1024+1024; ++si) s += h[(b*Ss+si)*128 + d];
  part[t] = s;
  __syncthreads();
  if(t<128) pool_s[t] = (part[t]+part[t+128]) * (1.0f/2048.0f);
  __syncthreads();
  if(t<10){
    float a = fb[t];
    for(int dd=0; dd<128; ++dd) a += pool_s[dd]*fw[dd*10+t];
    out[b*10+t] = a;
  }
}

extern "C" void kernel_launch(void* const* d_in, const int* in_sizes, int n_in,
                              void* d_out, int out_size, void* d_ws, size_t ws_size,
                              hipStream_t stream){
  (void)in_sizes; (void)n_in; (void)out_size; (void)ws_size;
  const float* x     = (const float*)d_in[0];
  const float* lin_w = (const float*)d_in[1];
  const float* lin_b = (const float*)d_in[2];
  const float* pe    = (const float*)d_in[3];
  const float* proj  = (const float*)d_in[4];
  const float* ln1_g = (const float*)d_in[5];
  const float* ln1_b = (const float*)d_in[6];
  const float* wq    = (const float*)d_in[7];
  const float* wk    = (const float*)d_in[8];
  const float* wv    = (const float*)d_in[9];
  const float* wo    = (const float*)d_in[10];
  const float* wo_b  = (const float*)d_in[11];
  const float* ln2_g = (const float*)d_in[12];
  const float* ln2_b = (const float*)d_in[13];
  const float* ff1w  = (const float*)d_in[14];
  const float* ff1b  = (const float*)d_in[15];
  const float* ff2w  = (const float*)d_in[16];
  const float* ff2b  = (const float*)d_in[17];
  const float* finw  = (const float*)d_in[18];
  const float* finb  = (const float*)d_in[19];
  float* out = (float*)d_out;

  // workspace layout (floats); total ~176 MB
  float* ws  = (float*)d_ws;
  float* h   = ws;              // [8192][128]
  float* y   = h  + 1048576;    // [8192][128]
  float* q   = y  + 1048576;    // [8192][1024]  (also reused as FF intermediate)
  float* k   = q  + 8388608;
  float* v   = k  + 8388608;
  float* o   = v  + 8388608;
  float* kvc = o  + 8388608;    // [32][16][128][128]
  float* ksc = kvc + 8388608;   // [32][16][128]
  unsigned* kstab = (unsigned*)(ksc + 65536);  // [DEPTH][32]

  k_init<<<1,64,0,stream>>>(kstab);
  k_embed<<<4096,256,0,stream>>>(x, lin_w, lin_b, pe, h);
  for(int l=0;l<2;l++){
    const float* projl = proj + l*Mf*DHc;
    k_ln<<<2048,256,0,stream>>>(h, ln1_g + l*DIMc, ln1_b + l*DIMc, y);
    k_gemm<false,false,false><<<dim3(16,128),256,0,stream>>>(y, wq + l*DIMc*INNERc, nullptr, nullptr, q, INNERc, DIMc);
    k_gemm<false,false,false><<<dim3(16,128),256,0,stream>>>(y, wk + l*DIMc*INNERc, nullptr, nullptr, k, INNERc, DIMc);
    k_gemm<false,false,false><<<dim3(16,128),256,0,stream>>>(y, wv + l*DIMc*INNERc, nullptr, nullptr, v, INNERc, DIMc);
    k_qfeat<<<1024,256,0,stream>>>(q, projl);
    k_kfeatA<<<1024,256,0,stream>>>(k, projl, kstab + l*32);
    k_kfeatB<<<8192,256,0,stream>>>(k, kstab + l*32);
    k_attn1<<<512,256,0,stream>>>(k, v, kvc, ksc);
    k_prefix<<<32,256,0,stream>>>(kvc, ksc);
    k_attn2<<<512,256,0,stream>>>(q, k, v, kvc, ksc, o);
    k_gemm<true,false,true><<<dim3(2,128),256,0,stream>>>(o, wo + l*INNERc*DIMc, wo_b + l*DIMc, h, h, DIMc, INNERc);
    k_ln<<<2048,256,0,stream>>>(h, ln2_g + l*DIMc, ln2_b + l*DIMc, y);
    k_gemm<true,true,false><<<dim3(8,128),256,0,stream>>>(y, ff1w + l*DIMc*FFc, ff1b + l*FFc, nullptr, q, FFc, DIMc);
    k_gemm<true,false,true><<<dim3(2,128),256,0,stream>>>(q, ff2w + l*FFc*DIMc, ff2b + l*DIMc, h, h, DIMc, FFc);
  }
  k_final<<<4,256,0,stream>>>(h, finw, finb, out);
}

// Round 2
// 1018.551 us; speedup vs baseline: 1.5517x; 1.5517x over previous
//
#include <hip/hip_runtime.h>
#include <hip/hip_bf16.h>

// Problem constants
#define Bb 4
#define Ss 2048
#define DIMc 128
#define Hh 8
#define DHc 128
#define Mf 128
#define CH 128
#define NCc 16         // S / CHUNK
#define INNERc 1024    // H*DH
#define FFc 512

union F4 { float4 v; float f[4]; };

typedef __bf16 bf16x8 __attribute__((ext_vector_type(8)));
typedef float  f32x4  __attribute__((ext_vector_type(4)));

__device__ __forceinline__ unsigned fkey(float f){
  unsigned b = __float_as_uint(f);
  return (b & 0x80000000u) ? ~b : (b | 0x80000000u);
}
__device__ __forceinline__ float funkey(unsigned u){
  unsigned b = (u & 0x80000000u) ? (u & 0x7fffffffu) : ~u;
  return __uint_as_float(b);
}
__device__ __forceinline__ float gelu_f(float x){
  return 0.5f*x*(1.0f + tanhf(0.7978845608028654f*(x + 0.044715f*x*x*x)));
}
// f32 -> bf16 (RNE) as raw ushort
__device__ __forceinline__ unsigned short f2bu(float f){
  unsigned u = __float_as_uint(f);
  return (unsigned short)((u + 0x7fffu + ((u>>16)&1u)) >> 16);
}

// ---------------- init (zero the kstab atomic-max slots) ----------------
__global__ __launch_bounds__(64) void k_init(unsigned* kstab){
  if(threadIdx.x < 64) kstab[threadIdx.x] = 0u;   // DEPTH*B*H = 64
}

// ---------------- embedding: h = x*lin_w + lin_b + pe ----------------
__global__ __launch_bounds__(256) void k_embed(const float* __restrict__ x,
    const float* __restrict__ lw, const float* __restrict__ lb,
    const float* __restrict__ pe, float* __restrict__ h){
  int idx = blockIdx.x*256 + threadIdx.x;   // over B*S*DIM = 1,048,576
  int d = idx & 127; int bs = idx >> 7; int s = bs & (Ss-1);
  h[idx] = x[bs]*lw[d] + lb[d] + pe[s*DIMc + d];
}

// ---------------- layernorm (one wave per row of 128) ----------------
__global__ __launch_bounds__(256) void k_ln(const float* __restrict__ in,
    const float* __restrict__ g, const float* __restrict__ bta,
    float* __restrict__ out){
  int wave = threadIdx.x >> 6; int lane = threadIdx.x & 63;
  int row = blockIdx.x*4 + wave;
  const float* r = in + row*DIMc;
  float x1 = r[lane], x2 = r[lane+64];
  float s = x1+x2, sq = x1*x1 + x2*x2;
  #pragma unroll
  for(int m=1;m<64;m<<=1){ s += __shfl_xor(s,m,64); sq += __shfl_xor(sq,m,64); }
  float mu = s * (1.0f/128.0f);
  float var = sq*(1.0f/128.0f) - mu*mu;
  float rs = rsqrtf(var + 1e-5f);
  out[row*DIMc+lane]    = (x1-mu)*rs*g[lane]+bta[lane];
  out[row*DIMc+lane+64] = (x2-mu)*rs*g[lane+64]+bta[lane+64];
}

// ---------------- bf16 MFMA GEMM: C = [resid +] act(A@B + bias) ----------
// 64x64 tile, 256 threads = 4 waves (2x2), each wave 32x32 via 2x2 16x16x32 frags
template<bool BIAS, bool GELU, bool RES>
__global__ __launch_bounds__(256) void k_gemm_mfma(const float* __restrict__ A,
    const float* __restrict__ Bw, const float* __restrict__ bias,
    const float* __restrict__ resid, float* __restrict__ C, int N, int K){
  __shared__ unsigned short As[64][40];  // [m][k], 80B padded rows (2-way max)
  __shared__ unsigned short Bs[64][40];  // [n][k]
  int m0 = blockIdx.y*64, n0 = blockIdx.x*64;
  int t = threadIdx.x; int wid = t>>6, lane = t&63;
  int wr = wid>>1, wc = wid&1;           // wave quadrant
  int fr = lane&15, kc = lane>>4;        // frag row/col, k-chunk
  f32x4 acc[2][2] = {};
  for(int k0=0; k0<K; k0+=32){
    { // stage A: 64 rows x 32 k. thread: r=t>>3 (0..31), c4=t&7
      int r = t>>3, c4 = t&7;
      #pragma unroll
      for(int it=0; it<2; ++it){
        int rr = r + it*32;
        F4 va; va.v = *(const float4*)(A + (m0+rr)*K + k0 + c4*4);
        unsigned lo = (unsigned)f2bu(va.f[0]) | ((unsigned)f2bu(va.f[1])<<16);
        unsigned hi = (unsigned)f2bu(va.f[2]) | ((unsigned)f2bu(va.f[3])<<16);
        *(uint2*)&As[rr][c4*4] = make_uint2(lo, hi);
      }
    }
    { // stage B: 32 k x 64 n, transposed to Bs[n][k].
      // thread: n = t&63, c8 = t>>6 (one 8-k chunk); 8 strided-coalesced loads
      int n = t&63, c8 = t>>6;
      unsigned short tmp[8];
      #pragma unroll
      for(int j=0;j<8;j++) tmp[j] = f2bu(Bw[(k0 + c8*8 + j)*N + n0 + n]);
      *(uint4*)&Bs[n][c8*8] = *(uint4*)tmp;
    }
    __syncthreads();
    bf16x8 af[2], bf[2];
    #pragma unroll
    for(int i=0;i<2;i++) af[i] = *(const bf16x8*)&As[wr*32 + i*16 + fr][kc*8];
    #pragma unroll
    for(int j=0;j<2;j++) bf[j] = *(const bf16x8*)&Bs[wc*32 + j*16 + fr][kc*8];
    #pragma unroll
    for(int i=0;i<2;i++)
      #pragma unroll
      for(int j=0;j<2;j++)
        acc[i][j] = __builtin_amdgcn_mfma_f32_16x16x32_bf16(af[i], bf[j], acc[i][j], 0, 0, 0);
    __syncthreads();
  }
  // epilogue: C/D layout col=lane&15, row=(lane>>4)*4+reg
  #pragma unroll
  for(int i=0;i<2;i++){
    #pragma unroll
    for(int r=0;r<4;r++){
      int row = m0 + wr*32 + i*16 + (lane>>4)*4 + r;
      #pragma unroll
      for(int j=0;j<2;j++){
        int col = n0 + wc*32 + j*16 + (lane&15);
        float val = acc[i][j][r];
        if(BIAS) val += bias[col];
        if(GELU) val = gelu_f(val);
        if(RES)  val += resid[row*N+col];
        C[row*N+col] = val;
      }
    }
  }
}

// ------------- FAVOR+ query features (in place over q) --------------------
__global__ __launch_bounds__(256) void k_qfeat(float* __restrict__ q,
    const float* __restrict__ proj){
  __shared__ float x_s[64][36];
  __shared__ float p_s[32][132];
  __shared__ float diag_s[64];
  int r0 = blockIdx.x*64;
  int t = threadIdx.x; int ti = t>>4, tj = t&15;
  const float norm  = 0.29730177875068026f;   // 128^-0.25
  const float ratio = 0.08838834764831845f;   // 128^-0.5
  { // diag pre-pass: 4 threads per row
    int r = t>>2, qt = t&3;
    const float* rp = q + (r0+r)*128 + qt*32;
    float ss = 0.f;
    #pragma unroll
    for(int u=0;u<32;u+=4){ F4 v4; v4.v = *(const float4*)(rp+u);
      ss += v4.f[0]*v4.f[0]+v4.f[1]*v4.f[1]+v4.f[2]*v4.f[2]+v4.f[3]*v4.f[3]; }
    ss *= norm*norm;
    ss += __shfl_xor(ss,1,64); ss += __shfl_xor(ss,2,64);
    if(qt==0) diag_s[r] = 0.5f*ss;
  }
  float dd[4][8] = {};
  for(int ds=0; ds<4; ++ds){
    #pragma unroll
    for(int it=0; it<2; ++it){  // stage 64x32 q slice, scaled
      int idx = t + it*256; int r = idx>>3, dc4 = idx&7;
      F4 v4; v4.v = *(const float4*)(q + (r0+r)*128 + ds*32 + dc4*4);
      v4.f[0]*=norm; v4.f[1]*=norm; v4.f[2]*=norm; v4.f[3]*=norm;
      *(float4*)&x_s[r][dc4*4] = v4.v;
    }
    #pragma unroll
    for(int it=0; it<4; ++it){  // stage proj^T slice p_s[d][m]
      int idx = t + it*256; int m = idx>>3, dc4 = idx&7;
      F4 v4; v4.v = *(const float4*)(proj + m*128 + ds*32 + dc4*4);
      p_s[dc4*4+0][m]=v4.f[0]; p_s[dc4*4+1][m]=v4.f[1];
      p_s[dc4*4+2][m]=v4.f[2]; p_s[dc4*4+3][m]=v4.f[3];
    }
    __syncthreads();
    #pragma unroll
    for(int d4=0;d4<8;d4++){
      F4 a[4];
      #pragma unroll
      for(int r=0;r<4;r++) a[r].v = *(const float4*)&x_s[ti*4+r][d4*4];
      #pragma unroll
      for(int dj=0;dj<4;dj++){
        F4 p0,p1;
        p0.v = *(const float4*)&p_s[d4*4+dj][tj*8];
        p1.v = *(const float4*)&p_s[d4*4+dj][tj*8+4];
        #pragma unroll
        for(int r=0;r<4;r++){
          float av = a[r].f[dj];
          dd[r][0]+=av*p0.f[0]; dd[r][1]+=av*p0.f[1]; dd[r][2]+=av*p0.f[2]; dd[r][3]+=av*p0.f[3];
          dd[r][4]+=av*p1.f[0]; dd[r][5]+=av*p1.f[1]; dd[r][6]+=av*p1.f[2]; dd[r][7]+=av*p1.f[3];
        }
      }
    }
    __syncthreads();
  }
  #pragma unroll
  for(int r=0;r<4;r++){
    float m8 = dd[r][0];
    #pragma unroll
    for(int mm=1;mm<8;mm++) m8 = fmaxf(m8, dd[r][mm]);
    #pragma unroll
    for(int msk=1;msk<16;msk<<=1) m8 = fmaxf(m8, __shfl_xor(m8, msk, 64));
    float dg = diag_s[ti*4+r];
    int row = r0 + ti*4 + r;
    float o_[8];
    #pragma unroll
    for(int mm=0;mm<8;mm++) o_[mm] = ratio*(expf(dd[r][mm]-dg-m8) + 1e-4f);
    *(float4*)(q + row*128 + tj*8)   = make_float4(o_[0],o_[1],o_[2],o_[3]);
    *(float4*)(q + row*128 + tj*8+4) = make_float4(o_[4],o_[5],o_[6],o_[7]);
  }
}

// ------------- FAVOR+ key features pass A: t = dd - diag, track max(dd) ----
__global__ __launch_bounds__(256) void k_kfeatA(float* __restrict__ k,
    const float* __restrict__ proj, unsigned* __restrict__ kstab){
  __shared__ float x_s[64][36];
  __shared__ float p_s[32][132];
  __shared__ float diag_s[64];
  __shared__ unsigned hmax[8];
  int r0 = blockIdx.x*64;
  int t = threadIdx.x; int ti = t>>4, tj = t&15;
  const float norm = 0.29730177875068026f;
  if(t<8) hmax[t] = 0u;
  {
    int r = t>>2, qt = t&3;
    const float* rp = k + (r0+r)*128 + qt*32;
    float ss = 0.f;
    #pragma unroll
    for(int u=0;u<32;u+=4){ F4 v4; v4.v = *(const float4*)(rp+u);
      ss += v4.f[0]*v4.f[0]+v4.f[1]*v4.f[1]+v4.f[2]*v4.f[2]+v4.f[3]*v4.f[3]; }
    ss *= norm*norm;
    ss += __shfl_xor(ss,1,64); ss += __shfl_xor(ss,2,64);
    if(qt==0) diag_s[r] = 0.5f*ss;
  }
  float dd[4][8] = {};
  for(int ds=0; ds<4; ++ds){
    #pragma unroll
    for(int it=0; it<2; ++it){
      int idx = t + it*256; int r = idx>>3, dc4 = idx&7;
      F4 v4; v4.v = *(const float4*)(k + (r0+r)*128 + ds*32 + dc4*4);
      v4.f[0]*=norm; v4.f[1]*=norm; v4.f[2]*=norm; v4.f[3]*=norm;
      *(float4*)&x_s[r][dc4*4] = v4.v;
    }
    #pragma unroll
    for(int it=0; it<4; ++it){
      int idx = t + it*256; int m = idx>>3, dc4 = idx&7;
      F4 v4; v4.v = *(const float4*)(proj + m*128 + ds*32 + dc4*4);
      p_s[dc4*4+0][m]=v4.f[0]; p_s[dc4*4+1][m]=v4.f[1];
      p_s[dc4*4+2][m]=v4.f[2]; p_s[dc4*4+3][m]=v4.f[3];
    }
    __syncthreads();
    #pragma unroll
    for(int d4=0;d4<8;d4++){
      F4 a[4];
      #pragma unroll
      for(int r=0;r<4;r++) a[r].v = *(const float4*)&x_s[ti*4+r][d4*4];
      #pragma unroll
      for(int dj=0;dj<4;dj++){
        F4 p0,p1;
        p0.v = *(const float4*)&p_s[d4*4+dj][tj*8];
        p1.v = *(const float4*)&p_s[d4*4+dj][tj*8+4];
        #pragma unroll
        for(int r=0;r<4;r++){
          float av = a[r].f[dj];
          dd[r][0]+=av*p0.f[0]; dd[r][1]+=av*p0.f[1]; dd[r][2]+=av*p0.f[2]; dd[r][3]+=av*p0.f[3];
          dd[r][4]+=av*p1.f[0]; dd[r][5]+=av*p1.f[1]; dd[r][6]+=av*p1.f[2]; dd[r][7]+=av*p1.f[3];
        }
      }
    }
    __syncthreads();
  }
  #pragma unroll
  for(int r=0;r<4;r++){
    float m8 = dd[r][0];
    #pragma unroll
    for(int mm=1;mm<8;mm++) m8 = fmaxf(m8, dd[r][mm]);
    #pragma unroll
    for(int msk=1;msk<16;msk<<=1) m8 = fmaxf(m8, __shfl_xor(m8, msk, 64));
    int row = r0 + ti*4 + r;
    if(tj==0) atomicMax(&hmax[row & 7], fkey(m8));
    float dg = diag_s[ti*4+r];
    float o_[8];
    #pragma unroll
    for(int mm=0;mm<8;mm++) o_[mm] = dd[r][mm]-dg;
    *(float4*)(k + row*128 + tj*8)   = make_float4(o_[0],o_[1],o_[2],o_[3]);
    *(float4*)(k + row*128 + tj*8+4) = make_float4(o_[4],o_[5],o_[6],o_[7]);
  }
  __syncthreads();
  int b = r0 >> 14;  // row / (S*H)
  if(t<8) atomicMax(&kstab[b*8 + t], hmax[t]);
}

// ------------- key features pass B: kp = ratio*(exp(t - stab)+eps) --------
__global__ __launch_bounds__(256) void k_kfeatB(float* __restrict__ k,
    const unsigned* __restrict__ kstab){
  const float ratio = 0.08838834764831845f;
  int idx4 = blockIdx.x*256 + threadIdx.x;   // f4 index, grid 8192
  int e = idx4*4;
  int row = e >> 7; int bh = ((row>>14)<<3) | (row & 7);
  float stab = funkey(kstab[bh]);
  F4 v4; v4.v = *(float4*)(k+e);
  #pragma unroll
  for(int u=0;u<4;u++) v4.f[u] = ratio*(expf(v4.f[u] - stab)+1e-4f);
  *(float4*)(k+e) = v4.v;
}

// ------------- attention phase 1: per-chunk kv = k^T v, ksum = sum k ------
__global__ __launch_bounds__(256) void k_attn1(const float* __restrict__ kp,
    const float* __restrict__ v, float* __restrict__ kvc, float* __restrict__ ksc){
  __shared__ float kp_s[32][132];
  __shared__ float v_s[32][132];
  int bc = blockIdx.x; int c = bc & 15; int bh = bc >> 4; int b = bh >> 3; int hh = bh & 7;
  int t = threadIdx.x; int tm = t>>4, td = t&15;
  float acc[8][8] = {};
  float ks = 0.f;
  for(int js=0; js<4; ++js){
    #pragma unroll
    for(int it=0; it<4; ++it){
      int idx = t + it*256; int jj = idx>>5, mc4 = idx&31;
      int s = c*128 + js*32 + jj;
      int base = ((b*Ss + s)*Hh + hh)*128;
      *(float4*)&kp_s[jj][mc4*4] = *(const float4*)(kp + base + mc4*4);
      *(float4*)&v_s[jj][mc4*4]  = *(const float4*)(v  + base + mc4*4);
    }
    __syncthreads();
    #pragma unroll 4
    for(int jj=0; jj<32; ++jj){
      F4 a0,a1,b0,b1;
      a0.v = *(const float4*)&kp_s[jj][tm*8];  a1.v = *(const float4*)&kp_s[jj][tm*8+4];
      b0.v = *(const float4*)&v_s[jj][td*8];   b1.v = *(const float4*)&v_s[jj][td*8+4];
      float av[8]={a0.f[0],a0.f[1],a0.f[2],a0.f[3],a1.f[0],a1.f[1],a1.f[2],a1.f[3]};
      float bv[8]={b0.f[0],b0.f[1],b0.f[2],b0.f[3],b1.f[0],b1.f[1],b1.f[2],b1.f[3]};
      #pragma unroll
      for(int i=0;i<8;i++){
        #pragma unroll
        for(int j=0;j<8;j++) acc[i][j] += av[i]*bv[j];
      }
    }
    if(t<128){
      #pragma unroll 8
      for(int jj=0;jj<32;++jj) ks += kp_s[jj][t];
    }
    __syncthreads();
  }
  int obase = bc*16384;
  #pragma unroll
  for(int r=0;r<8;r++){
    *(float4*)(kvc + obase + (tm*8+r)*128 + td*8)   = make_float4(acc[r][0],acc[r][1],acc[r][2],acc[r][3]);
    *(float4*)(kvc + obase + (tm*8+r)*128 + td*8+4) = make_float4(acc[r][4],acc[r][5],acc[r][6],acc[r][7]);
  }
  if(t<128) ksc[bc*128 + t] = ks;
}

// ------------- phase 1.5: element-parallel exclusive prefix over chunks ---
__global__ __launch_bounds__(256) void k_prefix(float* __restrict__ kvc){
  int bh = blockIdx.x >> 6; int pos = (blockIdx.x & 63)*256 + threadIdx.x;
  int base = bh*16*16384 + pos;
  float a = 0.f;
  #pragma unroll
  for(int c=0;c<16;c++){
    float xv = kvc[base + c*16384];
    kvc[base + c*16384] = a;
    a += xv;
  }
}
__global__ __launch_bounds__(256) void k_prefix_ks(float* __restrict__ ksc){
  int e = blockIdx.x*256 + threadIdx.x;  // 4096 total
  int bh = e>>7, m = e&127;
  float a = 0.f;
  #pragma unroll
  for(int c=0;c<16;c++){
    int idx = (bh*16+c)*128 + m;
    float xv = ksc[idx]; ksc[idx] = a; a += xv;
  }
}

// ------------- attention phase 2: per-chunk output -----------------------
__global__ __launch_bounds__(256) void k_attn2(const float* __restrict__ qp,
    const float* __restrict__ kp, const float* __restrict__ v,
    const float* __restrict__ kvc, const float* __restrict__ ksc,
    float* __restrict__ o){
  __shared__ float qp_s[128][36];
  __shared__ float kp_s[32][36];
  __shared__ float sv_s[32][132];
  __shared__ float attn_s[128][36];
  __shared__ float den_s[128];
  __shared__ float ksum_s[128];
  int bc = blockIdx.x; int c = bc&15, bh = bc>>4, b = bh>>3, hh = bh&7;
  int t = threadIdx.x; int ti = t>>4, tj = t&15;
  if(t<128){ den_s[t]=0.f; ksum_s[t] = ksc[bc*128+t]; }
  float acc[8][8] = {};
  int s0 = c*128;
  for(int js=0; js<4; ++js){
    float ar[8][2] = {};
    for(int ms=0; ms<4; ++ms){
      #pragma unroll
      for(int it=0; it<4; ++it){   // stage qp_s[128][32]
        int idx = t + it*256; int r = idx>>3, mc4 = idx&7;
        *(float4*)&qp_s[r][mc4*4] =
          *(const float4*)(qp + ((b*Ss+s0+r)*Hh+hh)*128 + ms*32 + mc4*4);
      }
      {                            // stage kp_s[32][32]
        int r = t>>3, mc4 = t&7;
        *(float4*)&kp_s[r][mc4*4] =
          *(const float4*)(kp + ((b*Ss+s0+js*32+r)*Hh+hh)*128 + ms*32 + mc4*4);
      }
      __syncthreads();
      #pragma unroll
      for(int m4=0;m4<8;m4++){
        F4 b0,b1;
        b0.v = *(const float4*)&kp_s[tj*2+0][m4*4];
        b1.v = *(const float4*)&kp_s[tj*2+1][m4*4];
        #pragma unroll
        for(int r=0;r<8;r++){
          F4 a; a.v = *(const float4*)&qp_s[ti*8+r][m4*4];
          #pragma unroll
          for(int u=0;u<4;u++){
            ar[r][0] += a.f[u]*b0.f[u];
            ar[r][1] += a.f[u]*b1.f[u];
          }
        }
      }
      __syncthreads();
    }
    #pragma unroll
    for(int r=0;r<8;r++){
      int i = ti*8+r;
      int j0 = js*32 + tj*2;
      float p0 = (j0   > i) ? 0.f : ar[r][0];
      float p1 = (j0+1 > i) ? 0.f : ar[r][1];
      attn_s[i][tj*2+0] = p0;
      attn_s[i][tj*2+1] = p1;
      float ps = p0+p1;
      #pragma unroll
      for(int msk=1;msk<16;msk<<=1) ps += __shfl_xor(ps,msk,64);
      if(tj==0) den_s[i] += ps;
    }
    #pragma unroll
    for(int it=0; it<4; ++it){   // stage v slice [32][128]
      int idx = t+it*256; int jj = idx>>5, mc4 = idx&31;
      *(float4*)&sv_s[jj][mc4*4] =
        *(const float4*)(v + ((b*Ss+s0+js*32+jj)*Hh+hh)*128 + mc4*4);
    }
    __syncthreads();
    #pragma unroll
    for(int j4=0;j4<8;j4++){
      F4 a[8];
      #pragma unroll
      for(int r=0;r<8;r++) a[r].v = *(const float4*)&attn_s[ti*8+r][j4*4];
      #pragma unroll
      for(int jj=0;jj<4;jj++){
        F4 v0,v1;
        v0.v = *(const float4*)&sv_s[j4*4+jj][tj*8];
        v1.v = *(const float4*)&sv_s[j4*4+jj][tj*8+4];
        #pragma unroll
        for(int r=0;r<8;r++){
          float av = a[r].f[jj];
          acc[r][0]+=av*v0.f[0]; acc[r][1]+=av*v0.f[1]; acc[r][2]+=av*v0.f[2]; acc[r][3]+=av*v0.f[3];
          acc[r][4]+=av*v1.f[0]; acc[r][5]+=av*v1.f[1]; acc[r][6]+=av*v1.f[2]; acc[r][7]+=av*v1.f[3];
        }
      }
    }
    __syncthreads();
  }
  for(int ms=0; ms<4; ++ms){
    #pragma unroll
    for(int it=0; it<4; ++it){
      int idx = t + it*256; int r = idx>>3, mc4 = idx&7;
      *(float4*)&qp_s[r][mc4*4] =
        *(const float4*)(qp + ((b*Ss+s0+r)*Hh+hh)*128 + ms*32 + mc4*4);
    }
    #pragma unroll
    for(int it=0; it<4; ++it){
      int idx = t+it*256; int mm = idx>>5, dc4 = idx&31;
      *(float4*)&sv_s[mm][dc4*4] =
        *(const float4*)(kvc + bc*16384 + (ms*32+mm)*128 + dc4*4);
    }
    __syncthreads();
    #pragma unroll
    for(int m4=0;m4<8;m4++){
      F4 a[8];
      #pragma unroll
      for(int r=0;r<8;r++) a[r].v = *(const float4*)&qp_s[ti*8+r][m4*4];
      #pragma unroll
      for(int mm=0;mm<4;mm++){
        F4 v0,v1;
        v0.v = *(const float4*)&sv_s[m4*4+mm][tj*8];
        v1.v = *(const float4*)&sv_s[m4*4+mm][tj*8+4];
        #pragma unroll
        for(int r=0;r<8;r++){
          float av = a[r].f[mm];
          acc[r][0]+=av*v0.f[0]; acc[r][1]+=av*v0.f[1]; acc[r][2]+=av*v0.f[2]; acc[r][3]+=av*v0.f[3];
          acc[r][4]+=av*v1.f[0]; acc[r][5]+=av*v1.f[1]; acc[r][6]+=av*v1.f[2]; acc[r][7]+=av*v1.f[3];
        }
      }
    }
    __syncthreads();
  }
  if(t<128){
    int i = t;
    const float* qrow = qp + ((b*Ss+s0+i)*Hh+hh)*128;
    float d2 = 0.f;
    #pragma unroll 8
    for(int m=0;m<128;m+=4){
      F4 a; a.v = *(const float4*)(qrow+m);
      d2 += a.f[0]*ksum_s[m]+a.f[1]*ksum_s[m+1]+a.f[2]*ksum_s[m+2]+a.f[3]*ksum_s[m+3];
    }
    den_s[i] += d2;
  }
  __syncthreads();
  #pragma unroll
  for(int r=0;r<8;r++){
    int i = ti*8+r;
    float inv = 1.0f/(den_s[i]+1e-6f);
    int base = ((b*Ss+s0+i)*Hh+hh)*128 + tj*8;
    *(float4*)(o+base)   = make_float4(acc[r][0]*inv, acc[r][1]*inv, acc[r][2]*inv, acc[r][3]*inv);
    *(float4*)(o+base+4) = make_float4(acc[r][4]*inv, acc[r][5]*inv, acc[r][6]*inv, acc[r][7]*inv);
  }
}

// ------------- pooling: partial sums over S (64 blocks) -------------------
__global__ __launch_bounds__(256) void k_pool(const float* __restrict__ h,
    float* __restrict__ pw){
  __shared__ float part[256];
  int blk = blockIdx.x; int b = blk>>4, c = blk&15;
  int t = threadIdx.x; int half = t>>7;
  float s = 0.f;
  int s0 = c*128 + half*64;
  for(int si=s0; si<s0+64; ++si) s += h[(b*Ss+si)*128 + (t&127)];
  part[t] = s;
  __syncthreads();
  if(t<128) pw[blk*128 + t] = part[t] + part[t+128];
}

// ------------- classifier ------------------------------------------------
__global__ __launch_bounds__(128) void k_cls(const float* __restrict__ pw,
    const float* __restrict__ fw, const float* __restrict__ fb,
    float* __restrict__ out){
  __shared__ float pool_s[128];
  int b = blockIdx.x; int t = threadIdx.x;
  float s = 0.f;
  for(int c=0;c<16;c++) s += pw[(b*16+c)*128 + t];
  pool_s[t] = s * (1.0f/2048.0f);
  __syncthreads();
  if(t<10){
    float a = fb[t];
    for(int d=0; d<128; ++d) a += pool_s[d]*fw[d*10+t];
    out[b*10+t] = a;
  }
}

extern "C" void kernel_launch(void* const* d_in, const int* in_sizes, int n_in,
                              void* d_out, int out_size, void* d_ws, size_t ws_size,
                              hipStream_t stream){
  (void)in_sizes; (void)n_in; (void)out_size; (void)ws_size;
  const float* x     = (const float*)d_in[0];
  const float* lin_w = (const float*)d_in[1];
  const float* lin_b = (const float*)d_in[2];
  const float* pe    = (const float*)d_in[3];
  const float* proj  = (const float*)d_in[4];
  const float* ln1_g = (const float*)d_in[5];
  const float* ln1_b = (const float*)d_in[6];
  const float* wq    = (const float*)d_in[7];
  const float* wk    = (const float*)d_in[8];
  const float* wv    = (const float*)d_in[9];
  const float* wo    = (const float*)d_in[10];
  const float* wo_b  = (const float*)d_in[11];
  const float* ln2_g = (const float*)d_in[12];
  const float* ln2_b = (const float*)d_in[13];
  const float* ff1w  = (const float*)d_in[14];
  const float* ff1b  = (const float*)d_in[15];
  const float* ff2w  = (const float*)d_in[16];
  const float* ff2b  = (const float*)d_in[17];
  const float* finw  = (const float*)d_in[18];
  const float* finb  = (const float*)d_in[19];
  float* out = (float*)d_out;

  // workspace layout (floats); total ~176 MB
  float* ws  = (float*)d_ws;
  float* h   = ws;              // [8192][128]
  float* y   = h  + 1048576;    // [8192][128]
  float* q   = y  + 1048576;    // [8192][1024]  (also reused as FF intermediate)
  float* k   = q  + 8388608;
  float* v   = k  + 8388608;
  float* o   = v  + 8388608;
  float* kvc = o  + 8388608;    // [32][16][128][128]
  float* ksc = kvc + 8388608;   // [32][16][128]
  float* pw  = ksc + 65536;     // [4][16][128] pooling partials
  unsigned* kstab = (unsigned*)(pw + 8192);  // [DEPTH][32]

  k_init<<<1,64,0,stream>>>(kstab);
  k_embed<<<4096,256,0,stream>>>(x, lin_w, lin_b, pe, h);
  for(int l=0;l<2;l++){
    const float* projl = proj + l*Mf*DHc;
    k_ln<<<2048,256,0,stream>>>(h, ln1_g + l*DIMc, ln1_b + l*DIMc, y);
    k_gemm_mfma<false,false,false><<<dim3(16,128),256,0,stream>>>(y, wq + l*DIMc*INNERc, nullptr, nullptr, q, INNERc, DIMc);
    k_gemm_mfma<false,false,false><<<dim3(16,128),256,0,stream>>>(y, wk + l*DIMc*INNERc, nullptr, nullptr, k, INNERc, DIMc);
    k_gemm_mfma<false,false,false><<<dim3(16,128),256,0,stream>>>(y, wv + l*DIMc*INNERc, nullptr, nullptr, v, INNERc, DIMc);
    k_qfeat<<<1024,256,0,stream>>>(q, projl);
    k_kfeatA<<<1024,256,0,stream>>>(k, projl, kstab + l*32);
    k_kfeatB<<<8192,256,0,stream>>>(k, kstab + l*32);
    k_attn1<<<512,256,0,stream>>>(k, v, kvc, ksc);
    k_prefix<<<2048,256,0,stream>>>(kvc);
    k_prefix_ks<<<16,256,0,stream>>>(ksc);
    k_attn2<<<512,256,0,stream>>>(q, k, v, kvc, ksc, o);
    k_gemm_mfma<true,false,true><<<dim3(2,128),256,0,stream>>>(o, wo + l*INNERc*DIMc, wo_b + l*DIMc, h, h, DIMc, INNERc);
    k_ln<<<2048,256,0,stream>>>(h, ln2_g + l*DIMc, ln2_b + l*DIMc, y);
    k_gemm_mfma<true,true,false><<<dim3(8,128),256,0,stream>>>(y, ff1w + l*DIMc*FFc, ff1b + l*FFc, nullptr, q, FFc, DIMc);
    k_gemm_mfma<true,false,true><<<dim3(2,128),256,0,stream>>>(q, ff2w + l*FFc*DIMc, ff2b + l*DIMc, h, h, DIMc, FFc);
  }
  k_pool<<<64,256,0,stream>>>(h, pw);
  k_cls<<<4,128,0,stream>>>(pw, finw, finb, out);
}

// Round 3
// 719.245 us; speedup vs baseline: 2.1975x; 1.4161x over previous
//
#include <hip/hip_runtime.h>
#include <hip/hip_bf16.h>

// Problem constants
#define Bb 4
#define Ss 2048
#define DIMc 128
#define Hh 8
#define DHc 128
#define Mf 128
#define CH 128
#define NCc 16         // S / CHUNK
#define INNERc 1024    // H*DH
#define FFc 512

union F4 { float4 v; float f[4]; };

typedef __bf16 bf16x8 __attribute__((ext_vector_type(8)));
typedef float  f32x4  __attribute__((ext_vector_type(4)));

__device__ __forceinline__ unsigned fkey(float f){
  unsigned b = __float_as_uint(f);
  return (b & 0x80000000u) ? ~b : (b | 0x80000000u);
}
__device__ __forceinline__ float funkey(unsigned u){
  unsigned b = (u & 0x80000000u) ? (u & 0x7fffffffu) : ~u;
  return __uint_as_float(b);
}
__device__ __forceinline__ float gelu_f(float x){
  return 0.5f*x*(1.0f + tanhf(0.7978845608028654f*(x + 0.044715f*x*x*x)));
}
// f32 -> bf16 (RNE) as raw ushort
__device__ __forceinline__ unsigned short f2bu(float f){
  unsigned u = __float_as_uint(f);
  return (unsigned short)((u + 0x7fffu + ((u>>16)&1u)) >> 16);
}

// ---- swizzled bf16 LDS tile helpers: tile is [128][128] bf16 (32KB),
// byte addr = row*256 + elem*2, XOR-swizzled by ((row&7)<<4)  (G4 fix) ----
__device__ __forceinline__ bf16x8 ldfrag(const unsigned short* base, int row, int e){
  int byte = (row*256 + e*2) ^ ((row&7)<<4);
  return *(const bf16x8*)((const char*)base + byte);
}
// stage fp32 row-major [128 rows x 128 cols] (row stride srs floats) -> bf16 tile
__device__ __forceinline__ void stage_lin(unsigned short* dst, const float* src,
    int srs, int t){
  #pragma unroll
  for(int it=0; it<16; ++it){
    int e4 = t + it*256; int r = e4>>5, c4 = e4&31;
    F4 v; v.v = *(const float4*)(src + r*srs + c4*4);
    unsigned lo = (unsigned)f2bu(v.f[0]) | ((unsigned)f2bu(v.f[1])<<16);
    unsigned hi = (unsigned)f2bu(v.f[2]) | ((unsigned)f2bu(v.f[3])<<16);
    int byte = (r*256 + c4*8) ^ ((r&7)<<4);
    *(uint2*)((char*)dst + byte) = make_uint2(lo, hi);
  }
}
// stage TRANSPOSED: dst[d][j] = src[j][d]; src row stride srs floats
__device__ __forceinline__ void stage_tr(unsigned short* dst, const float* src,
    int srs, int t){
  int jp = t & 63; int j0 = jp*2; int wv = t>>6;
  #pragma unroll
  for(int it=0; it<2; ++it){
    int d0 = wv*16 + it*64;
    F4 r0[4], r1[4];
    #pragma unroll
    for(int u=0;u<4;u++){
      r0[u].v = *(const float4*)(src + j0*srs     + d0 + u*4);
      r1[u].v = *(const float4*)(src + (j0+1)*srs + d0 + u*4);
    }
    #pragma unroll
    for(int dc=0; dc<16; ++dc){
      int d = d0 + dc;
      unsigned pk = (unsigned)f2bu(r0[dc>>2].f[dc&3]) |
                    ((unsigned)f2bu(r1[dc>>2].f[dc&3])<<16);
      int byte = (d*256 + j0*2) ^ ((d&7)<<4);
      *(unsigned*)((char*)dst + byte) = pk;
    }
  }
}

// ---------------- init (zero the kstab atomic-max slots) ----------------
__global__ __launch_bounds__(64) void k_init(unsigned* kstab){
  if(threadIdx.x < 64) kstab[threadIdx.x] = 0u;   // DEPTH*B*H = 64
}

// ---------------- embedding: h = x*lin_w + lin_b + pe ----------------
__global__ __launch_bounds__(256) void k_embed(const float* __restrict__ x,
    const float* __restrict__ lw, const float* __restrict__ lb,
    const float* __restrict__ pe, float* __restrict__ h){
  int idx = blockIdx.x*256 + threadIdx.x;
  int d = idx & 127; int bs = idx >> 7; int s = bs & (Ss-1);
  h[idx] = x[bs]*lw[d] + lb[d] + pe[s*DIMc + d];
}

// ---------------- layernorm (one wave per row of 128) ----------------
__global__ __launch_bounds__(256) void k_ln(const float* __restrict__ in,
    const float* __restrict__ g, const float* __restrict__ bta,
    float* __restrict__ out){
  int wave = threadIdx.x >> 6; int lane = threadIdx.x & 63;
  int row = blockIdx.x*4 + wave;
  const float* r = in + row*DIMc;
  float x1 = r[lane], x2 = r[lane+64];
  float s = x1+x2, sq = x1*x1 + x2*x2;
  #pragma unroll
  for(int m=1;m<64;m<<=1){ s += __shfl_xor(s,m,64); sq += __shfl_xor(sq,m,64); }
  float mu = s * (1.0f/128.0f);
  float var = sq*(1.0f/128.0f) - mu*mu;
  float rs = rsqrtf(var + 1e-5f);
  out[row*DIMc+lane]    = (x1-mu)*rs*g[lane]+bta[lane];
  out[row*DIMc+lane+64] = (x2-mu)*rs*g[lane+64]+bta[lane+64];
}

// ---------------- bf16 MFMA GEMM: C = [resid +] act(A@B + bias) ----------
template<bool BIAS, bool GELU, bool RES>
__global__ __launch_bounds__(256) void k_gemm_mfma(const float* __restrict__ A,
    const float* __restrict__ Bw, const float* __restrict__ bias,
    const float* __restrict__ resid, float* __restrict__ C, int N, int K){
  __shared__ unsigned short As[64][40];
  __shared__ unsigned short Bs[64][40];
  int m0 = blockIdx.y*64, n0 = blockIdx.x*64;
  int t = threadIdx.x; int wid = t>>6, lane = t&63;
  int wr = wid>>1, wc = wid&1;
  int fr = lane&15, kc = lane>>4;
  f32x4 acc[2][2] = {};
  for(int k0=0; k0<K; k0+=32){
    {
      int r = t>>3, c4 = t&7;
      #pragma unroll
      for(int it=0; it<2; ++it){
        int rr = r + it*32;
        F4 va; va.v = *(const float4*)(A + (m0+rr)*K + k0 + c4*4);
        unsigned lo = (unsigned)f2bu(va.f[0]) | ((unsigned)f2bu(va.f[1])<<16);
        unsigned hi = (unsigned)f2bu(va.f[2]) | ((unsigned)f2bu(va.f[3])<<16);
        *(uint2*)&As[rr][c4*4] = make_uint2(lo, hi);
      }
    }
    {
      int n = t&63, c8 = t>>6;
      unsigned short tmp[8];
      #pragma unroll
      for(int j=0;j<8;j++) tmp[j] = f2bu(Bw[(k0 + c8*8 + j)*N + n0 + n]);
      *(uint4*)&Bs[n][c8*8] = *(uint4*)tmp;
    }
    __syncthreads();
    bf16x8 af[2], bf[2];
    #pragma unroll
    for(int i=0;i<2;i++) af[i] = *(const bf16x8*)&As[wr*32 + i*16 + fr][kc*8];
    #pragma unroll
    for(int j=0;j<2;j++) bf[j] = *(const bf16x8*)&Bs[wc*32 + j*16 + fr][kc*8];
    #pragma unroll
    for(int i=0;i<2;i++)
      #pragma unroll
      for(int j=0;j<2;j++)
        acc[i][j] = __builtin_amdgcn_mfma_f32_16x16x32_bf16(af[i], bf[j], acc[i][j], 0, 0, 0);
    __syncthreads();
  }
  #pragma unroll
  for(int i=0;i<2;i++){
    #pragma unroll
    for(int r=0;r<4;r++){
      int row = m0 + wr*32 + i*16 + (lane>>4)*4 + r;
      #pragma unroll
      for(int j=0;j<2;j++){
        int col = n0 + wc*32 + j*16 + (lane&15);
        float val = acc[i][j][r];
        if(BIAS) val += bias[col];
        if(GELU) val = gelu_f(val);
        if(RES)  val += resid[row*N+col];
        C[row*N+col] = val;
      }
    }
  }
}

// ------------- FAVOR+ query features (in place over q) --------------------
__global__ __launch_bounds__(256) void k_qfeat(float* __restrict__ q,
    const float* __restrict__ proj){
  __shared__ float x_s[64][36];
  __shared__ float p_s[32][132];
  __shared__ float diag_s[64];
  int r0 = blockIdx.x*64;
  int t = threadIdx.x; int ti = t>>4, tj = t&15;
  const float norm  = 0.29730177875068026f;   // 128^-0.25
  const float ratio = 0.08838834764831845f;   // 128^-0.5
  {
    int r = t>>2, qt = t&3;
    const float* rp = q + (r0+r)*128 + qt*32;
    float ss = 0.f;
    #pragma unroll
    for(int u=0;u<32;u+=4){ F4 v4; v4.v = *(const float4*)(rp+u);
      ss += v4.f[0]*v4.f[0]+v4.f[1]*v4.f[1]+v4.f[2]*v4.f[2]+v4.f[3]*v4.f[3]; }
    ss *= norm*norm;
    ss += __shfl_xor(ss,1,64); ss += __shfl_xor(ss,2,64);
    if(qt==0) diag_s[r] = 0.5f*ss;
  }
  float dd[4][8] = {};
  for(int ds=0; ds<4; ++ds){
    #pragma unroll
    for(int it=0; it<2; ++it){
      int idx = t + it*256; int r = idx>>3, dc4 = idx&7;
      F4 v4; v4.v = *(const float4*)(q + (r0+r)*128 + ds*32 + dc4*4);
      v4.f[0]*=norm; v4.f[1]*=norm; v4.f[2]*=norm; v4.f[3]*=norm;
      *(float4*)&x_s[r][dc4*4] = v4.v;
    }
    #pragma unroll
    for(int it=0; it<4; ++it){
      int idx = t + it*256; int m = idx>>3, dc4 = idx&7;
      F4 v4; v4.v = *(const float4*)(proj + m*128 + ds*32 + dc4*4);
      p_s[dc4*4+0][m]=v4.f[0]; p_s[dc4*4+1][m]=v4.f[1];
      p_s[dc4*4+2][m]=v4.f[2]; p_s[dc4*4+3][m]=v4.f[3];
    }
    __syncthreads();
    #pragma unroll
    for(int d4=0;d4<8;d4++){
      F4 a[4];
      #pragma unroll
      for(int r=0;r<4;r++) a[r].v = *(const float4*)&x_s[ti*4+r][d4*4];
      #pragma unroll
      for(int dj=0;dj<4;dj++){
        F4 p0,p1;
        p0.v = *(const float4*)&p_s[d4*4+dj][tj*8];
        p1.v = *(const float4*)&p_s[d4*4+dj][tj*8+4];
        #pragma unroll
        for(int r=0;r<4;r++){
          float av = a[r].f[dj];
          dd[r][0]+=av*p0.f[0]; dd[r][1]+=av*p0.f[1]; dd[r][2]+=av*p0.f[2]; dd[r][3]+=av*p0.f[3];
          dd[r][4]+=av*p1.f[0]; dd[r][5]+=av*p1.f[1]; dd[r][6]+=av*p1.f[2]; dd[r][7]+=av*p1.f[3];
        }
      }
    }
    __syncthreads();
  }
  #pragma unroll
  for(int r=0;r<4;r++){
    float m8 = dd[r][0];
    #pragma unroll
    for(int mm=1;mm<8;mm++) m8 = fmaxf(m8, dd[r][mm]);
    #pragma unroll
    for(int msk=1;msk<16;msk<<=1) m8 = fmaxf(m8, __shfl_xor(m8, msk, 64));
    float dg = diag_s[ti*4+r];
    int row = r0 + ti*4 + r;
    float o_[8];
    #pragma unroll
    for(int mm=0;mm<8;mm++) o_[mm] = ratio*(expf(dd[r][mm]-dg-m8) + 1e-4f);
    *(float4*)(q + row*128 + tj*8)   = make_float4(o_[0],o_[1],o_[2],o_[3]);
    *(float4*)(q + row*128 + tj*8+4) = make_float4(o_[4],o_[5],o_[6],o_[7]);
  }
}

// ------------- FAVOR+ key features pass A: t = dd - diag, track max(dd) ----
__global__ __launch_bounds__(256) void k_kfeatA(float* __restrict__ k,
    const float* __restrict__ proj, unsigned* __restrict__ kstab){
  __shared__ float x_s[64][36];
  __shared__ float p_s[32][132];
  __shared__ float diag_s[64];
  __shared__ unsigned hmax[8];
  int r0 = blockIdx.x*64;
  int t = threadIdx.x; int ti = t>>4, tj = t&15;
  const float norm = 0.29730177875068026f;
  if(t<8) hmax[t] = 0u;
  {
    int r = t>>2, qt = t&3;
    const float* rp = k + (r0+r)*128 + qt*32;
    float ss = 0.f;
    #pragma unroll
    for(int u=0;u<32;u+=4){ F4 v4; v4.v = *(const float4*)(rp+u);
      ss += v4.f[0]*v4.f[0]+v4.f[1]*v4.f[1]+v4.f[2]*v4.f[2]+v4.f[3]*v4.f[3]; }
    ss *= norm*norm;
    ss += __shfl_xor(ss,1,64); ss += __shfl_xor(ss,2,64);
    if(qt==0) diag_s[r] = 0.5f*ss;
  }
  float dd[4][8] = {};
  for(int ds=0; ds<4; ++ds){
    #pragma unroll
    for(int it=0; it<2; ++it){
      int idx = t + it*256; int r = idx>>3, dc4 = idx&7;
      F4 v4; v4.v = *(const float4*)(k + (r0+r)*128 + ds*32 + dc4*4);
      v4.f[0]*=norm; v4.f[1]*=norm; v4.f[2]*=norm; v4.f[3]*=norm;
      *(float4*)&x_s[r][dc4*4] = v4.v;
    }
    #pragma unroll
    for(int it=0; it<4; ++it){
      int idx = t + it*256; int m = idx>>3, dc4 = idx&7;
      F4 v4; v4.v = *(const float4*)(proj + m*128 + ds*32 + dc4*4);
      p_s[dc4*4+0][m]=v4.f[0]; p_s[dc4*4+1][m]=v4.f[1];
      p_s[dc4*4+2][m]=v4.f[2]; p_s[dc4*4+3][m]=v4.f[3];
    }
    __syncthreads();
    #pragma unroll
    for(int d4=0;d4<8;d4++){
      F4 a[4];
      #pragma unroll
      for(int r=0;r<4;r++) a[r].v = *(const float4*)&x_s[ti*4+r][d4*4];
      #pragma unroll
      for(int dj=0;dj<4;dj++){
        F4 p0,p1;
        p0.v = *(const float4*)&p_s[d4*4+dj][tj*8];
        p1.v = *(const float4*)&p_s[d4*4+dj][tj*8+4];
        #pragma unroll
        for(int r=0;r<4;r++){
          float av = a[r].f[dj];
          dd[r][0]+=av*p0.f[0]; dd[r][1]+=av*p0.f[1]; dd[r][2]+=av*p0.f[2]; dd[r][3]+=av*p0.f[3];
          dd[r][4]+=av*p1.f[0]; dd[r][5]+=av*p1.f[1]; dd[r][6]+=av*p1.f[2]; dd[r][7]+=av*p1.f[7-4+4];
        }
      }
    }
    __syncthreads();
  }
  #pragma unroll
  for(int r=0;r<4;r++){
    float m8 = dd[r][0];
    #pragma unroll
    for(int mm=1;mm<8;mm++) m8 = fmaxf(m8, dd[r][mm]);
    #pragma unroll
    for(int msk=1;msk<16;msk<<=1) m8 = fmaxf(m8, __shfl_xor(m8, msk, 64));
    int row = r0 + ti*4 + r;
    if(tj==0) atomicMax(&hmax[row & 7], fkey(m8));
    float dg = diag_s[ti*4+r];
    float o_[8];
    #pragma unroll
    for(int mm=0;mm<8;mm++) o_[mm] = dd[r][mm]-dg;
    *(float4*)(k + row*128 + tj*8)   = make_float4(o_[0],o_[1],o_[2],o_[3]);
    *(float4*)(k + row*128 + tj*8+4) = make_float4(o_[4],o_[5],o_[6],o_[7]);
  }
  __syncthreads();
  int b = r0 >> 14;
  if(t<8) atomicMax(&kstab[b*8 + t], hmax[t]);
}

// ------------- key features pass B: kp = ratio*(exp(t - stab)+eps) --------
__global__ __launch_bounds__(256) void k_kfeatB(float* __restrict__ k,
    const unsigned* __restrict__ kstab){
  const float ratio = 0.08838834764831845f;
  int idx4 = blockIdx.x*256 + threadIdx.x;
  int e = idx4*4;
  int row = e >> 7; int bh = ((row>>14)<<3) | (row & 7);
  float stab = funkey(kstab[bh]);
  F4 v4; v4.v = *(float4*)(k+e);
  #pragma unroll
  for(int u=0;u<4;u++) v4.f[u] = ratio*(expf(v4.f[u] - stab)+1e-4f);
  *(float4*)(k+e) = v4.v;
}

// ------------- attention phase 1 (MFMA): kv = k^T v, ksum = sum k ---------
__global__ __launch_bounds__(256) void k_attn1m(const float* __restrict__ kp,
    const float* __restrict__ v, float* __restrict__ kvc, float* __restrict__ ksc){
  __shared__ __align__(16) unsigned short kt[16384];  // kt[m][j] = kp[j][m]
  __shared__ __align__(16) unsigned short vt[16384];  // vt[d][j] = v[j][d]
  int bc = blockIdx.x; int c = bc&15, bh = bc>>4, b = bh>>3, hh = bh&7;
  int t = threadIdx.x; int lane = t&63, w = t>>6;
  int fr = lane&15, kc = lane>>4;
  int s0 = c*128;
  const float* kb = kp + (size_t)((b*Ss+s0)*Hh + hh)*128;
  const float* vb = v  + (size_t)((b*Ss+s0)*Hh + hh)*128;
  stage_tr(kt, kb, 1024, t);
  stage_tr(vt, vb, 1024, t);
  __syncthreads();
  f32x4 acc[2][8] = {};
  f32x4 ks[2] = {};
  bf16x8 bones;
  #pragma unroll
  for(int e=0;e<8;e++) bones[e] = (fr==0) ? (__bf16)1.0f : (__bf16)0.0f;
  #pragma unroll
  for(int js=0;js<4;js++){
    bf16x8 am[2];
    #pragma unroll
    for(int i=0;i<2;i++) am[i] = ldfrag(kt, w*32+i*16+fr, js*32+kc*8);
    bf16x8 bv[8];
    #pragma unroll
    for(int cb=0;cb<8;cb++) bv[cb] = ldfrag(vt, cb*16+fr, js*32+kc*8);
    #pragma unroll
    for(int i=0;i<2;i++){
      ks[i] = __builtin_amdgcn_mfma_f32_16x16x32_bf16(am[i], bones, ks[i], 0,0,0);
      #pragma unroll
      for(int cb=0;cb<8;cb++)
        acc[i][cb] = __builtin_amdgcn_mfma_f32_16x16x32_bf16(am[i], bv[cb], acc[i][cb], 0,0,0);
    }
  }
  float* kvb = kvc + (size_t)bc*16384;
  #pragma unroll
  for(int i=0;i<2;i++){
    #pragma unroll
    for(int r=0;r<4;r++){
      int m = w*32 + i*16 + kc*4 + r;
      #pragma unroll
      for(int cb=0;cb<8;cb++) kvb[m*128 + cb*16 + fr] = acc[i][cb][r];
      if(fr==0) ksc[bc*128 + m] = ks[i][r];
    }
  }
}

// ------------- phase 1.5: element-parallel exclusive prefix over chunks ---
__global__ __launch_bounds__(256) void k_prefix(float* __restrict__ kvc){
  int bh = blockIdx.x >> 6; int pos = (blockIdx.x & 63)*256 + threadIdx.x;
  int base = bh*16*16384 + pos;
  float a = 0.f;
  #pragma unroll
  for(int c=0;c<16;c++){
    float xv = kvc[base + c*16384];
    kvc[base + c*16384] = a;
    a += xv;
  }
}
__global__ __launch_bounds__(256) void k_prefix_ks(float* __restrict__ ksc){
  int e = blockIdx.x*256 + threadIdx.x;
  int bh = e>>7, m = e&127;
  float a = 0.f;
  #pragma unroll
  for(int c=0;c<16;c++){
    int idx = (bh*16+c)*128 + m;
    float xv = ksc[idx]; ksc[idx] = a; a += xv;
  }
}

// ------------- attention phase 2 (MFMA): per-chunk output ----------------
__global__ __launch_bounds__(256) void k_attn2m(const float* __restrict__ qp,
    const float* __restrict__ kp, const float* __restrict__ v,
    const float* __restrict__ kvc, const float* __restrict__ ksc,
    float* __restrict__ o){
  __shared__ __align__(16) unsigned short qs[16384];  // qp -> P
  __shared__ __align__(16) unsigned short bs[16384];  // kp -> v^T -> kv^T
  __shared__ float ksum_s[128];
  int bc = blockIdx.x; int c = bc&15, bh = bc>>4, b = bh>>3, hh = bh&7;
  int t = threadIdx.x; int lane = t&63, w = t>>6;
  int fr = lane&15, kc = lane>>4;
  int s0 = c*128;
  const float* qb = qp + (size_t)((b*Ss+s0)*Hh + hh)*128;
  const float* kb = kp + (size_t)((b*Ss+s0)*Hh + hh)*128;
  const float* vb = v  + (size_t)((b*Ss+s0)*Hh + hh)*128;
  const float* kvb = kvc + (size_t)bc*16384;
  stage_lin(qs, qb, 1024, t);
  stage_lin(bs, kb, 1024, t);
  if(t<128) ksum_s[t] = ksc[bc*128 + t];
  __syncthreads();
  // A-fragments of qp (reused for S and for qp@kv)
  bf16x8 aq[2][4];
  #pragma unroll
  for(int i=0;i<2;i++)
    #pragma unroll
    for(int ks=0;ks<4;ks++)
      aq[i][ks] = ldfrag(qs, w*32+i*16+fr, ks*32+kc*8);
  // S = qp @ kp^T
  f32x4 sacc[2][8] = {};
  #pragma unroll
  for(int ks=0;ks<4;ks++){
    bf16x8 bk[8];
    #pragma unroll
    for(int cb=0;cb<8;cb++) bk[cb] = ldfrag(bs, cb*16+fr, ks*32+kc*8);
    #pragma unroll
    for(int i=0;i<2;i++)
      #pragma unroll
      for(int cb=0;cb<8;cb++)
        sacc[i][cb] = __builtin_amdgcn_mfma_f32_16x16x32_bf16(aq[i][ks], bk[cb], sacc[i][cb], 0,0,0);
  }
  __syncthreads();   // all qs(aq) & bs(kp) reads complete
  // masked P -> qs (bf16); stage v^T -> bs
  #pragma unroll
  for(int i=0;i<2;i++){
    #pragma unroll
    for(int cb=0;cb<8;cb++){
      #pragma unroll
      for(int r=0;r<4;r++){
        int prow = w*32 + i*16 + kc*4 + r;
        int pcol = cb*16 + fr;
        float pv = (pcol > prow) ? 0.f : sacc[i][cb][r];
        int byte = (prow*256 + pcol*2) ^ ((prow&7)<<4);
        *(unsigned short*)((char*)qs + byte) = f2bu(pv);
      }
    }
  }
  stage_tr(bs, vb, 1024, t);
  __syncthreads();
  // num = P @ v ; den = P @ ones
  f32x4 nacc[2][8] = {};
  f32x4 dacc[2] = {};
  bf16x8 bones;
  #pragma unroll
  for(int e=0;e<8;e++) bones[e] = (fr==0) ? (__bf16)1.0f : (__bf16)0.0f;
  #pragma unroll
  for(int js=0;js<4;js++){
    bf16x8 ap[2];
    #pragma unroll
    for(int i=0;i<2;i++) ap[i] = ldfrag(qs, w*32+i*16+fr, js*32+kc*8);
    bf16x8 bv[8];
    #pragma unroll
    for(int cb=0;cb<8;cb++) bv[cb] = ldfrag(bs, cb*16+fr, js*32+kc*8);
    #pragma unroll
    for(int i=0;i<2;i++){
      dacc[i] = __builtin_amdgcn_mfma_f32_16x16x32_bf16(ap[i], bones, dacc[i], 0,0,0);
      #pragma unroll
      for(int cb=0;cb<8;cb++)
        nacc[i][cb] = __builtin_amdgcn_mfma_f32_16x16x32_bf16(ap[i], bv[cb], nacc[i][cb], 0,0,0);
    }
  }
  __syncthreads();
  stage_tr(bs, kvb, 128, t);
  __syncthreads();
  // num += qp @ kv_excl ; den += qp @ ksum_excl
  #pragma unroll
  for(int ms=0;ms<4;ms++){
    bf16x8 bkv[8];
    #pragma unroll
    for(int cb=0;cb<8;cb++) bkv[cb] = ldfrag(bs, cb*16+fr, ms*32+kc*8);
    bf16x8 bks;
    #pragma unroll
    for(int e=0;e<8;e++) bks[e] = (fr==0) ? (__bf16)ksum_s[ms*32+kc*8+e] : (__bf16)0.0f;
    #pragma unroll
    for(int i=0;i<2;i++){
      dacc[i] = __builtin_amdgcn_mfma_f32_16x16x32_bf16(aq[i][ms], bks, dacc[i], 0,0,0);
      #pragma unroll
      for(int cb=0;cb<8;cb++)
        nacc[i][cb] = __builtin_amdgcn_mfma_f32_16x16x32_bf16(aq[i][ms], bkv[cb], nacc[i][cb], 0,0,0);
    }
  }
  // epilogue: den broadcast per row via shfl, divide, store
  #pragma unroll
  for(int i=0;i<2;i++){
    #pragma unroll
    for(int r=0;r<4;r++){
      float den = __shfl(dacc[i][r], lane & 48, 64);
      float inv = 1.0f/(den + 1e-6f);
      int row = w*32 + i*16 + kc*4 + r;
      float* ob = o + (size_t)((b*Ss+s0+row)*Hh + hh)*128;
      #pragma unroll
      for(int cb=0;cb<8;cb++)
        ob[cb*16 + fr] = nacc[i][cb][r] * inv;
    }
  }
}

// ------------- pooling: partial sums over S (64 blocks) -------------------
__global__ __launch_bounds__(256) void k_pool(const float* __restrict__ h,
    float* __restrict__ pw){
  __shared__ float part[256];
  int blk = blockIdx.x; int b = blk>>4, c = blk&15;
  int t = threadIdx.x; int half = t>>7;
  float s = 0.f;
  int s0 = c*128 + half*64;
  for(int si=s0; si<s0+64; ++si) s += h[(b*Ss+si)*128 + (t&127)];
  part[t] = s;
  __syncthreads();
  if(t<128) pw[blk*128 + t] = part[t] + part[t+128];
}

// ------------- classifier ------------------------------------------------
__global__ __launch_bounds__(128) void k_cls(const float* __restrict__ pw,
    const float* __restrict__ fw, const float* __restrict__ fb,
    float* __restrict__ out){
  __shared__ float pool_s[128];
  int b = blockIdx.x; int t = threadIdx.x;
  float s = 0.f;
  for(int c=0;c<16;c++) s += pw[(b*16+c)*128 + t];
  pool_s[t] = s * (1.0f/2048.0f);
  __syncthreads();
  if(t<10){
    float a = fb[t];
    for(int d=0; d<128; ++d) a += pool_s[d]*fw[d*10+t];
    out[b*10+t] = a;
  }
}

extern "C" void kernel_launch(void* const* d_in, const int* in_sizes, int n_in,
                              void* d_out, int out_size, void* d_ws, size_t ws_size,
                              hipStream_t stream){
  (void)in_sizes; (void)n_in; (void)out_size; (void)ws_size;
  const float* x     = (const float*)d_in[0];
  const float* lin_w = (const float*)d_in[1];
  const float* lin_b = (const float*)d_in[2];
  const float* pe    = (const float*)d_in[3];
  const float* proj  = (const float*)d_in[4];
  const float* ln1_g = (const float*)d_in[5];
  const float* ln1_b = (const float*)d_in[6];
  const float* wq    = (const float*)d_in[7];
  const float* wk    = (const float*)d_in[8];
  const float* wv    = (const float*)d_in[9];
  const float* wo    = (const float*)d_in[10];
  const float* wo_b  = (const float*)d_in[11];
  const float* ln2_g = (const float*)d_in[12];
  const float* ln2_b = (const float*)d_in[13];
  const float* ff1w  = (const float*)d_in[14];
  const float* ff1b  = (const float*)d_in[15];
  const float* ff2w  = (const float*)d_in[16];
  const float* ff2b  = (const float*)d_in[17];
  const float* finw  = (const float*)d_in[18];
  const float* finb  = (const float*)d_in[19];
  float* out = (float*)d_out;

  float* ws  = (float*)d_ws;
  float* h   = ws;              // [8192][128]
  float* y   = h  + 1048576;    // [8192][128]
  float* q   = y  + 1048576;    // [8192][1024]  (also FF intermediate)
  float* k   = q  + 8388608;
  float* v   = k  + 8388608;
  float* o   = v  + 8388608;
  float* kvc = o  + 8388608;    // [32][16][128][128]
  float* ksc = kvc + 8388608;   // [32][16][128]
  float* pw  = ksc + 65536;     // [4][16][128]
  unsigned* kstab = (unsigned*)(pw + 8192);  // [DEPTH][32]

  k_init<<<1,64,0,stream>>>(kstab);
  k_embed<<<4096,256,0,stream>>>(x, lin_w, lin_b, pe, h);
  for(int l=0;l<2;l++){
    const float* projl = proj + l*Mf*DHc;
    k_ln<<<2048,256,0,stream>>>(h, ln1_g + l*DIMc, ln1_b + l*DIMc, y);
    k_gemm_mfma<false,false,false><<<dim3(16,128),256,0,stream>>>(y, wq + l*DIMc*INNERc, nullptr, nullptr, q, INNERc, DIMc);
    k_gemm_mfma<false,false,false><<<dim3(16,128),256,0,stream>>>(y, wk + l*DIMc*INNERc, nullptr, nullptr, k, INNERc, DIMc);
    k_gemm_mfma<false,false,false><<<dim3(16,128),256,0,stream>>>(y, wv + l*DIMc*INNERc, nullptr, nullptr, v, INNERc, DIMc);
    k_qfeat<<<1024,256,0,stream>>>(q, projl);
    k_kfeatA<<<1024,256,0,stream>>>(k, projl, kstab + l*32);
    k_kfeatB<<<8192,256,0,stream>>>(k, kstab + l*32);
    k_attn1m<<<512,256,0,stream>>>(k, v, kvc, ksc);
    k_prefix<<<2048,256,0,stream>>>(kvc);
    k_prefix_ks<<<16,256,0,stream>>>(ksc);
    k_attn2m<<<512,256,0,stream>>>(q, k, v, kvc, ksc, o);
    k_gemm_mfma<true,false,true><<<dim3(2,128),256,0,stream>>>(o, wo + l*INNERc*DIMc, wo_b + l*DIMc, h, h, DIMc, INNERc);
    k_ln<<<2048,256,0,stream>>>(h, ln2_g + l*DIMc, ln2_b + l*DIMc, y);
    k_gemm_mfma<true,true,false><<<dim3(8,128),256,0,stream>>>(y, ff1w + l*DIMc*FFc, ff1b + l*FFc, nullptr, q, FFc, DIMc);
    k_gemm_mfma<true,false,true><<<dim3(2,128),256,0,stream>>>(q, ff2w + l*FFc*DIMc, ff2b + l*DIMc, h, h, DIMc, FFc);
  }
  k_pool<<<64,256,0,stream>>>(h, pw);
  k_cls<<<4,128,0,stream>>>(pw, finw, finb, out);
}

// Round 5
// 562.899 us; speedup vs baseline: 2.8078x; 1.2778x over previous
//
#include <hip/hip_runtime.h>
#include <hip/hip_bf16.h>

// Problem constants
#define Bb 4
#define Ss 2048
#define DIMc 128
#define Hh 8
#define DHc 128
#define Mf 128
#define CH 128
#define NCc 16         // S / CHUNK
#define INNERc 1024    // H*DH
#define FFc 512

union F4 { float4 v; float f[4]; };
typedef unsigned short u16;

typedef __bf16 bf16x8 __attribute__((ext_vector_type(8)));
typedef float  f32x4  __attribute__((ext_vector_type(4)));

__device__ __forceinline__ unsigned fkey(float f){
  unsigned b = __float_as_uint(f);
  return (b & 0x80000000u) ? ~b : (b | 0x80000000u);
}
__device__ __forceinline__ float funkey(unsigned u){
  unsigned b = (u & 0x80000000u) ? (u & 0x7fffffffu) : ~u;
  return __uint_as_float(b);
}
__device__ __forceinline__ float gelu_f(float x){
  return 0.5f*x*(1.0f + tanhf(0.7978845608028654f*(x + 0.044715f*x*x*x)));
}
// f32 -> bf16 (RNE) raw
__device__ __forceinline__ u16 f2bu(float f){
  unsigned u = __float_as_uint(f);
  return (u16)((u + 0x7fffu + ((u>>16)&1u)) >> 16);
}
__device__ __forceinline__ float b2f(u16 u){
  return __uint_as_float(((unsigned)u)<<16);
}

// ---- swizzled bf16 LDS tile: [128][128] bf16 (32KB), byte = row*256+e*2,
// XOR ((row&7)<<4)  (G4 bank-conflict fix) ----
__device__ __forceinline__ bf16x8 ldfrag(const u16* base, int row, int e){
  int byte = (row*256 + e*2) ^ ((row&7)<<4);
  return *(const bf16x8*)((const char*)base + byte);
}
// stage bf16 row-major [128 x 128] (row stride srs elems) -> swizzled tile
__device__ __forceinline__ void stage_lin_bf(u16* dst, const u16* src, int srs, int t){
  #pragma unroll
  for(int it=0; it<8; ++it){
    int idx = t + it*256; int r = idx>>4, c8 = idx&15;
    int byte = (r*256 + c8*16) ^ ((r&7)<<4);
    *(uint4*)((char*)dst + byte) = *(const uint4*)(src + r*srs + c8*8);
  }
}
// stage TRANSPOSED from bf16 source: dst[d][j] = src[j][d]
__device__ __forceinline__ void stage_tr_bf(u16* dst, const u16* src, int srs, int t){
  int j0 = (t & 63)*2; int wv = t>>6;
  #pragma unroll
  for(int it=0; it<2; ++it){
    int d0 = wv*16 + it*64;
    u16 a0[16], a1[16];
    *(uint4*)&a0[0] = *(const uint4*)(src + j0*srs + d0);
    *(uint4*)&a0[8] = *(const uint4*)(src + j0*srs + d0 + 8);
    *(uint4*)&a1[0] = *(const uint4*)(src + (j0+1)*srs + d0);
    *(uint4*)&a1[8] = *(const uint4*)(src + (j0+1)*srs + d0 + 8);
    #pragma unroll
    for(int dc=0; dc<16; ++dc){
      int d = d0 + dc;
      unsigned pk = (unsigned)a0[dc] | ((unsigned)a1[dc]<<16);
      int byte = (d*256 + j0*2) ^ ((d&7)<<4);
      *(unsigned*)((char*)dst + byte) = pk;
    }
  }
}
// stage TRANSPOSED from fp32 source (for kvc)
__device__ __forceinline__ void stage_tr_f32(u16* dst, const float* src, int srs, int t){
  int j0 = (t & 63)*2; int wv = t>>6;
  #pragma unroll
  for(int it=0; it<2; ++it){
    int d0 = wv*16 + it*64;
    F4 r0[4], r1[4];
    #pragma unroll
    for(int u=0;u<4;u++){
      r0[u].v = *(const float4*)(src + j0*srs     + d0 + u*4);
      r1[u].v = *(const float4*)(src + (j0+1)*srs + d0 + u*4);
    }
    #pragma unroll
    for(int dc=0; dc<16; ++dc){
      int d = d0 + dc;
      unsigned pk = (unsigned)f2bu(r0[dc>>2].f[dc&3]) |
                    ((unsigned)f2bu(r1[dc>>2].f[dc&3])<<16);
      int byte = (d*256 + j0*2) ^ ((d&7)<<4);
      *(unsigned*)((char*)dst + byte) = pk;
    }
  }
}

// bijective XCD-aware tile swizzle: returns (tile_n, tile_m)
__device__ __forceinline__ int2 swz_tile(){
  int nx = gridDim.x;
  int nwg = gridDim.x*gridDim.y;
  int lin = blockIdx.y*nx + blockIdx.x;
  int q = nwg>>3, r = nwg&7;
  int xcd = lin&7, idx = lin>>3;
  int nl = (xcd<r) ? (xcd*(q+1)+idx) : (r*(q+1)+(xcd-r)*q+idx);
  return make_int2(nl % nx, nl / nx);
}

// ---------------- init ----------------
__global__ __launch_bounds__(64) void k_init(unsigned* kstab){
  if(threadIdx.x < 64) kstab[threadIdx.x] = 0u;
}

// ---------------- embedding ----------------
__global__ __launch_bounds__(256) void k_embed(const float* __restrict__ x,
    const float* __restrict__ lw, const float* __restrict__ lb,
    const float* __restrict__ pe, float* __restrict__ h){
  int idx = blockIdx.x*256 + threadIdx.x;
  int d = idx & 127; int bs = idx >> 7; int s = bs & (Ss-1);
  h[idx] = x[bs]*lw[d] + lb[d] + pe[s*DIMc + d];
}

// ---------------- layernorm: fp32 in -> bf16 out ----------------
__global__ __launch_bounds__(256) void k_ln(const float* __restrict__ in,
    const float* __restrict__ g, const float* __restrict__ bta,
    u16* __restrict__ out){
  int wave = threadIdx.x >> 6; int lane = threadIdx.x & 63;
  int row = blockIdx.x*4 + wave;
  const float* r = in + row*DIMc;
  float x1 = r[lane], x2 = r[lane+64];
  float s = x1+x2, sq = x1*x1 + x2*x2;
  #pragma unroll
  for(int m=1;m<64;m<<=1){ s += __shfl_xor(s,m,64); sq += __shfl_xor(sq,m,64); }
  float mu = s * (1.0f/128.0f);
  float var = sq*(1.0f/128.0f) - mu*mu;
  float rs = rsqrtf(var + 1e-5f);
  out[row*DIMc+lane]    = f2bu((x1-mu)*rs*g[lane]+bta[lane]);
  out[row*DIMc+lane+64] = f2bu((x2-mu)*rs*g[lane+64]+bta[lane+64]);
}

// ------------ bf16-A MFMA GEMM: C = [resid +] act(A@B + bias) ------------
// A bf16 [M][K], B fp32 [K][N] (weights), C bf16 or fp32. 64x64 tile.
template<bool BIAS, bool GELU, bool RES, bool OBF>
__global__ __launch_bounds__(256) void k_gemm_bf(const u16* __restrict__ A,
    const float* __restrict__ Bw, const float* __restrict__ bias,
    const float* __restrict__ resid, void* __restrict__ Cp, int N, int K){
  __shared__ u16 As[64][40];
  __shared__ u16 Bs[64][40];
  int2 tt = swz_tile();
  int n0 = tt.x*64, m0 = tt.y*64;
  int t = threadIdx.x; int wid = t>>6, lane = t&63;
  int wr = wid>>1, wc = wid&1;
  int fr = lane&15, kc = lane>>4;
  f32x4 acc[2][2] = {};
  for(int k0=0; k0<K; k0+=32){
    { // A: 64 rows x 32 k bf16, one uint4 per thread
      int r = t>>2, c8 = t&3;
      *(uint4*)&As[r][c8*8] = *(const uint4*)(A + (m0+r)*K + k0 + c8*8);
    }
    { // B: 32 k x 64 n fp32 -> Bs[n][k]
      int n = t&63, c8 = t>>6;
      u16 tmp[8];
      #pragma unroll
      for(int j=0;j<8;j++) tmp[j] = f2bu(Bw[(k0 + c8*8 + j)*N + n0 + n]);
      *(uint4*)&Bs[n][c8*8] = *(uint4*)tmp;
    }
    __syncthreads();
    bf16x8 af[2], bf[2];
    #pragma unroll
    for(int i=0;i<2;i++) af[i] = *(const bf16x8*)&As[wr*32 + i*16 + fr][kc*8];
    #pragma unroll
    for(int j=0;j<2;j++) bf[j] = *(const bf16x8*)&Bs[wc*32 + j*16 + fr][kc*8];
    #pragma unroll
    for(int i=0;i<2;i++)
      #pragma unroll
      for(int j=0;j<2;j++)
        acc[i][j] = __builtin_amdgcn_mfma_f32_16x16x32_bf16(af[i], bf[j], acc[i][j], 0, 0, 0);
    __syncthreads();
  }
  #pragma unroll
  for(int i=0;i<2;i++){
    #pragma unroll
    for(int r=0;r<4;r++){
      int row = m0 + wr*32 + i*16 + kc*4 + r;
      #pragma unroll
      for(int j=0;j<2;j++){
        int col = n0 + wc*32 + j*16 + fr;
        float val = acc[i][j][r];
        if(BIAS) val += bias[col];
        if(GELU) val = gelu_f(val);
        if(RES)  val += resid[row*N+col];
        if(OBF) ((u16*)Cp)[row*N+col] = f2bu(val);
        else    ((float*)Cp)[row*N+col] = val;
      }
    }
  }
}

// ------------- FAVOR+ query features: q bf16 -> qp bf16 (in place) -------
__global__ __launch_bounds__(256) void k_qfeat(u16* __restrict__ q,
    const float* __restrict__ proj){
  __shared__ float x_s[64][36];
  __shared__ float p_s[32][132];
  __shared__ float diag_s[64];
  int r0 = blockIdx.x*64;
  int t = threadIdx.x; int ti = t>>4, tj = t&15;
  const float norm  = 0.29730177875068026f;   // 128^-0.25
  const float ratio = 0.08838834764831845f;   // 128^-0.5
  { // diag pre-pass: 4 threads per row, 32 elems each
    int r = t>>2, qt = t&3;
    const u16* rp = q + (r0+r)*128 + qt*32;
    float ss = 0.f;
    #pragma unroll
    for(int u4=0; u4<4; ++u4){
      u16 tmp[8]; *(uint4*)tmp = *(const uint4*)(rp + u4*8);
      #pragma unroll
      for(int u=0;u<8;u++){ float f = b2f(tmp[u]); ss += f*f; }
    }
    ss *= norm*norm;
    ss += __shfl_xor(ss,1,64); ss += __shfl_xor(ss,2,64);
    if(qt==0) diag_s[r] = 0.5f*ss;
  }
  float dd[4][8] = {};
  for(int ds=0; ds<4; ++ds){
    { // stage 64x32 q slice (scaled by norm)
      int r = t>>2, c8 = t&3;
      u16 tmp[8]; *(uint4*)tmp = *(const uint4*)(q + (r0+r)*128 + ds*32 + c8*8);
      float fv[8];
      #pragma unroll
      for(int u=0;u<8;u++) fv[u] = b2f(tmp[u])*norm;
      *(float4*)&x_s[r][c8*8]   = make_float4(fv[0],fv[1],fv[2],fv[3]);
      *(float4*)&x_s[r][c8*8+4] = make_float4(fv[4],fv[5],fv[6],fv[7]);
    }
    #pragma unroll
    for(int it=0; it<4; ++it){  // stage proj^T slice p_s[d][m]
      int idx = t + it*256; int m = idx>>3, dc4 = idx&7;
      F4 v4; v4.v = *(const float4*)(proj + m*128 + ds*32 + dc4*4);
      p_s[dc4*4+0][m]=v4.f[0]; p_s[dc4*4+1][m]=v4.f[1];
      p_s[dc4*4+2][m]=v4.f[2]; p_s[dc4*4+3][m]=v4.f[3];
    }
    __syncthreads();
    #pragma unroll
    for(int d4=0;d4<8;d4++){
      F4 a[4];
      #pragma unroll
      for(int r=0;r<4;r++) a[r].v = *(const float4*)&x_s[ti*4+r][d4*4];
      #pragma unroll
      for(int dj=0;dj<4;dj++){
        F4 p0,p1;
        p0.v = *(const float4*)&p_s[d4*4+dj][tj*8];
        p1.v = *(const float4*)&p_s[d4*4+dj][tj*8+4];
        #pragma unroll
        for(int r=0;r<4;r++){
          float av = a[r].f[dj];
          dd[r][0]+=av*p0.f[0]; dd[r][1]+=av*p0.f[1]; dd[r][2]+=av*p0.f[2]; dd[r][3]+=av*p0.f[3];
          dd[r][4]+=av*p1.f[0]; dd[r][5]+=av*p1.f[1]; dd[r][6]+=av*p1.f[2]; dd[r][7]+=av*p1.f[3];
        }
      }
    }
    __syncthreads();
  }
  #pragma unroll
  for(int r=0;r<4;r++){
    float m8 = dd[r][0];
    #pragma unroll
    for(int mm=1;mm<8;mm++) m8 = fmaxf(m8, dd[r][mm]);
    #pragma unroll
    for(int msk=1;msk<16;msk<<=1) m8 = fmaxf(m8, __shfl_xor(m8, msk, 64));
    float dg = diag_s[ti*4+r];
    int row = r0 + ti*4 + r;
    u16 ob[8];
    #pragma unroll
    for(int mm=0;mm<8;mm++) ob[mm] = f2bu(ratio*(expf(dd[r][mm]-dg-m8) + 1e-4f));
    *(uint4*)(q + row*128 + tj*8) = *(uint4*)ob;
  }
}

// ------------- key features pass A: k bf16 -> t fp32 (ktmp), track max ----
__global__ __launch_bounds__(256) void k_kfeatA(const u16* __restrict__ k,
    float* __restrict__ ktmp, const float* __restrict__ proj,
    unsigned* __restrict__ kstab){
  __shared__ float x_s[64][36];
  __shared__ float p_s[32][132];
  __shared__ float diag_s[64];
  __shared__ unsigned hmax[8];
  int r0 = blockIdx.x*64;
  int t = threadIdx.x; int ti = t>>4, tj = t&15;
  const float norm = 0.29730177875068026f;
  if(t<8) hmax[t] = 0u;
  {
    int r = t>>2, qt = t&3;
    const u16* rp = k + (r0+r)*128 + qt*32;
    float ss = 0.f;
    #pragma unroll
    for(int u4=0; u4<4; ++u4){
      u16 tmp[8]; *(uint4*)tmp = *(const uint4*)(rp + u4*8);
      #pragma unroll
      for(int u=0;u<8;u++){ float f = b2f(tmp[u]); ss += f*f; }
    }
    ss *= norm*norm;
    ss += __shfl_xor(ss,1,64); ss += __shfl_xor(ss,2,64);
    if(qt==0) diag_s[r] = 0.5f*ss;
  }
  float dd[4][8] = {};
  for(int ds=0; ds<4; ++ds){
    {
      int r = t>>2, c8 = t&3;
      u16 tmp[8]; *(uint4*)tmp = *(const uint4*)(k + (r0+r)*128 + ds*32 + c8*8);
      float fv[8];
      #pragma unroll
      for(int u=0;u<8;u++) fv[u] = b2f(tmp[u])*norm;
      *(float4*)&x_s[r][c8*8]   = make_float4(fv[0],fv[1],fv[2],fv[3]);
      *(float4*)&x_s[r][c8*8+4] = make_float4(fv[4],fv[5],fv[6],fv[7]);
    }
    #pragma unroll
    for(int it=0; it<4; ++it){
      int idx = t + it*256; int m = idx>>3, dc4 = idx&7;
      F4 v4; v4.v = *(const float4*)(proj + m*128 + ds*32 + dc4*4);
      p_s[dc4*4+0][m]=v4.f[0]; p_s[dc4*4+1][m]=v4.f[1];
      p_s[dc4*4+2][m]=v4.f[2]; p_s[dc4*4+3][m]=v4.f[3];
    }
    __syncthreads();
    #pragma unroll
    for(int d4=0;d4<8;d4++){
      F4 a[4];
      #pragma unroll
      for(int r=0;r<4;r++) a[r].v = *(const float4*)&x_s[ti*4+r][d4*4];
      #pragma unroll
      for(int dj=0;dj<4;dj++){
        F4 p0,p1;
        p0.v = *(const float4*)&p_s[d4*4+dj][tj*8];
        p1.v = *(const float4*)&p_s[d4*4+dj][tj*8+4];
        #pragma unroll
        for(int r=0;r<4;r++){
          float av = a[r].f[dj];
          dd[r][0]+=av*p0.f[0]; dd[r][1]+=av*p0.f[1]; dd[r][2]+=av*p0.f[2]; dd[r][3]+=av*p0.f[3];
          dd[r][4]+=av*p1.f[0]; dd[r][5]+=av*p1.f[1]; dd[r][6]+=av*p1.f[2]; dd[r][7]+=av*p1.f[3];
        }
      }
    }
    __syncthreads();
  }
  #pragma unroll
  for(int r=0;r<4;r++){
    float m8 = dd[r][0];
    #pragma unroll
    for(int mm=1;mm<8;mm++) m8 = fmaxf(m8, dd[r][mm]);
    #pragma unroll
    for(int msk=1;msk<16;msk<<=1) m8 = fmaxf(m8, __shfl_xor(m8, msk, 64));
    int row = r0 + ti*4 + r;
    if(tj==0) atomicMax(&hmax[row & 7], fkey(m8));
    float dg = diag_s[ti*4+r];
    float o_[8];
    #pragma unroll
    for(int mm=0;mm<8;mm++) o_[mm] = dd[r][mm]-dg;
    *(float4*)(ktmp + row*128 + tj*8)   = make_float4(o_[0],o_[1],o_[2],o_[3]);
    *(float4*)(ktmp + row*128 + tj*8+4) = make_float4(o_[4],o_[5],o_[6],o_[7]);
  }
  __syncthreads();
  int b = r0 >> 14;
  if(t<8) atomicMax(&kstab[b*8 + t], hmax[t]);
}

// ------------- key features pass B: kp = ratio*(exp(t - stab)+eps) --------
__global__ __launch_bounds__(256) void k_kfeatB(const float* __restrict__ ktmp,
    u16* __restrict__ kp, const unsigned* __restrict__ kstab){
  const float ratio = 0.08838834764831845f;
  int idx8 = blockIdx.x*256 + threadIdx.x;   // 8 elems/thread, grid 4096
  int e = idx8*8;
  int row = e >> 7; int bh = ((row>>14)<<3) | (row & 7);
  float stab = funkey(kstab[bh]);
  F4 v0, v1;
  v0.v = *(const float4*)(ktmp+e);
  v1.v = *(const float4*)(ktmp+e+4);
  u16 ob[8];
  #pragma unroll
  for(int u=0;u<4;u++) ob[u]   = f2bu(ratio*(expf(v0.f[u] - stab)+1e-4f));
  #pragma unroll
  for(int u=0;u<4;u++) ob[4+u] = f2bu(ratio*(expf(v1.f[u] - stab)+1e-4f));
  *(uint4*)(kp+e) = *(uint4*)ob;
}

// ------------- attention phase 1 (MFMA): kv = k^T v, ksum = sum k ---------
__global__ __launch_bounds__(256) void k_attn1m(const u16* __restrict__ kp,
    const u16* __restrict__ v, float* __restrict__ kvc, float* __restrict__ ksc){
  __shared__ __align__(16) u16 kt[16384];
  __shared__ __align__(16) u16 vt[16384];
  int bc = blockIdx.x; int c = bc&15, bh = bc>>4, b = bh>>3, hh = bh&7;
  int t = threadIdx.x; int lane = t&63, w = t>>6;
  int fr = lane&15, kc = lane>>4;
  int s0 = c*128;
  const u16* kb = kp + (size_t)((b*Ss+s0)*Hh + hh)*128;
  const u16* vb = v  + (size_t)((b*Ss+s0)*Hh + hh)*128;
  stage_tr_bf(kt, kb, 1024, t);
  stage_tr_bf(vt, vb, 1024, t);
  __syncthreads();
  f32x4 acc[2][8] = {};
  f32x4 ks[2] = {};
  bf16x8 bones;
  #pragma unroll
  for(int e=0;e<8;e++) bones[e] = (fr==0) ? (__bf16)1.0f : (__bf16)0.0f;
  #pragma unroll
  for(int js=0;js<4;js++){
    bf16x8 am[2];
    #pragma unroll
    for(int i=0;i<2;i++) am[i] = ldfrag(kt, w*32+i*16+fr, js*32+kc*8);
    bf16x8 bv[8];
    #pragma unroll
    for(int cb=0;cb<8;cb++) bv[cb] = ldfrag(vt, cb*16+fr, js*32+kc*8);
    #pragma unroll
    for(int i=0;i<2;i++){
      ks[i] = __builtin_amdgcn_mfma_f32_16x16x32_bf16(am[i], bones, ks[i], 0,0,0);
      #pragma unroll
      for(int cb=0;cb<8;cb++)
        acc[i][cb] = __builtin_amdgcn_mfma_f32_16x16x32_bf16(am[i], bv[cb], acc[i][cb], 0,0,0);
    }
  }
  float* kvb = kvc + (size_t)bc*16384;
  #pragma unroll
  for(int i=0;i<2;i++){
    #pragma unroll
    for(int r=0;r<4;r++){
      int m = w*32 + i*16 + kc*4 + r;
      #pragma unroll
      for(int cb=0;cb<8;cb++) kvb[m*128 + cb*16 + fr] = acc[i][cb][r];
      if(fr==0) ksc[bc*128 + m] = ks[i][r];
    }
  }
}

// ------------- phase 1.5: element-parallel exclusive prefix over chunks ---
__global__ __launch_bounds__(256) void k_prefix(float* __restrict__ kvc){
  int bh = blockIdx.x >> 6; int pos = (blockIdx.x & 63)*256 + threadIdx.x;
  int base = bh*16*16384 + pos;
  float a = 0.f;
  #pragma unroll
  for(int c=0;c<16;c++){
    float xv = kvc[base + c*16384];
    kvc[base + c*16384] = a;
    a += xv;
  }
}
__global__ __launch_bounds__(256) void k_prefix_ks(float* __restrict__ ksc){
  int e = blockIdx.x*256 + threadIdx.x;
  int bh = e>>7, m = e&127;
  float a = 0.f;
  #pragma unroll
  for(int c=0;c<16;c++){
    int idx = (bh*16+c)*128 + m;
    float xv = ksc[idx]; ksc[idx] = a; a += xv;
  }
}

// ------------- attention phase 2 (MFMA): per-chunk output ----------------
__global__ __launch_bounds__(256) void k_attn2m(const u16* __restrict__ qp,
    const u16* __restrict__ kp, const u16* __restrict__ v,
    const float* __restrict__ kvc, const float* __restrict__ ksc,
    u16* __restrict__ o){
  __shared__ __align__(16) u16 qs[16384];  // qp -> P
  __shared__ __align__(16) u16 bs[16384];  // kp -> v^T -> kv^T
  __shared__ float ksum_s[128];
  int bc = blockIdx.x; int c = bc&15, bh = bc>>4, b = bh>>3, hh = bh&7;
  int t = threadIdx.x; int lane = t&63, w = t>>6;
  int fr = lane&15, kc = lane>>4;
  int s0 = c*128;
  const u16* qb = qp + (size_t)((b*Ss+s0)*Hh + hh)*128;
  const u16* kb = kp + (size_t)((b*Ss+s0)*Hh + hh)*128;
  const u16* vb = v  + (size_t)((b*Ss+s0)*Hh + hh)*128;
  const float* kvb = kvc + (size_t)bc*16384;
  stage_lin_bf(qs, qb, 1024, t);
  stage_lin_bf(bs, kb, 1024, t);
  if(t<128) ksum_s[t] = ksc[bc*128 + t];
  __syncthreads();
  bf16x8 aq[2][4];
  #pragma unroll
  for(int i=0;i<2;i++)
    #pragma unroll
    for(int ks=0;ks<4;ks++)
      aq[i][ks] = ldfrag(qs, w*32+i*16+fr, ks*32+kc*8);
  // S = qp @ kp^T
  f32x4 sacc[2][8] = {};
  #pragma unroll
  for(int ks=0;ks<4;ks++){
    bf16x8 bk[8];
    #pragma unroll
    for(int cb=0;cb<8;cb++) bk[cb] = ldfrag(bs, cb*16+fr, ks*32+kc*8);
    #pragma unroll
    for(int i=0;i<2;i++)
      #pragma unroll
      for(int cb=0;cb<8;cb++)
        sacc[i][cb] = __builtin_amdgcn_mfma_f32_16x16x32_bf16(aq[i][ks], bk[cb], sacc[i][cb], 0,0,0);
  }
  __syncthreads();
  // masked P -> qs (bf16); stage v^T -> bs
  #pragma unroll
  for(int i=0;i<2;i++){
    #pragma unroll
    for(int cb=0;cb<8;cb++){
      #pragma unroll
      for(int r=0;r<4;r++){
        int prow = w*32 + i*16 + kc*4 + r;
        int pcol = cb*16 + fr;
        float pv = (pcol > prow) ? 0.f : sacc[i][cb][r];
        int byte = (prow*256 + pcol*2) ^ ((prow&7)<<4);
        *(u16*)((char*)qs + byte) = f2bu(pv);
      }
    }
  }
  stage_tr_bf(bs, vb, 1024, t);
  __syncthreads();
  // num = P @ v ; den = P @ ones
  f32x4 nacc[2][8] = {};
  f32x4 dacc[2] = {};
  bf16x8 bones;
  #pragma unroll
  for(int e=0;e<8;e++) bones[e] = (fr==0) ? (__bf16)1.0f : (__bf16)0.0f;
  #pragma unroll
  for(int js=0;js<4;js++){
    bf16x8 ap[2];
    #pragma unroll
    for(int i=0;i<2;i++) ap[i] = ldfrag(qs, w*32+i*16+fr, js*32+kc*8);
    bf16x8 bv[8];
    #pragma unroll
    for(int cb=0;cb<8;cb++) bv[cb] = ldfrag(bs, cb*16+fr, js*32+kc*8);
    #pragma unroll
    for(int i=0;i<2;i++){
      dacc[i] = __builtin_amdgcn_mfma_f32_16x16x32_bf16(ap[i], bones, dacc[i], 0,0,0);
      #pragma unroll
      for(int cb=0;cb<8;cb++)
        nacc[i][cb] = __builtin_amdgcn_mfma_f32_16x16x32_bf16(ap[i], bv[cb], nacc[i][cb], 0,0,0);
    }
  }
  __syncthreads();
  stage_tr_f32(bs, kvb, 128, t);
  __syncthreads();
  // num += qp @ kv_excl ; den += qp @ ksum_excl
  #pragma unroll
  for(int ms=0;ms<4;ms++){
    bf16x8 bkv[8];
    #pragma unroll
    for(int cb=0;cb<8;cb++) bkv[cb] = ldfrag(bs, cb*16+fr, ms*32+kc*8);
    bf16x8 bks;
    #pragma unroll
    for(int e=0;e<8;e++) bks[e] = (fr==0) ? (__bf16)ksum_s[ms*32+kc*8+e] : (__bf16)0.0f;
    #pragma unroll
    for(int i=0;i<2;i++){
      dacc[i] = __builtin_amdgcn_mfma_f32_16x16x32_bf16(aq[i][ms], bks, dacc[i], 0,0,0);
      #pragma unroll
      for(int cb=0;cb<8;cb++)
        nacc[i][cb] = __builtin_amdgcn_mfma_f32_16x16x32_bf16(aq[i][ms], bkv[cb], nacc[i][cb], 0,0,0);
    }
  }
  #pragma unroll
  for(int i=0;i<2;i++){
    #pragma unroll
    for(int r=0;r<4;r++){
      float den = __shfl(dacc[i][r], lane & 48, 64);
      float inv = 1.0f/(den + 1e-6f);
      int row = w*32 + i*16 + kc*4 + r;
      u16* ob = o + (size_t)((b*Ss+s0+row)*Hh + hh)*128;
      #pragma unroll
      for(int cb=0;cb<8;cb++)
        ob[cb*16 + fr] = f2bu(nacc[i][cb][r] * inv);
    }
  }
}

// ------------- pooling + classifier --------------------------------------
__global__ __launch_bounds__(256) void k_pool(const float* __restrict__ h,
    float* __restrict__ pw){
  __shared__ float part[256];
  int blk = blockIdx.x; int b = blk>>4, c = blk&15;
  int t = threadIdx.x; int half = t>>7;
  float s = 0.f;
  int s0 = c*128 + half*64;
  for(int si=s0; si<s0+64; ++si) s += h[(b*Ss+si)*128 + (t&127)];
  part[t] = s;
  __syncthreads();
  if(t<128) pw[blk*128 + t] = part[t] + part[t+128];
}
__global__ __launch_bounds__(128) void k_cls(const float* __restrict__ pw,
    const float* __restrict__ fw, const float* __restrict__ fb,
    float* __restrict__ out){
  __shared__ float pool_s[128];
  int b = blockIdx.x; int t = threadIdx.x;
  float s = 0.f;
  for(int c=0;c<16;c++) s += pw[(b*16+c)*128 + t];
  pool_s[t] = s * (1.0f/2048.0f);
  __syncthreads();
  if(t<10){
    float a = fb[t];
    for(int d=0; d<128; ++d) a += pool_s[d]*fw[d*10+t];
    out[b*10+t] = a;
  }
}

extern "C" void kernel_launch(void* const* d_in, const int* in_sizes, int n_in,
                              void* d_out, int out_size, void* d_ws, size_t ws_size,
                              hipStream_t stream){
  (void)in_sizes; (void)n_in; (void)out_size; (void)ws_size;
  const float* x     = (const float*)d_in[0];
  const float* lin_w = (const float*)d_in[1];
  const float* lin_b = (const float*)d_in[2];
  const float* pe    = (const float*)d_in[3];
  const float* proj  = (const float*)d_in[4];
  const float* ln1_g = (const float*)d_in[5];
  const float* ln1_b = (const float*)d_in[6];
  const float* wq    = (const float*)d_in[7];
  const float* wk    = (const float*)d_in[8];
  const float* wv    = (const float*)d_in[9];
  const float* wo    = (const float*)d_in[10];
  const float* wo_b  = (const float*)d_in[11];
  const float* ln2_g = (const float*)d_in[12];
  const float* ln2_b = (const float*)d_in[13];
  const float* ff1w  = (const float*)d_in[14];
  const float* ff1b  = (const float*)d_in[15];
  const float* ff2w  = (const float*)d_in[16];
  const float* ff2b  = (const float*)d_in[17];
  const float* finw  = (const float*)d_in[18];
  const float* finb  = (const float*)d_in[19];
  float* out = (float*)d_out;

  // workspace layout (in floats; bf16 buffers use half-float slots)
  float* ws  = (float*)d_ws;
  float* h    = ws;               // fp32 [8192][128]
  u16*  y    = (u16*)(h + 1048576);               // bf16 [8192][128]
  u16*  q    = (u16*)(h + 1048576 + 524288);      // bf16 [8192][1024]
  u16*  k    = q + 8388608;       // bf16 [8192][1024]
  u16*  v    = k + 8388608;       // bf16
  u16*  o    = v + 8388608;       // bf16
  float* ktmp = (float*)(o + 8388608);     // fp32 [65536][128]
  float* kvc  = ktmp + 8388608;   // fp32 [32][16][128][128]
  float* ksc  = kvc + 8388608;    // fp32 [32][16][128]
  float* pw   = ksc + 65536;
  unsigned* kstab = (unsigned*)(pw + 8192);

  k_init<<<1,64,0,stream>>>(kstab);
  k_embed<<<4096,256,0,stream>>>(x, lin_w, lin_b, pe, h);
  for(int l=0;l<2;l++){
    const float* projl = proj + l*Mf*DHc;
    k_ln<<<2048,256,0,stream>>>(h, ln1_g + l*DIMc, ln1_b + l*DIMc, y);
    k_gemm_bf<false,false,false,true><<<dim3(16,128),256,0,stream>>>(y, wq + l*DIMc*INNERc, nullptr, nullptr, q, INNERc, DIMc);
    k_gemm_bf<false,false,false,true><<<dim3(16,128),256,0,stream>>>(y, wk + l*DIMc*INNERc, nullptr, nullptr, k, INNERc, DIMc);
    k_gemm_bf<false,false,false,true><<<dim3(16,128),256,0,stream>>>(y, wv + l*DIMc*INNERc, nullptr, nullptr, v, INNERc, DIMc);
    k_qfeat<<<1024,256,0,stream>>>(q, projl);
    k_kfeatA<<<1024,256,0,stream>>>(k, ktmp, projl, kstab + l*32);
    k_kfeatB<<<4096,256,0,stream>>>(ktmp, k, kstab + l*32);
    k_attn1m<<<512,256,0,stream>>>(k, v, kvc, ksc);
    k_prefix<<<2048,256,0,stream>>>(kvc);
    k_prefix_ks<<<16,256,0,stream>>>(ksc);
    k_attn2m<<<512,256,0,stream>>>(q, k, v, kvc, ksc, o);
    k_gemm_bf<true,false,true,false><<<dim3(2,128),256,0,stream>>>(o, wo + l*INNERc*DIMc, wo_b + l*DIMc, h, h, DIMc, INNERc);
    k_ln<<<2048,256,0,stream>>>(h, ln2_g + l*DIMc, ln2_b + l*DIMc, y);
    k_gemm_bf<true,true,false,true><<<dim3(8,128),256,0,stream>>>(y, ff1w + l*DIMc*FFc, ff1b + l*FFc, nullptr, q, FFc, DIMc);
    k_gemm_bf<true,false,true,false><<<dim3(2,128),256,0,stream>>>(q, ff2w + l*FFc*DIMc, ff2b + l*DIMc, h, h, DIMc, FFc);
  }
  k_pool<<<64,256,0,stream>>>(h, pw);
  k_cls<<<4,128,0,stream>>>(pw, finw, finb, out);
}

// Round 6
// 487.683 us; speedup vs baseline: 3.2409x; 1.1542x over previous
//
#include <hip/hip_runtime.h>
#include <hip/hip_bf16.h>

// Problem constants
#define Bb 4
#define Ss 2048
#define DIMc 128
#define Hh 8
#define DHc 128
#define Mf 128
#define CH 128
#define NCc 16         // S / CHUNK
#define INNERc 1024    // H*DH
#define FFc 512

union F4 { float4 v; float f[4]; };
typedef unsigned short u16;

typedef __bf16 bf16x8 __attribute__((ext_vector_type(8)));
typedef float  f32x4  __attribute__((ext_vector_type(4)));

__device__ __forceinline__ unsigned fkey(float f){
  unsigned b = __float_as_uint(f);
  return (b & 0x80000000u) ? ~b : (b | 0x80000000u);
}
__device__ __forceinline__ float funkey(unsigned u){
  unsigned b = (u & 0x80000000u) ? (u & 0x7fffffffu) : ~u;
  return __uint_as_float(b);
}
__device__ __forceinline__ float gelu_f(float x){
  return 0.5f*x*(1.0f + tanhf(0.7978845608028654f*(x + 0.044715f*x*x*x)));
}
// f32 -> bf16 (RNE) raw
__device__ __forceinline__ u16 f2bu(float f){
  unsigned u = __float_as_uint(f);
  return (u16)((u + 0x7fffu + ((u>>16)&1u)) >> 16);
}
__device__ __forceinline__ float b2f(u16 u){
  return __uint_as_float(((unsigned)u)<<16);
}

// ---- swizzled bf16 LDS tile: [128][128] bf16 (32KB), byte = row*256+e*2,
// XOR ((row&7)<<4)  (G4 bank-conflict fix) ----
__device__ __forceinline__ bf16x8 ldfrag(const u16* base, int row, int e){
  int byte = (row*256 + e*2) ^ ((row&7)<<4);
  return *(const bf16x8*)((const char*)base + byte);
}
// stage bf16 row-major [128 x 128] (row stride srs elems) -> swizzled tile
__device__ __forceinline__ void stage_lin_bf(u16* dst, const u16* src, int srs, int t){
  #pragma unroll
  for(int it=0; it<8; ++it){
    int idx = t + it*256; int r = idx>>4, c8 = idx&15;
    int byte = (r*256 + c8*16) ^ ((r&7)<<4);
    *(uint4*)((char*)dst + byte) = *(const uint4*)(src + r*srs + c8*8);
  }
}
// stage fp32 row-major [128 x 128] -> bf16 swizzled tile
__device__ __forceinline__ void stage_lin_f32(u16* dst, const float* src, int srs, int t){
  #pragma unroll
  for(int it=0; it<8; ++it){
    int idx = t + it*256; int r = idx>>4, c8 = idx&15;
    F4 v0, v1;
    v0.v = *(const float4*)(src + r*srs + c8*8);
    v1.v = *(const float4*)(src + r*srs + c8*8 + 4);
    u16 tmp[8];
    #pragma unroll
    for(int u=0;u<4;u++){ tmp[u] = f2bu(v0.f[u]); tmp[4+u] = f2bu(v1.f[u]); }
    int byte = (r*256 + c8*16) ^ ((r&7)<<4);
    *(uint4*)((char*)dst + byte) = *(uint4*)tmp;
  }
}
// stage TRANSPOSED from bf16 source: dst[d][j] = src[j][d]
__device__ __forceinline__ void stage_tr_bf(u16* dst, const u16* src, int srs, int t){
  int j0 = (t & 63)*2; int wv = t>>6;
  #pragma unroll
  for(int it=0; it<2; ++it){
    int d0 = wv*16 + it*64;
    u16 a0[16], a1[16];
    *(uint4*)&a0[0] = *(const uint4*)(src + j0*srs + d0);
    *(uint4*)&a0[8] = *(const uint4*)(src + j0*srs + d0 + 8);
    *(uint4*)&a1[0] = *(const uint4*)(src + (j0+1)*srs + d0);
    *(uint4*)&a1[8] = *(const uint4*)(src + (j0+1)*srs + d0 + 8);
    #pragma unroll
    for(int dc=0; dc<16; ++dc){
      int d = d0 + dc;
      unsigned pk = (unsigned)a0[dc] | ((unsigned)a1[dc]<<16);
      int byte = (d*256 + j0*2) ^ ((d&7)<<4);
      *(unsigned*)((char*)dst + byte) = pk;
    }
  }
}
// stage TRANSPOSED from fp32 source (for kvc)
__device__ __forceinline__ void stage_tr_f32(u16* dst, const float* src, int srs, int t){
  int j0 = (t & 63)*2; int wv = t>>6;
  #pragma unroll
  for(int it=0; it<2; ++it){
    int d0 = wv*16 + it*64;
    F4 r0[4], r1[4];
    #pragma unroll
    for(int u=0;u<4;u++){
      r0[u].v = *(const float4*)(src + j0*srs     + d0 + u*4);
      r1[u].v = *(const float4*)(src + (j0+1)*srs + d0 + u*4);
    }
    #pragma unroll
    for(int dc=0; dc<16; ++dc){
      int d = d0 + dc;
      unsigned pk = (unsigned)f2bu(r0[dc>>2].f[dc&3]) |
                    ((unsigned)f2bu(r1[dc>>2].f[dc&3])<<16);
      int byte = (d*256 + j0*2) ^ ((d&7)<<4);
      *(unsigned*)((char*)dst + byte) = pk;
    }
  }
}

// bijective XCD-aware tile swizzle: returns (tile_n, tile_m)
__device__ __forceinline__ int2 swz_tile(){
  int nx = gridDim.x;
  int nwg = gridDim.x*gridDim.y;
  int lin = blockIdx.y*nx + blockIdx.x;
  int q = nwg>>3, r = nwg&7;
  int xcd = lin&7, idx = lin>>3;
  int nl = (xcd<r) ? (xcd*(q+1)+idx) : (r*(q+1)+(xcd-r)*q+idx);
  return make_int2(nl % nx, nl / nx);
}

// ---------------- init ----------------
__global__ __launch_bounds__(64) void k_init(unsigned* kstab){
  if(threadIdx.x < 64) kstab[threadIdx.x] = 0u;
}

// ---------------- embedding ----------------
__global__ __launch_bounds__(256) void k_embed(const float* __restrict__ x,
    const float* __restrict__ lw, const float* __restrict__ lb,
    const float* __restrict__ pe, float* __restrict__ h){
  int idx = blockIdx.x*256 + threadIdx.x;
  int d = idx & 127; int bs = idx >> 7; int s = bs & (Ss-1);
  h[idx] = x[bs]*lw[d] + lb[d] + pe[s*DIMc + d];
}

// ---------------- layernorm: fp32 in -> bf16 out ----------------
__global__ __launch_bounds__(256) void k_ln(const float* __restrict__ in,
    const float* __restrict__ g, const float* __restrict__ bta,
    u16* __restrict__ out){
  int wave = threadIdx.x >> 6; int lane = threadIdx.x & 63;
  int row = blockIdx.x*4 + wave;
  const float* r = in + row*DIMc;
  float x1 = r[lane], x2 = r[lane+64];
  float s = x1+x2, sq = x1*x1 + x2*x2;
  #pragma unroll
  for(int m=1;m<64;m<<=1){ s += __shfl_xor(s,m,64); sq += __shfl_xor(sq,m,64); }
  float mu = s * (1.0f/128.0f);
  float var = sq*(1.0f/128.0f) - mu*mu;
  float rs = rsqrtf(var + 1e-5f);
  out[row*DIMc+lane]    = f2bu((x1-mu)*rs*g[lane]+bta[lane]);
  out[row*DIMc+lane+64] = f2bu((x2-mu)*rs*g[lane+64]+bta[lane+64]);
}

// ------------ bf16-A MFMA GEMM: C = [resid +] act(A@B + bias) ------------
template<bool BIAS, bool GELU, bool RES, bool OBF>
__global__ __launch_bounds__(256) void k_gemm_bf(const u16* __restrict__ A,
    const float* __restrict__ Bw, const float* __restrict__ bias,
    const float* __restrict__ resid, void* __restrict__ Cp, int N, int K){
  __shared__ u16 As[64][40];
  __shared__ u16 Bs[64][40];
  int2 tt = swz_tile();
  int n0 = tt.x*64, m0 = tt.y*64;
  int t = threadIdx.x; int wid = t>>6, lane = t&63;
  int wr = wid>>1, wc = wid&1;
  int fr = lane&15, kc = lane>>4;
  f32x4 acc[2][2] = {};
  for(int k0=0; k0<K; k0+=32){
    {
      int r = t>>2, c8 = t&3;
      *(uint4*)&As[r][c8*8] = *(const uint4*)(A + (m0+r)*K + k0 + c8*8);
    }
    {
      int n = t&63, c8 = t>>6;
      u16 tmp[8];
      #pragma unroll
      for(int j=0;j<8;j++) tmp[j] = f2bu(Bw[(k0 + c8*8 + j)*N + n0 + n]);
      *(uint4*)&Bs[n][c8*8] = *(uint4*)tmp;
    }
    __syncthreads();
    bf16x8 af[2], bf[2];
    #pragma unroll
    for(int i=0;i<2;i++) af[i] = *(const bf16x8*)&As[wr*32 + i*16 + fr][kc*8];
    #pragma unroll
    for(int j=0;j<2;j++) bf[j] = *(const bf16x8*)&Bs[wc*32 + j*16 + fr][kc*8];
    #pragma unroll
    for(int i=0;i<2;i++)
      #pragma unroll
      for(int j=0;j<2;j++)
        acc[i][j] = __builtin_amdgcn_mfma_f32_16x16x32_bf16(af[i], bf[j], acc[i][j], 0, 0, 0);
    __syncthreads();
  }
  #pragma unroll
  for(int i=0;i<2;i++){
    #pragma unroll
    for(int r=0;r<4;r++){
      int row = m0 + wr*32 + i*16 + kc*4 + r;
      #pragma unroll
      for(int j=0;j<2;j++){
        int col = n0 + wc*32 + j*16 + fr;
        float val = acc[i][j][r];
        if(BIAS) val += bias[col];
        if(GELU) val = gelu_f(val);
        if(RES)  val += resid[row*N+col];
        if(OBF) ((u16*)Cp)[row*N+col] = f2bu(val);
        else    ((float*)Cp)[row*N+col] = val;
      }
    }
  }
}

// ------------- FAVOR+ features via MFMA ----------------------------------
// view x as [65536][128] bf16 (row = (b*S+s)*H + h). 128 rows/block.
// raw = x @ proj^T (MFMA); dd = norm*raw; diag = 0.5*norm^2*sum(x^2).
// ISQ: out = ratio*(exp(dd - diag - rowmax(dd)) + eps) -> bf16 in place.
// !ISQ: ktmp = dd - diag (fp32), kstab[b*8+h] = max(dd) per (b,h).
template<bool ISQ>
__global__ __launch_bounds__(256) void k_featm(
    const u16* xin, u16* qout, float* ktmp,
    const float* __restrict__ proj, unsigned* kstab){
  __shared__ __align__(16) u16 xs[16384];
  __shared__ __align__(16) u16 ps[16384];
  __shared__ float diag_s[128];
  __shared__ unsigned hmax[8];
  int r0 = blockIdx.x*128;
  int t = threadIdx.x; int lane = t&63, w = t>>6;
  int fr = lane&15, kc = lane>>4;
  const float norm  = 0.29730177875068026f;   // 128^-0.25
  const float ratio = 0.08838834764831845f;   // 128^-0.5
  if(!ISQ && t<8) hmax[t] = 0u;
  stage_lin_bf(xs, xin + (size_t)r0*128, 128, t);
  stage_lin_f32(ps, proj, 128, t);
  { // diag: 2 threads per row, 64 elems each
    int r = t>>1, half = t&1;
    const u16* rp = xin + (size_t)(r0+r)*128 + half*64;
    float ss = 0.f;
    #pragma unroll
    for(int u4=0; u4<8; ++u4){
      u16 tmp[8]; *(uint4*)tmp = *(const uint4*)(rp + u4*8);
      #pragma unroll
      for(int u=0;u<8;u++){ float f = b2f(tmp[u]); ss += f*f; }
    }
    ss += __shfl_xor(ss, 1, 64);
    if(half==0) diag_s[r] = 0.5f*norm*norm*ss;
  }
  __syncthreads();
  f32x4 acc[2][8] = {};
  #pragma unroll
  for(int ks=0; ks<4; ++ks){
    bf16x8 a[2];
    #pragma unroll
    for(int i=0;i<2;i++) a[i] = ldfrag(xs, w*32+i*16+fr, ks*32+kc*8);
    bf16x8 bm[8];
    #pragma unroll
    for(int cb=0;cb<8;cb++) bm[cb] = ldfrag(ps, cb*16+fr, ks*32+kc*8);
    #pragma unroll
    for(int i=0;i<2;i++)
      #pragma unroll
      for(int cb=0;cb<8;cb++)
        acc[i][cb] = __builtin_amdgcn_mfma_f32_16x16x32_bf16(a[i], bm[cb], acc[i][cb], 0,0,0);
  }
  __syncthreads();   // all xs/ps reads complete before reuse
  #pragma unroll
  for(int i=0;i<2;i++){
    #pragma unroll
    for(int r=0;r<4;r++){
      int row = w*32 + i*16 + kc*4 + r;
      float rmax = acc[i][0][r];
      #pragma unroll
      for(int cb=1;cb<8;cb++) rmax = fmaxf(rmax, acc[i][cb][r]);
      #pragma unroll
      for(int msk=1;msk<16;msk<<=1) rmax = fmaxf(rmax, __shfl_xor(rmax, msk, 64));
      float dg = diag_s[row];
      if(ISQ){
        float base = -dg - norm*rmax;
        #pragma unroll
        for(int cb=0;cb<8;cb++){
          float val = ratio*(expf(fmaf(norm, acc[i][cb][r], base)) + 1e-4f);
          int byte = (row*256 + (cb*16+fr)*2) ^ ((row&7)<<4);
          *(u16*)((char*)xs + byte) = f2bu(val);
        }
      } else {
        if(fr==0) atomicMax(&hmax[row&7], fkey(norm*rmax));
        float* kb = ktmp + (size_t)(r0+row)*128;
        #pragma unroll
        for(int cb=0;cb<8;cb++)
          kb[cb*16+fr] = fmaf(norm, acc[i][cb][r], -dg);
      }
    }
  }
  __syncthreads();
  if(ISQ){
    // coalesced copy out of the restaged tile
    #pragma unroll
    for(int it=0; it<8; ++it){
      int idx = t + it*256; int r = idx>>4, c8 = idx&15;
      int byte = (r*256 + c8*16) ^ ((r&7)<<4);
      *(uint4*)(qout + (size_t)(r0+r)*128 + c8*8) = *(uint4*)((char*)xs + byte);
    }
  } else {
    int b = r0 >> 14;
    if(t<8) atomicMax(&kstab[b*8 + t], hmax[t]);
  }
}

// ------------- key features pass B: kp = ratio*(exp(t - stab)+eps) --------
__global__ __launch_bounds__(256) void k_kfeatB(const float* __restrict__ ktmp,
    u16* __restrict__ kp, const unsigned* __restrict__ kstab){
  const float ratio = 0.08838834764831845f;
  int idx8 = blockIdx.x*256 + threadIdx.x;   // 8 elems/thread, grid 4096
  int e = idx8*8;
  int row = e >> 7; int bh = ((row>>14)<<3) | (row & 7);
  float stab = funkey(kstab[bh]);
  F4 v0, v1;
  v0.v = *(const float4*)(ktmp+e);
  v1.v = *(const float4*)(ktmp+e+4);
  u16 ob[8];
  #pragma unroll
  for(int u=0;u<4;u++) ob[u]   = f2bu(ratio*(expf(v0.f[u] - stab)+1e-4f));
  #pragma unroll
  for(int u=0;u<4;u++) ob[4+u] = f2bu(ratio*(expf(v1.f[u] - stab)+1e-4f));
  *(uint4*)(kp+e) = *(uint4*)ob;
}

// ------------- attention phase 1 (MFMA): kv = k^T v, ksum = sum k ---------
__global__ __launch_bounds__(256) void k_attn1m(const u16* __restrict__ kp,
    const u16* __restrict__ v, float* __restrict__ kvc, float* __restrict__ ksc){
  __shared__ __align__(16) u16 kt[16384];
  __shared__ __align__(16) u16 vt[16384];
  int bc = blockIdx.x; int c = bc&15, bh = bc>>4, b = bh>>3, hh = bh&7;
  int t = threadIdx.x; int lane = t&63, w = t>>6;
  int fr = lane&15, kc = lane>>4;
  int s0 = c*128;
  const u16* kb = kp + (size_t)((b*Ss+s0)*Hh + hh)*128;
  const u16* vb = v  + (size_t)((b*Ss+s0)*Hh + hh)*128;
  stage_tr_bf(kt, kb, 1024, t);
  stage_tr_bf(vt, vb, 1024, t);
  __syncthreads();
  f32x4 acc[2][8] = {};
  f32x4 ks[2] = {};
  bf16x8 bones;
  #pragma unroll
  for(int e=0;e<8;e++) bones[e] = (fr==0) ? (__bf16)1.0f : (__bf16)0.0f;
  #pragma unroll
  for(int js=0;js<4;js++){
    bf16x8 am[2];
    #pragma unroll
    for(int i=0;i<2;i++) am[i] = ldfrag(kt, w*32+i*16+fr, js*32+kc*8);
    bf16x8 bv[8];
    #pragma unroll
    for(int cb=0;cb<8;cb++) bv[cb] = ldfrag(vt, cb*16+fr, js*32+kc*8);
    #pragma unroll
    for(int i=0;i<2;i++){
      ks[i] = __builtin_amdgcn_mfma_f32_16x16x32_bf16(am[i], bones, ks[i], 0,0,0);
      #pragma unroll
      for(int cb=0;cb<8;cb++)
        acc[i][cb] = __builtin_amdgcn_mfma_f32_16x16x32_bf16(am[i], bv[cb], acc[i][cb], 0,0,0);
    }
  }
  float* kvb = kvc + (size_t)bc*16384;
  #pragma unroll
  for(int i=0;i<2;i++){
    #pragma unroll
    for(int r=0;r<4;r++){
      int m = w*32 + i*16 + kc*4 + r;
      #pragma unroll
      for(int cb=0;cb<8;cb++) kvb[m*128 + cb*16 + fr] = acc[i][cb][r];
      if(fr==0) ksc[bc*128 + m] = ks[i][r];
    }
  }
}

// ------------- phase 1.5: element-parallel exclusive prefix over chunks ---
__global__ __launch_bounds__(256) void k_prefix(float* __restrict__ kvc){
  int bh = blockIdx.x >> 6; int pos = (blockIdx.x & 63)*256 + threadIdx.x;
  int base = bh*16*16384 + pos;
  float a = 0.f;
  #pragma unroll
  for(int c=0;c<16;c++){
    float xv = kvc[base + c*16384];
    kvc[base + c*16384] = a;
    a += xv;
  }
}
__global__ __launch_bounds__(256) void k_prefix_ks(float* __restrict__ ksc){
  int e = blockIdx.x*256 + threadIdx.x;
  int bh = e>>7, m = e&127;
  float a = 0.f;
  #pragma unroll
  for(int c=0;c<16;c++){
    int idx = (bh*16+c)*128 + m;
    float xv = ksc[idx]; ksc[idx] = a; a += xv;
  }
}

// ------------- attention phase 2 (MFMA): per-chunk output ----------------
__global__ __launch_bounds__(256) void k_attn2m(const u16* __restrict__ qp,
    const u16* __restrict__ kp, const u16* __restrict__ v,
    const float* __restrict__ kvc, const float* __restrict__ ksc,
    u16* __restrict__ o){
  __shared__ __align__(16) u16 qs[16384];  // qp -> P
  __shared__ __align__(16) u16 bs[16384];  // kp -> v^T -> kv^T
  __shared__ float ksum_s[128];
  int bc = blockIdx.x; int c = bc&15, bh = bc>>4, b = bh>>3, hh = bh&7;
  int t = threadIdx.x; int lane = t&63, w = t>>6;
  int fr = lane&15, kc = lane>>4;
  int s0 = c*128;
  const u16* qb = qp + (size_t)((b*Ss+s0)*Hh + hh)*128;
  const u16* kb = kp + (size_t)((b*Ss+s0)*Hh + hh)*128;
  const u16* vb = v  + (size_t)((b*Ss+s0)*Hh + hh)*128;
  const float* kvb = kvc + (size_t)bc*16384;
  stage_lin_bf(qs, qb, 1024, t);
  stage_lin_bf(bs, kb, 1024, t);
  if(t<128) ksum_s[t] = ksc[bc*128 + t];
  __syncthreads();
  bf16x8 aq[2][4];
  #pragma unroll
  for(int i=0;i<2;i++)
    #pragma unroll
    for(int ks=0;ks<4;ks++)
      aq[i][ks] = ldfrag(qs, w*32+i*16+fr, ks*32+kc*8);
  // S = qp @ kp^T
  f32x4 sacc[2][8] = {};
  #pragma unroll
  for(int ks=0;ks<4;ks++){
    bf16x8 bk[8];
    #pragma unroll
    for(int cb=0;cb<8;cb++) bk[cb] = ldfrag(bs, cb*16+fr, ks*32+kc*8);
    #pragma unroll
    for(int i=0;i<2;i++)
      #pragma unroll
      for(int cb=0;cb<8;cb++)
        sacc[i][cb] = __builtin_amdgcn_mfma_f32_16x16x32_bf16(aq[i][ks], bk[cb], sacc[i][cb], 0,0,0);
  }
  __syncthreads();
  // masked P -> qs (bf16); stage v^T -> bs
  #pragma unroll
  for(int i=0;i<2;i++){
    #pragma unroll
    for(int cb=0;cb<8;cb++){
      #pragma unroll
      for(int r=0;r<4;r++){
        int prow = w*32 + i*16 + kc*4 + r;
        int pcol = cb*16 + fr;
        float pv = (pcol > prow) ? 0.f : sacc[i][cb][r];
        int byte = (prow*256 + pcol*2) ^ ((prow&7)<<4);
        *(u16*)((char*)qs + byte) = f2bu(pv);
      }
    }
  }
  stage_tr_bf(bs, vb, 1024, t);
  __syncthreads();
  // num = P @ v ; den = P @ ones
  f32x4 nacc[2][8] = {};
  f32x4 dacc[2] = {};
  bf16x8 bones;
  #pragma unroll
  for(int e=0;e<8;e++) bones[e] = (fr==0) ? (__bf16)1.0f : (__bf16)0.0f;
  #pragma unroll
  for(int js=0;js<4;js++){
    bf16x8 ap[2];
    #pragma unroll
    for(int i=0;i<2;i++) ap[i] = ldfrag(qs, w*32+i*16+fr, js*32+kc*8);
    bf16x8 bv[8];
    #pragma unroll
    for(int cb=0;cb<8;cb++) bv[cb] = ldfrag(bs, cb*16+fr, js*32+kc*8);
    #pragma unroll
    for(int i=0;i<2;i++){
      dacc[i] = __builtin_amdgcn_mfma_f32_16x16x32_bf16(ap[i], bones, dacc[i], 0,0,0);
      #pragma unroll
      for(int cb=0;cb<8;cb++)
        nacc[i][cb] = __builtin_amdgcn_mfma_f32_16x16x32_bf16(ap[i], bv[cb], nacc[i][cb], 0,0,0);
    }
  }
  __syncthreads();
  stage_tr_f32(bs, kvb, 128, t);
  __syncthreads();
  // num += qp @ kv_excl ; den += qp @ ksum_excl
  #pragma unroll
  for(int ms=0;ms<4;ms++){
    bf16x8 bkv[8];
    #pragma unroll
    for(int cb=0;cb<8;cb++) bkv[cb] = ldfrag(bs, cb*16+fr, ms*32+kc*8);
    bf16x8 bks;
    #pragma unroll
    for(int e=0;e<8;e++) bks[e] = (fr==0) ? (__bf16)ksum_s[ms*32+kc*8+e] : (__bf16)0.0f;
    #pragma unroll
    for(int i=0;i<2;i++){
      dacc[i] = __builtin_amdgcn_mfma_f32_16x16x32_bf16(aq[i][ms], bks, dacc[i], 0,0,0);
      #pragma unroll
      for(int cb=0;cb<8;cb++)
        nacc[i][cb] = __builtin_amdgcn_mfma_f32_16x16x32_bf16(aq[i][ms], bkv[cb], nacc[i][cb], 0,0,0);
    }
  }
  #pragma unroll
  for(int i=0;i<2;i++){
    #pragma unroll
    for(int r=0;r<4;r++){
      float den = __shfl(dacc[i][r], lane & 48, 64);
      float inv = 1.0f/(den + 1e-6f);
      int row = w*32 + i*16 + kc*4 + r;
      u16* ob = o + (size_t)((b*Ss+s0+row)*Hh + hh)*128;
      #pragma unroll
      for(int cb=0;cb<8;cb++)
        ob[cb*16 + fr] = f2bu(nacc[i][cb][r] * inv);
    }
  }
}

// ------------- pooling + classifier --------------------------------------
__global__ __launch_bounds__(256) void k_pool(const float* __restrict__ h,
    float* __restrict__ pw){
  __shared__ float part[256];
  int blk = blockIdx.x; int b = blk>>4, c = blk&15;
  int t = threadIdx.x; int half = t>>7;
  float s = 0.f;
  int s0 = c*128 + half*64;
  for(int si=s0; si<s0+64; ++si) s += h[(b*Ss+si)*128 + (t&127)];
  part[t] = s;
  __syncthreads();
  if(t<128) pw[blk*128 + t] = part[t] + part[t+128];
}
__global__ __launch_bounds__(128) void k_cls(const float* __restrict__ pw,
    const float* __restrict__ fw, const float* __restrict__ fb,
    float* __restrict__ out){
  __shared__ float pool_s[128];
  int b = blockIdx.x; int t = threadIdx.x;
  float s = 0.f;
  for(int c=0;c<16;c++) s += pw[(b*16+c)*128 + t];
  pool_s[t] = s * (1.0f/2048.0f);
  __syncthreads();
  if(t<10){
    float a = fb[t];
    for(int d=0; d<128; ++d) a += pool_s[d]*fw[d*10+t];
    out[b*10+t] = a;
  }
}

extern "C" void kernel_launch(void* const* d_in, const int* in_sizes, int n_in,
                              void* d_out, int out_size, void* d_ws, size_t ws_size,
                              hipStream_t stream){
  (void)in_sizes; (void)n_in; (void)out_size; (void)ws_size;
  const float* x     = (const float*)d_in[0];
  const float* lin_w = (const float*)d_in[1];
  const float* lin_b = (const float*)d_in[2];
  const float* pe    = (const float*)d_in[3];
  const float* proj  = (const float*)d_in[4];
  const float* ln1_g = (const float*)d_in[5];
  const float* ln1_b = (const float*)d_in[6];
  const float* wq    = (const float*)d_in[7];
  const float* wk    = (const float*)d_in[8];
  const float* wv    = (const float*)d_in[9];
  const float* wo    = (const float*)d_in[10];
  const float* wo_b  = (const float*)d_in[11];
  const float* ln2_g = (const float*)d_in[12];
  const float* ln2_b = (const float*)d_in[13];
  const float* ff1w  = (const float*)d_in[14];
  const float* ff1b  = (const float*)d_in[15];
  const float* ff2w  = (const float*)d_in[16];
  const float* ff2b  = (const float*)d_in[17];
  const float* finw  = (const float*)d_in[18];
  const float* finb  = (const float*)d_in[19];
  float* out = (float*)d_out;

  // workspace layout (in floats; bf16 buffers use half-float slots)
  float* ws  = (float*)d_ws;
  float* h    = ws;               // fp32 [8192][128]
  u16*  y    = (u16*)(h + 1048576);               // bf16 [8192][128]
  u16*  q    = (u16*)(h + 1048576 + 524288);      // bf16 [8192][1024]
  u16*  k    = q + 8388608;       // bf16 [8192][1024]
  u16*  v    = k + 8388608;       // bf16
  u16*  o    = v + 8388608;       // bf16
  float* ktmp = (float*)(o + 8388608);     // fp32 [65536][128]
  float* kvc  = ktmp + 8388608;   // fp32 [32][16][128][128]
  float* ksc  = kvc + 8388608;    // fp32 [32][16][128]
  float* pw   = ksc + 65536;
  unsigned* kstab = (unsigned*)(pw + 8192);

  k_init<<<1,64,0,stream>>>(kstab);
  k_embed<<<4096,256,0,stream>>>(x, lin_w, lin_b, pe, h);
  for(int l=0;l<2;l++){
    const float* projl = proj + l*Mf*DHc;
    k_ln<<<2048,256,0,stream>>>(h, ln1_g + l*DIMc, ln1_b + l*DIMc, y);
    k_gemm_bf<false,false,false,true><<<dim3(16,128),256,0,stream>>>(y, wq + l*DIMc*INNERc, nullptr, nullptr, q, INNERc, DIMc);
    k_gemm_bf<false,false,false,true><<<dim3(16,128),256,0,stream>>>(y, wk + l*DIMc*INNERc, nullptr, nullptr, k, INNERc, DIMc);
    k_gemm_bf<false,false,false,true><<<dim3(16,128),256,0,stream>>>(y, wv + l*DIMc*INNERc, nullptr, nullptr, v, INNERc, DIMc);
    k_featm<true><<<512,256,0,stream>>>(q, q, nullptr, projl, nullptr);
    k_featm<false><<<512,256,0,stream>>>(k, nullptr, ktmp, projl, kstab + l*32);
    k_kfeatB<<<4096,256,0,stream>>>(ktmp, k, kstab + l*32);
    k_attn1m<<<512,256,0,stream>>>(k, v, kvc, ksc);
    k_prefix<<<2048,256,0,stream>>>(kvc);
    k_prefix_ks<<<16,256,0,stream>>>(ksc);
    k_attn2m<<<512,256,0,stream>>>(q, k, v, kvc, ksc, o);
    k_gemm_bf<true,false,true,false><<<dim3(2,128),256,0,stream>>>(o, wo + l*INNERc*DIMc, wo_b + l*DIMc, h, h, DIMc, INNERc);
    k_ln<<<2048,256,0,stream>>>(h, ln2_g + l*DIMc, ln2_b + l*DIMc, y);
    k_gemm_bf<true,true,false,true><<<dim3(8,128),256,0,stream>>>(y, ff1w + l*DIMc*FFc, ff1b + l*FFc, nullptr, q, FFc, DIMc);
    k_gemm_bf<true,false,true,false><<<dim3(2,128),256,0,stream>>>(q, ff2w + l*FFc*DIMc, ff2b + l*DIMc, h, h, DIMc, FFc);
  }
  k_pool<<<64,256,0,stream>>>(h, pw);
  k_cls<<<4,128,0,stream>>>(pw, finw, finb, out);
}

// Round 8
// 455.904 us; speedup vs baseline: 3.4668x; 1.0697x over previous
//
#include <hip/hip_runtime.h>
#include <hip/hip_bf16.h>

// Problem constants
#define Bb 4
#define Ss 2048
#define DIMc 128
#define Hh 8
#define DHc 128
#define Mf 128
#define CH 128
#define NCc 16         // S / CHUNK
#define INNERc 1024    // H*DH
#define FFc 512

union F4 { float4 v; float f[4]; };
typedef unsigned short u16;

typedef __bf16 bf16x8 __attribute__((ext_vector_type(8)));
typedef float  f32x4  __attribute__((ext_vector_type(4)));

__device__ __forceinline__ unsigned fkey(float f){
  unsigned b = __float_as_uint(f);
  return (b & 0x80000000u) ? ~b : (b | 0x80000000u);
}
__device__ __forceinline__ float funkey(unsigned u){
  unsigned b = (u & 0x80000000u) ? (u & 0x7fffffffu) : ~u;
  return __uint_as_float(b);
}
__device__ __forceinline__ float gelu_f(float x){
  return 0.5f*x*(1.0f + tanhf(0.7978845608028654f*(x + 0.044715f*x*x*x)));
}
// f32 -> bf16 (RNE) raw
__device__ __forceinline__ u16 f2bu(float f){
  unsigned u = __float_as_uint(f);
  return (u16)((u + 0x7fffu + ((u>>16)&1u)) >> 16);
}
__device__ __forceinline__ float b2f(u16 u){
  return __uint_as_float(((unsigned)u)<<16);
}

// ---- swizzled bf16 LDS tile: [128][128] bf16 (32KB), byte = row*256+e*2,
// XOR ((row&7)<<4)  (G4 bank-conflict fix) ----
__device__ __forceinline__ bf16x8 ldfrag(const u16* base, int row, int e){
  int byte = (row*256 + e*2) ^ ((row&7)<<4);
  return *(const bf16x8*)((const char*)base + byte);
}
// stage bf16 row-major [128 x 128] (row stride srs elems) -> swizzled tile
__device__ __forceinline__ void stage_lin_bf(u16* dst, const u16* src, int srs, int t){
  #pragma unroll
  for(int it=0; it<8; ++it){
    int idx = t + it*256; int r = idx>>4, c8 = idx&15;
    int byte = (r*256 + c8*16) ^ ((r&7)<<4);
    *(uint4*)((char*)dst + byte) = *(const uint4*)(src + r*srs + c8*8);
  }
}
// stage bf16 row-major with per-element scale+offset: val*sc + off
// (kp reconstruction: kp = csc*E + ratio*eps — restores reference eps floor)
__device__ __forceinline__ void stage_lin_bf_s(u16* dst, const u16* src, int srs,
    int t, float sc, float off){
  #pragma unroll
  for(int it=0; it<8; ++it){
    int idx = t + it*256; int r = idx>>4, c8 = idx&15;
    u16 tmp[8]; *(uint4*)tmp = *(const uint4*)(src + r*srs + c8*8);
    #pragma unroll
    for(int u=0;u<8;u++) tmp[u] = f2bu(fmaf(b2f(tmp[u]), sc, off));
    int byte = (r*256 + c8*16) ^ ((r&7)<<4);
    *(uint4*)((char*)dst + byte) = *(uint4*)tmp;
  }
}
// stage fp32 row-major [128 x 128] -> bf16 swizzled tile
__device__ __forceinline__ void stage_lin_f32(u16* dst, const float* src, int srs, int t){
  #pragma unroll
  for(int it=0; it<8; ++it){
    int idx = t + it*256; int r = idx>>4, c8 = idx&15;
    F4 v0, v1;
    v0.v = *(const float4*)(src + r*srs + c8*8);
    v1.v = *(const float4*)(src + r*srs + c8*8 + 4);
    u16 tmp[8];
    #pragma unroll
    for(int u=0;u<4;u++){ tmp[u] = f2bu(v0.f[u]); tmp[4+u] = f2bu(v1.f[u]); }
    int byte = (r*256 + c8*16) ^ ((r&7)<<4);
    *(uint4*)((char*)dst + byte) = *(uint4*)tmp;
  }
}
// stage TRANSPOSED from bf16 source: dst[d][j] = src[j][d]
__device__ __forceinline__ void stage_tr_bf(u16* dst, const u16* src, int srs, int t){
  int j0 = (t & 63)*2; int wv = t>>6;
  #pragma unroll
  for(int it=0; it<2; ++it){
    int d0 = wv*16 + it*64;
    u16 a0[16], a1[16];
    *(uint4*)&a0[0] = *(const uint4*)(src + j0*srs + d0);
    *(uint4*)&a0[8] = *(const uint4*)(src + j0*srs + d0 + 8);
    *(uint4*)&a1[0] = *(const uint4*)(src + (j0+1)*srs + d0);
    *(uint4*)&a1[8] = *(const uint4*)(src + (j0+1)*srs + d0 + 8);
    #pragma unroll
    for(int dc=0; dc<16; ++dc){
      int d = d0 + dc;
      unsigned pk = (unsigned)a0[dc] | ((unsigned)a1[dc]<<16);
      int byte = (d*256 + j0*2) ^ ((d&7)<<4);
      *(unsigned*)((char*)dst + byte) = pk;
    }
  }
}
// stage TRANSPOSED from bf16 source with per-element scale+offset
__device__ __forceinline__ void stage_tr_bf_s(u16* dst, const u16* src, int srs,
    int t, float sc, float off){
  int j0 = (t & 63)*2; int wv = t>>6;
  #pragma unroll
  for(int it=0; it<2; ++it){
    int d0 = wv*16 + it*64;
    u16 a0[16], a1[16];
    *(uint4*)&a0[0] = *(const uint4*)(src + j0*srs + d0);
    *(uint4*)&a0[8] = *(const uint4*)(src + j0*srs + d0 + 8);
    *(uint4*)&a1[0] = *(const uint4*)(src + (j0+1)*srs + d0);
    *(uint4*)&a1[8] = *(const uint4*)(src + (j0+1)*srs + d0 + 8);
    #pragma unroll
    for(int dc=0; dc<16; ++dc){
      int d = d0 + dc;
      unsigned pk = (unsigned)f2bu(fmaf(b2f(a0[dc]), sc, off)) |
                    ((unsigned)f2bu(fmaf(b2f(a1[dc]), sc, off))<<16);
      int byte = (d*256 + j0*2) ^ ((d&7)<<4);
      *(unsigned*)((char*)dst + byte) = pk;
    }
  }
}

// bijective XCD-aware tile swizzle: returns (tile_n, tile_m)
__device__ __forceinline__ int2 swz_tile(){
  int nx = gridDim.x;
  int nwg = gridDim.x*gridDim.y;
  int lin = blockIdx.y*nx + blockIdx.x;
  int q = nwg>>3, r = nwg&7;
  int xcd = lin&7, idx = lin>>3;
  int nl = (xcd<r) ? (xcd*(q+1)+idx) : (r*(q+1)+(xcd-r)*q+idx);
  return make_int2(nl % nx, nl / nx);
}

// ---------------- init ----------------
__global__ __launch_bounds__(64) void k_init(unsigned* kstab){
  if(threadIdx.x < 64) kstab[threadIdx.x] = 0u;
}

// ---------------- embedding ----------------
__global__ __launch_bounds__(256) void k_embed(const float* __restrict__ x,
    const float* __restrict__ lw, const float* __restrict__ lb,
    const float* __restrict__ pe, float* __restrict__ h){
  int idx = blockIdx.x*256 + threadIdx.x;
  int d = idx & 127; int bs = idx >> 7; int s = bs & (Ss-1);
  h[idx] = x[bs]*lw[d] + lb[d] + pe[s*DIMc + d];
}

// ---------------- layernorm: fp32 in -> bf16 out ----------------
__global__ __launch_bounds__(256) void k_ln(const float* __restrict__ in,
    const float* __restrict__ g, const float* __restrict__ bta,
    u16* __restrict__ out){
  int wave = threadIdx.x >> 6; int lane = threadIdx.x & 63;
  int row = blockIdx.x*4 + wave;
  const float* r = in + row*DIMc;
  float x1 = r[lane], x2 = r[lane+64];
  float s = x1+x2, sq = x1*x1 + x2*x2;
  #pragma unroll
  for(int m=1;m<64;m<<=1){ s += __shfl_xor(s,m,64); sq += __shfl_xor(sq,m,64); }
  float mu = s * (1.0f/128.0f);
  float var = sq*(1.0f/128.0f) - mu*mu;
  float rs = rsqrtf(var + 1e-5f);
  out[row*DIMc+lane]    = f2bu((x1-mu)*rs*g[lane]+bta[lane]);
  out[row*DIMc+lane+64] = f2bu((x2-mu)*rs*g[lane+64]+bta[lane+64]);
}

// ------------ bf16-A MFMA GEMM: C = [resid +] act(A@B + bias) ------------
template<bool BIAS, bool GELU, bool RES, bool OBF>
__global__ __launch_bounds__(256) void k_gemm_bf(const u16* __restrict__ A,
    const float* __restrict__ Bw, const float* __restrict__ bias,
    const float* __restrict__ resid, void* __restrict__ Cp, int N, int K){
  __shared__ u16 As[64][40];
  __shared__ u16 Bs[64][40];
  int2 tt = swz_tile();
  int n0 = tt.x*64, m0 = tt.y*64;
  int t = threadIdx.x; int wid = t>>6, lane = t&63;
  int wr = wid>>1, wc = wid&1;
  int fr = lane&15, kc = lane>>4;
  f32x4 acc[2][2] = {};
  for(int k0=0; k0<K; k0+=32){
    {
      int r = t>>2, c8 = t&3;
      *(uint4*)&As[r][c8*8] = *(const uint4*)(A + (m0+r)*K + k0 + c8*8);
    }
    {
      int n = t&63, c8 = t>>6;
      u16 tmp[8];
      #pragma unroll
      for(int j=0;j<8;j++) tmp[j] = f2bu(Bw[(k0 + c8*8 + j)*N + n0 + n]);
      *(uint4*)&Bs[n][c8*8] = *(uint4*)tmp;
    }
    __syncthreads();
    bf16x8 af[2], bf[2];
    #pragma unroll
    for(int i=0;i<2;i++) af[i] = *(const bf16x8*)&As[wr*32 + i*16 + fr][kc*8];
    #pragma unroll
    for(int j=0;j<2;j++) bf[j] = *(const bf16x8*)&Bs[wc*32 + j*16 + fr][kc*8];
    #pragma unroll
    for(int i=0;i<2;i++)
      #pragma unroll
      for(int j=0;j<2;j++)
        acc[i][j] = __builtin_amdgcn_mfma_f32_16x16x32_bf16(af[i], bf[j], acc[i][j], 0, 0, 0);
    __syncthreads();
  }
  #pragma unroll
  for(int i=0;i<2;i++){
    #pragma unroll
    for(int r=0;r<4;r++){
      int row = m0 + wr*32 + i*16 + kc*4 + r;
      #pragma unroll
      for(int j=0;j<2;j++){
        int col = n0 + wc*32 + j*16 + fr;
        float val = acc[i][j][r];
        if(BIAS) val += bias[col];
        if(GELU) val = gelu_f(val);
        if(RES)  val += resid[row*N+col];
        if(OBF) ((u16*)Cp)[row*N+col] = f2bu(val);
        else    ((float*)Cp)[row*N+col] = val;
      }
    }
  }
}

// ------------- FAVOR+ features via MFMA ----------------------------------
// view x as [65536][128] bf16 (row = (b*S+s)*H + h). 128 rows/block.
// raw = x @ proj^T (MFMA); dd = norm*raw; diag = 0.5*norm^2*sum(x^2).
// ISQ: out = ratio*(exp(dd - diag - rowmax(dd)) + eps) -> bf16.
// !ISQ: out = E = exp(dd - diag) (bf16); kp is reconstructed downstream as
//       csc*E + ratio*eps (csc = ratio*exp(-stab)); kstab = max(dd) per (b,h).
template<bool ISQ>
__global__ __launch_bounds__(256) void k_featm(
    const u16* xin, u16* qout, const float* __restrict__ proj, unsigned* kstab){
  __shared__ __align__(16) u16 xs[16384];
  __shared__ __align__(16) u16 ps[16384];
  __shared__ float diag_s[128];
  __shared__ unsigned hmax[8];
  int r0 = blockIdx.x*128;
  int t = threadIdx.x; int lane = t&63, w = t>>6;
  int fr = lane&15, kc = lane>>4;
  const float norm  = 0.29730177875068026f;   // 128^-0.25
  const float ratio = 0.08838834764831845f;   // 128^-0.5
  if(!ISQ && t<8) hmax[t] = 0u;
  stage_lin_bf(xs, xin + (size_t)r0*128, 128, t);
  stage_lin_f32(ps, proj, 128, t);
  { // diag: 2 threads per row, 64 elems each
    int r = t>>1, half = t&1;
    const u16* rp = xin + (size_t)(r0+r)*128 + half*64;
    float ss = 0.f;
    #pragma unroll
    for(int u4=0; u4<8; ++u4){
      u16 tmp[8]; *(uint4*)tmp = *(const uint4*)(rp + u4*8);
      #pragma unroll
      for(int u=0;u<8;u++){ float f = b2f(tmp[u]); ss += f*f; }
    }
    ss += __shfl_xor(ss, 1, 64);
    if(half==0) diag_s[r] = 0.5f*norm*norm*ss;
  }
  __syncthreads();
  f32x4 acc[2][8] = {};
  #pragma unroll
  for(int ks=0; ks<4; ++ks){
    bf16x8 a[2];
    #pragma unroll
    for(int i=0;i<2;i++) a[i] = ldfrag(xs, w*32+i*16+fr, ks*32+kc*8);
    bf16x8 bm[8];
    #pragma unroll
    for(int cb=0;cb<8;cb++) bm[cb] = ldfrag(ps, cb*16+fr, ks*32+kc*8);
    #pragma unroll
    for(int i=0;i<2;i++)
      #pragma unroll
      for(int cb=0;cb<8;cb++)
        acc[i][cb] = __builtin_amdgcn_mfma_f32_16x16x32_bf16(a[i], bm[cb], acc[i][cb], 0,0,0);
  }
  __syncthreads();   // all xs/ps reads complete before reuse
  #pragma unroll
  for(int i=0;i<2;i++){
    #pragma unroll
    for(int r=0;r<4;r++){
      int row = w*32 + i*16 + kc*4 + r;
      float dg = diag_s[row];
      float rmax = acc[i][0][r];
      #pragma unroll
      for(int cb=1;cb<8;cb++) rmax = fmaxf(rmax, acc[i][cb][r]);
      #pragma unroll
      for(int msk=1;msk<16;msk<<=1) rmax = fmaxf(rmax, __shfl_xor(rmax, msk, 64));
      if(ISQ){
        float base = -dg - norm*rmax;
        #pragma unroll
        for(int cb=0;cb<8;cb++){
          float val = ratio*(expf(fmaf(norm, acc[i][cb][r], base)) + 1e-4f);
          int byte = (row*256 + (cb*16+fr)*2) ^ ((row&7)<<4);
          *(u16*)((char*)xs + byte) = f2bu(val);
        }
      } else {
        if(fr==0) atomicMax(&hmax[row&7], fkey(norm*rmax));
        #pragma unroll
        for(int cb=0;cb<8;cb++){
          float val = expf(fmaf(norm, acc[i][cb][r], -dg));
          int byte = (row*256 + (cb*16+fr)*2) ^ ((row&7)<<4);
          *(u16*)((char*)xs + byte) = f2bu(val);
        }
      }
    }
  }
  __syncthreads();
  // coalesced copy out of the restaged tile
  #pragma unroll
  for(int it=0; it<8; ++it){
    int idx = t + it*256; int r = idx>>4, c8 = idx&15;
    int byte = (r*256 + c8*16) ^ ((r&7)<<4);
    *(uint4*)(qout + (size_t)(r0+r)*128 + c8*8) = *(uint4*)((char*)xs + byte);
  }
  if(!ISQ){
    int b = r0 >> 14;
    if(t<8) atomicMax(&kstab[b*8 + t], hmax[t]);
  }
}

// ------------- attention phase 1 (MFMA): kv = kp^T v, ksum = sum kp ------
// kp = csc*E + ratio*eps  (reconstructed at staging)
__global__ __launch_bounds__(256) void k_attn1m(const u16* __restrict__ kp,
    const u16* __restrict__ v, u16* __restrict__ kvc, float* __restrict__ ksc,
    const unsigned* __restrict__ kstab){
  __shared__ __align__(16) u16 kt[16384];
  __shared__ __align__(16) u16 vt[16384];
  int bc = blockIdx.x; int c = bc&15, bh = bc>>4, b = bh>>3, hh = bh&7;
  int t = threadIdx.x; int lane = t&63, w = t>>6;
  int fr = lane&15, kc = lane>>4;
  int s0 = c*128;
  const float ratio = 0.08838834764831845f;
  float stab = funkey(kstab[bh]);
  float csc = ratio * expf(-stab);
  float reps = ratio * 1e-4f;
  const u16* kb = kp + (size_t)((b*Ss+s0)*Hh + hh)*128;
  const u16* vb = v  + (size_t)((b*Ss+s0)*Hh + hh)*128;
  stage_tr_bf_s(kt, kb, 1024, t, csc, reps);
  stage_tr_bf(vt, vb, 1024, t);
  __syncthreads();
  f32x4 acc[2][8] = {};
  f32x4 ks[2] = {};
  bf16x8 bones;
  #pragma unroll
  for(int e=0;e<8;e++) bones[e] = (fr==0) ? (__bf16)1.0f : (__bf16)0.0f;
  #pragma unroll
  for(int js=0;js<4;js++){
    bf16x8 am[2];
    #pragma unroll
    for(int i=0;i<2;i++) am[i] = ldfrag(kt, w*32+i*16+fr, js*32+kc*8);
    bf16x8 bv[8];
    #pragma unroll
    for(int cb=0;cb<8;cb++) bv[cb] = ldfrag(vt, cb*16+fr, js*32+kc*8);
    #pragma unroll
    for(int i=0;i<2;i++){
      ks[i] = __builtin_amdgcn_mfma_f32_16x16x32_bf16(am[i], bones, ks[i], 0,0,0);
      #pragma unroll
      for(int cb=0;cb<8;cb++)
        acc[i][cb] = __builtin_amdgcn_mfma_f32_16x16x32_bf16(am[i], bv[cb], acc[i][cb], 0,0,0);
    }
  }
  u16* kvb = kvc + (size_t)bc*16384;
  #pragma unroll
  for(int i=0;i<2;i++){
    #pragma unroll
    for(int r=0;r<4;r++){
      int m = w*32 + i*16 + kc*4 + r;
      #pragma unroll
      for(int cb=0;cb<8;cb++) kvb[m*128 + cb*16 + fr] = f2bu(acc[i][cb][r]);
      if(fr==0) ksc[bc*128 + m] = ks[i][r];
    }
  }
}

// ------------- phase 1.5: exclusive prefix over chunks (bf16, fp32 accum) -
__global__ __launch_bounds__(256) void k_prefix(unsigned* __restrict__ kvc){
  int bh = blockIdx.x >> 5; int pos = (blockIdx.x & 31)*256 + threadIdx.x; // uint idx
  int base = bh*16*8192 + pos;
  float a0 = 0.f, a1 = 0.f;
  #pragma unroll
  for(int c=0;c<16;c++){
    unsigned pk = kvc[base + c*8192];
    float x0 = b2f((u16)pk), x1 = b2f((u16)(pk>>16));
    kvc[base + c*8192] = (unsigned)f2bu(a0) | ((unsigned)f2bu(a1)<<16);
    a0 += x0; a1 += x1;
  }
}
__global__ __launch_bounds__(256) void k_prefix_ks(float* __restrict__ ksc){
  int e = blockIdx.x*256 + threadIdx.x;
  int bh = e>>7, m = e&127;
  float a = 0.f;
  #pragma unroll
  for(int c=0;c<16;c++){
    int idx = (bh*16+c)*128 + m;
    float xv = ksc[idx]; ksc[idx] = a; a += xv;
  }
}

// ------------- attention phase 2 (MFMA): per-chunk output ----------------
__global__ __launch_bounds__(256) void k_attn2m(const u16* __restrict__ qp,
    const u16* __restrict__ kp, const u16* __restrict__ v,
    const u16* __restrict__ kvc, const float* __restrict__ ksc,
    u16* __restrict__ o, const unsigned* __restrict__ kstab){
  __shared__ __align__(16) u16 qs[16384];  // qp -> P
  __shared__ __align__(16) u16 bs[16384];  // kp -> v^T -> kv^T
  __shared__ float ksum_s[128];
  int bc = blockIdx.x; int c = bc&15, bh = bc>>4, b = bh>>3, hh = bh&7;
  int t = threadIdx.x; int lane = t&63, w = t>>6;
  int fr = lane&15, kc = lane>>4;
  int s0 = c*128;
  const float ratio = 0.08838834764831845f;
  float stab = funkey(kstab[bh]);
  float csc = ratio * expf(-stab);
  float reps = ratio * 1e-4f;
  const u16* qb = qp + (size_t)((b*Ss+s0)*Hh + hh)*128;
  const u16* kb = kp + (size_t)((b*Ss+s0)*Hh + hh)*128;
  const u16* vb = v  + (size_t)((b*Ss+s0)*Hh + hh)*128;
  const u16* kvb = kvc + (size_t)bc*16384;
  stage_lin_bf(qs, qb, 1024, t);
  stage_lin_bf_s(bs, kb, 1024, t, csc, reps);
  if(t<128) ksum_s[t] = ksc[bc*128 + t];
  __syncthreads();
  bf16x8 aq[2][4];
  #pragma unroll
  for(int i=0;i<2;i++)
    #pragma unroll
    for(int ks=0;ks<4;ks++)
      aq[i][ks] = ldfrag(qs, w*32+i*16+fr, ks*32+kc*8);
  // S = qp @ kp^T
  f32x4 sacc[2][8] = {};
  #pragma unroll
  for(int ks=0;ks<4;ks++){
    bf16x8 bk[8];
    #pragma unroll
    for(int cb=0;cb<8;cb++) bk[cb] = ldfrag(bs, cb*16+fr, ks*32+kc*8);
    #pragma unroll
    for(int i=0;i<2;i++)
      #pragma unroll
      for(int cb=0;cb<8;cb++)
        sacc[i][cb] = __builtin_amdgcn_mfma_f32_16x16x32_bf16(aq[i][ks], bk[cb], sacc[i][cb], 0,0,0);
  }
  __syncthreads();
  // masked P -> qs (bf16); stage v^T -> bs
  #pragma unroll
  for(int i=0;i<2;i++){
    #pragma unroll
    for(int cb=0;cb<8;cb++){
      #pragma unroll
      for(int r=0;r<4;r++){
        int prow = w*32 + i*16 + kc*4 + r;
        int pcol = cb*16 + fr;
        float pv = (pcol > prow) ? 0.f : sacc[i][cb][r];
        int byte = (prow*256 + pcol*2) ^ ((prow&7)<<4);
        *(u16*)((char*)qs + byte) = f2bu(pv);
      }
    }
  }
  stage_tr_bf(bs, vb, 1024, t);
  __syncthreads();
  // num = P @ v ; den = P @ ones
  f32x4 nacc[2][8] = {};
  f32x4 dacc[2] = {};
  bf16x8 bones;
  #pragma unroll
  for(int e=0;e<8;e++) bones[e] = (fr==0) ? (__bf16)1.0f : (__bf16)0.0f;
  #pragma unroll
  for(int js=0;js<4;js++){
    bf16x8 ap[2];
    #pragma unroll
    for(int i=0;i<2;i++) ap[i] = ldfrag(qs, w*32+i*16+fr, js*32+kc*8);
    bf16x8 bv[8];
    #pragma unroll
    for(int cb=0;cb<8;cb++) bv[cb] = ldfrag(bs, cb*16+fr, js*32+kc*8);
    #pragma unroll
    for(int i=0;i<2;i++){
      dacc[i] = __builtin_amdgcn_mfma_f32_16x16x32_bf16(ap[i], bones, dacc[i], 0,0,0);
      #pragma unroll
      for(int cb=0;cb<8;cb++)
        nacc[i][cb] = __builtin_amdgcn_mfma_f32_16x16x32_bf16(ap[i], bv[cb], nacc[i][cb], 0,0,0);
    }
  }
  __syncthreads();
  stage_tr_bf(bs, kvb, 128, t);
  __syncthreads();
  // num += qp @ kv_excl ; den += qp @ ksum_excl
  #pragma unroll
  for(int ms=0;ms<4;ms++){
    bf16x8 bkv[8];
    #pragma unroll
    for(int cb=0;cb<8;cb++) bkv[cb] = ldfrag(bs, cb*16+fr, ms*32+kc*8);
    bf16x8 bks;
    #pragma unroll
    for(int e=0;e<8;e++) bks[e] = (fr==0) ? (__bf16)ksum_s[ms*32+kc*8+e] : (__bf16)0.0f;
    #pragma unroll
    for(int i=0;i<2;i++){
      dacc[i] = __builtin_amdgcn_mfma_f32_16x16x32_bf16(aq[i][ms], bks, dacc[i], 0,0,0);
      #pragma unroll
      for(int cb=0;cb<8;cb++)
        nacc[i][cb] = __builtin_amdgcn_mfma_f32_16x16x32_bf16(aq[i][ms], bkv[cb], nacc[i][cb], 0,0,0);
    }
  }
  #pragma unroll
  for(int i=0;i<2;i++){
    #pragma unroll
    for(int r=0;r<4;r++){
      float den = __shfl(dacc[i][r], lane & 48, 64);
      float inv = 1.0f/(den + 1e-6f);
      int row = w*32 + i*16 + kc*4 + r;
      u16* ob = o + (size_t)((b*Ss+s0+row)*Hh + hh)*128;
      #pragma unroll
      for(int cb=0;cb<8;cb++)
        ob[cb*16 + fr] = f2bu(nacc[i][cb][r] * inv);
    }
  }
}

// ------------- pooling + classifier --------------------------------------
__global__ __launch_bounds__(256) void k_pool(const float* __restrict__ h,
    float* __restrict__ pw){
  __shared__ float part[256];
  int blk = blockIdx.x; int b = blk>>4, c = blk&15;
  int t = threadIdx.x; int half = t>>7;
  float s = 0.f;
  int s0 = c*128 + half*64;
  for(int si=s0; si<s0+64; ++si) s += h[(b*Ss+si)*128 + (t&127)];
  part[t] = s;
  __syncthreads();
  if(t<128) pw[blk*128 + t] = part[t] + part[t+128];
}
__global__ __launch_bounds__(128) void k_cls(const float* __restrict__ pw,
    const float* __restrict__ fw, const float* __restrict__ fb,
    float* __restrict__ out){
  __shared__ float pool_s[128];
  int b = blockIdx.x; int t = threadIdx.x;
  float s = 0.f;
  for(int c=0;c<16;c++) s += pw[(b*16+c)*128 + t];
  pool_s[t] = s * (1.0f/2048.0f);
  __syncthreads();
  if(t<10){
    float a = fb[t];
    for(int d=0; d<128; ++d) a += pool_s[d]*fw[d*10+t];
    out[b*10+t] = a;
  }
}

extern "C" void kernel_launch(void* const* d_in, const int* in_sizes, int n_in,
                              void* d_out, int out_size, void* d_ws, size_t ws_size,
                              hipStream_t stream){
  (void)in_sizes; (void)n_in; (void)out_size; (void)ws_size;
  const float* x     = (const float*)d_in[0];
  const float* lin_w = (const float*)d_in[1];
  const float* lin_b = (const float*)d_in[2];
  const float* pe    = (const float*)d_in[3];
  const float* proj  = (const float*)d_in[4];
  const float* ln1_g = (const float*)d_in[5];
  const float* ln1_b = (const float*)d_in[6];
  const float* wq    = (const float*)d_in[7];
  const float* wk    = (const float*)d_in[8];
  const float* wv    = (const float*)d_in[9];
  const float* wo    = (const float*)d_in[10];
  const float* wo_b  = (const float*)d_in[11];
  const float* ln2_g = (const float*)d_in[12];
  const float* ln2_b = (const float*)d_in[13];
  const float* ff1w  = (const float*)d_in[14];
  const float* ff1b  = (const float*)d_in[15];
  const float* ff2w  = (const float*)d_in[16];
  const float* ff2b  = (const float*)d_in[17];
  const float* finw  = (const float*)d_in[18];
  const float* finb  = (const float*)d_in[19];
  float* out = (float*)d_out;

  // workspace layout (in floats; bf16 buffers use half-float slots)
  float* ws  = (float*)d_ws;
  float* h    = ws;               // fp32 [8192][128]
  u16*  y    = (u16*)(h + 1048576);               // bf16 [8192][128]
  u16*  q    = (u16*)(h + 1048576 + 524288);      // bf16 [8192][1024]
  u16*  k    = q + 8388608;       // bf16 [8192][1024]
  u16*  v    = k + 8388608;       // bf16
  u16*  o    = v + 8388608;       // bf16
  u16*  kvc  = o + 8388608;       // bf16 [32][16][128][128]
  float* ksc  = (float*)(kvc + 8388608);  // fp32 [32][16][128]
  float* pw   = ksc + 65536;
  unsigned* kstab = (unsigned*)(pw + 8192);

  k_init<<<1,64,0,stream>>>(kstab);
  k_embed<<<4096,256,0,stream>>>(x, lin_w, lin_b, pe, h);
  for(int l=0;l<2;l++){
    const float* projl = proj + l*Mf*DHc;
    k_ln<<<2048,256,0,stream>>>(h, ln1_g + l*DIMc, ln1_b + l*DIMc, y);
    k_gemm_bf<false,false,false,true><<<dim3(16,128),256,0,stream>>>(y, wq + l*DIMc*INNERc, nullptr, nullptr, q, INNERc, DIMc);
    k_gemm_bf<false,false,false,true><<<dim3(16,128),256,0,stream>>>(y, wk + l*DIMc*INNERc, nullptr, nullptr, k, INNERc, DIMc);
    k_gemm_bf<false,false,false,true><<<dim3(16,128),256,0,stream>>>(y, wv + l*DIMc*INNERc, nullptr, nullptr, v, INNERc, DIMc);
    k_featm<true><<<512,256,0,stream>>>(q, q, projl, nullptr);
    k_featm<false><<<512,256,0,stream>>>(k, k, projl, kstab + l*32);
    k_attn1m<<<512,256,0,stream>>>(k, v, kvc, ksc, kstab + l*32);
    k_prefix<<<1024,256,0,stream>>>((unsigned*)kvc);
    k_prefix_ks<<<16,256,0,stream>>>(ksc);
    k_attn2m<<<512,256,0,stream>>>(q, k, v, kvc, ksc, o, kstab + l*32);
    k_gemm_bf<true,false,true,false><<<dim3(2,128),256,0,stream>>>(o, wo + l*INNERc*DIMc, wo_b + l*DIMc, h, h, DIMc, INNERc);
    k_ln<<<2048,256,0,stream>>>(h, ln2_g + l*DIMc, ln2_b + l*DIMc, y);
    k_gemm_bf<true,true,false,true><<<dim3(8,128),256,0,stream>>>(y, ff1w + l*DIMc*FFc, ff1b + l*FFc, nullptr, q, FFc, DIMc);
    k_gemm_bf<true,false,true,false><<<dim3(2,128),256,0,stream>>>(q, ff2w + l*FFc*DIMc, ff2b + l*DIMc, h, h, DIMc, FFc);
  }
  k_pool<<<64,256,0,stream>>>(h, pw);
  k_cls<<<4,128,0,stream>>>(pw, finw, finb, out);
}

// Round 9
// 438.114 us; speedup vs baseline: 3.6076x; 1.0406x over previous
//
#include <hip/hip_runtime.h>
#include <hip/hip_bf16.h>

// Problem constants
#define Bb 4
#define Ss 2048
#define DIMc 128
#define Hh 8
#define DHc 128
#define Mf 128
#define CH 128
#define NCc 16         // S / CHUNK
#define INNERc 1024    // H*DH
#define FFc 512

union F4 { float4 v; float f[4]; };
typedef unsigned short u16;

typedef __bf16 bf16x8 __attribute__((ext_vector_type(8)));
typedef float  f32x4  __attribute__((ext_vector_type(4)));

__device__ __forceinline__ unsigned fkey(float f){
  unsigned b = __float_as_uint(f);
  return (b & 0x80000000u) ? ~b : (b | 0x80000000u);
}
__device__ __forceinline__ float funkey(unsigned u){
  unsigned b = (u & 0x80000000u) ? (u & 0x7fffffffu) : ~u;
  return __uint_as_float(b);
}
__device__ __forceinline__ float gelu_f(float x){
  return 0.5f*x*(1.0f + tanhf(0.7978845608028654f*(x + 0.044715f*x*x*x)));
}
// f32 -> bf16 (RNE) raw
__device__ __forceinline__ u16 f2bu(float f){
  unsigned u = __float_as_uint(f);
  return (u16)((u + 0x7fffu + ((u>>16)&1u)) >> 16);
}
__device__ __forceinline__ float b2f(u16 u){
  return __uint_as_float(((unsigned)u)<<16);
}

// ---- swizzled bf16 LDS tile: [128][128] bf16 (32KB), byte = row*256+e*2,
// XOR ((row&7)<<4)  (G4 bank-conflict fix) ----
__device__ __forceinline__ bf16x8 ldfrag(const u16* base, int row, int e){
  int byte = (row*256 + e*2) ^ ((row&7)<<4);
  return *(const bf16x8*)((const char*)base + byte);
}
// stage bf16 row-major [128 x 128] (row stride srs elems) -> swizzled tile
__device__ __forceinline__ void stage_lin_bf(u16* dst, const u16* src, int srs, int t){
  #pragma unroll
  for(int it=0; it<8; ++it){
    int idx = t + it*256; int r = idx>>4, c8 = idx&15;
    int byte = (r*256 + c8*16) ^ ((r&7)<<4);
    *(uint4*)((char*)dst + byte) = *(const uint4*)(src + r*srs + c8*8);
  }
}
// stage bf16 row-major with per-element scale+offset: val*sc + off
__device__ __forceinline__ void stage_lin_bf_s(u16* dst, const u16* src, int srs,
    int t, float sc, float off){
  #pragma unroll
  for(int it=0; it<8; ++it){
    int idx = t + it*256; int r = idx>>4, c8 = idx&15;
    u16 tmp[8]; *(uint4*)tmp = *(const uint4*)(src + r*srs + c8*8);
    #pragma unroll
    for(int u=0;u<8;u++) tmp[u] = f2bu(fmaf(b2f(tmp[u]), sc, off));
    int byte = (r*256 + c8*16) ^ ((r&7)<<4);
    *(uint4*)((char*)dst + byte) = *(uint4*)tmp;
  }
}
// stage fp32 row-major [128 x 128] -> bf16 swizzled tile
__device__ __forceinline__ void stage_lin_f32(u16* dst, const float* src, int srs, int t){
  #pragma unroll
  for(int it=0; it<8; ++it){
    int idx = t + it*256; int r = idx>>4, c8 = idx&15;
    F4 v0, v1;
    v0.v = *(const float4*)(src + r*srs + c8*8);
    v1.v = *(const float4*)(src + r*srs + c8*8 + 4);
    u16 tmp[8];
    #pragma unroll
    for(int u=0;u<4;u++){ tmp[u] = f2bu(v0.f[u]); tmp[4+u] = f2bu(v1.f[u]); }
    int byte = (r*256 + c8*16) ^ ((r&7)<<4);
    *(uint4*)((char*)dst + byte) = *(uint4*)tmp;
  }
}
// stage TRANSPOSED from bf16 source: dst[d][j] = src[j][d]
__device__ __forceinline__ void stage_tr_bf(u16* dst, const u16* src, int srs, int t){
  int j0 = (t & 63)*2; int wv = t>>6;
  #pragma unroll
  for(int it=0; it<2; ++it){
    int d0 = wv*16 + it*64;
    u16 a0[16], a1[16];
    *(uint4*)&a0[0] = *(const uint4*)(src + j0*srs + d0);
    *(uint4*)&a0[8] = *(const uint4*)(src + j0*srs + d0 + 8);
    *(uint4*)&a1[0] = *(const uint4*)(src + (j0+1)*srs + d0);
    *(uint4*)&a1[8] = *(const uint4*)(src + (j0+1)*srs + d0 + 8);
    #pragma unroll
    for(int dc=0; dc<16; ++dc){
      int d = d0 + dc;
      unsigned pk = (unsigned)a0[dc] | ((unsigned)a1[dc]<<16);
      int byte = (d*256 + j0*2) ^ ((d&7)<<4);
      *(unsigned*)((char*)dst + byte) = pk;
    }
  }
}
// stage TRANSPOSED from bf16 source with per-element scale+offset
__device__ __forceinline__ void stage_tr_bf_s(u16* dst, const u16* src, int srs,
    int t, float sc, float off){
  int j0 = (t & 63)*2; int wv = t>>6;
  #pragma unroll
  for(int it=0; it<2; ++it){
    int d0 = wv*16 + it*64;
    u16 a0[16], a1[16];
    *(uint4*)&a0[0] = *(const uint4*)(src + j0*srs + d0);
    *(uint4*)&a0[8] = *(const uint4*)(src + j0*srs + d0 + 8);
    *(uint4*)&a1[0] = *(const uint4*)(src + (j0+1)*srs + d0);
    *(uint4*)&a1[8] = *(const uint4*)(src + (j0+1)*srs + d0 + 8);
    #pragma unroll
    for(int dc=0; dc<16; ++dc){
      int d = d0 + dc;
      unsigned pk = (unsigned)f2bu(fmaf(b2f(a0[dc]), sc, off)) |
                    ((unsigned)f2bu(fmaf(b2f(a1[dc]), sc, off))<<16);
      int byte = (d*256 + j0*2) ^ ((d&7)<<4);
      *(unsigned*)((char*)dst + byte) = pk;
    }
  }
}

// bijective XCD-aware tile swizzle: returns (tile_n, tile_m)
__device__ __forceinline__ int2 swz_tile(){
  int nx = gridDim.x;
  int nwg = gridDim.x*gridDim.y;
  int lin = blockIdx.y*nx + blockIdx.x;
  int q = nwg>>3, r = nwg&7;
  int xcd = lin&7, idx = lin>>3;
  int nl = (xcd<r) ? (xcd*(q+1)+idx) : (r*(q+1)+(xcd-r)*q+idx);
  return make_int2(nl % nx, nl / nx);
}

// ---------------- init ----------------
__global__ __launch_bounds__(64) void k_init(unsigned* kstab){
  if(threadIdx.x < 64) kstab[threadIdx.x] = 0u;
}

// ---------------- embedding ----------------
__global__ __launch_bounds__(256) void k_embed(const float* __restrict__ x,
    const float* __restrict__ lw, const float* __restrict__ lb,
    const float* __restrict__ pe, float* __restrict__ h){
  int idx = blockIdx.x*256 + threadIdx.x;
  int d = idx & 127; int bs = idx >> 7; int s = bs & (Ss-1);
  h[idx] = x[bs]*lw[d] + lb[d] + pe[s*DIMc + d];
}

// ---------------- layernorm: fp32 in -> bf16 out ----------------
__global__ __launch_bounds__(256) void k_ln(const float* __restrict__ in,
    const float* __restrict__ g, const float* __restrict__ bta,
    u16* __restrict__ out){
  int wave = threadIdx.x >> 6; int lane = threadIdx.x & 63;
  int row = blockIdx.x*4 + wave;
  const float* r = in + row*DIMc;
  float x1 = r[lane], x2 = r[lane+64];
  float s = x1+x2, sq = x1*x1 + x2*x2;
  #pragma unroll
  for(int m=1;m<64;m<<=1){ s += __shfl_xor(s,m,64); sq += __shfl_xor(sq,m,64); }
  float mu = s * (1.0f/128.0f);
  float var = sq*(1.0f/128.0f) - mu*mu;
  float rs = rsqrtf(var + 1e-5f);
  out[row*DIMc+lane]    = f2bu((x1-mu)*rs*g[lane]+bta[lane]);
  out[row*DIMc+lane+64] = f2bu((x2-mu)*rs*g[lane+64]+bta[lane+64]);
}

// ------------ 128x128 K-resident MFMA GEMM (K=128), bf16 A, fp32 W -------
// QKV3: fuse 3 weight matrices (N=1024 each, grid.x = 24); else single
// weight, grid.x = N/128. C output bf16. Optional bias+GELU.
template<bool QKV3, bool BIAS, bool GELU>
__global__ __launch_bounds__(256) void k_gemm128(const u16* __restrict__ A,
    const float* __restrict__ B0, const float* __restrict__ B1,
    const float* __restrict__ B2, const float* __restrict__ bias,
    u16* __restrict__ C0, u16* __restrict__ C1, u16* __restrict__ C2,
    int N){
  __shared__ __align__(16) u16 As[16384];
  __shared__ __align__(16) u16 Bs[16384];
  int2 tt = swz_tile();
  int tn = tt.x, m0 = tt.y*128;
  const float* Bw; u16* C; int n0;
  if(QKV3){
    int tpw = N>>7;
    int widx = tn / tpw; n0 = (tn % tpw)*128;
    Bw = (widx==0) ? B0 : ((widx==1) ? B1 : B2);
    C  = (widx==0) ? C0 : ((widx==1) ? C1 : C2);
  } else { Bw = B0; C = C0; n0 = tn*128; }
  int t = threadIdx.x; int lane = t&63, w = t>>6;
  int fr = lane&15, kc = lane>>4;
  stage_lin_bf(As, A + (size_t)m0*128, 128, t);
  { // stage B [k=128][n0..n0+128) fp32 -> Bs[n][k] swizzled, coalesced on n
    #pragma unroll
    for(int it=0; it<8; ++it){
      int idx = t + it*256; int n = idx&127, c8 = idx>>7;
      u16 tmp[8];
      #pragma unroll
      for(int j=0;j<8;j++) tmp[j] = f2bu(Bw[(c8*8+j)*N + n0 + n]);
      int byte = (n*256 + c8*16) ^ ((n&7)<<4);
      *(uint4*)((char*)Bs + byte) = *(uint4*)tmp;
    }
  }
  __syncthreads();
  f32x4 acc[2][8] = {};
  #pragma unroll
  for(int ks=0; ks<4; ++ks){
    bf16x8 a[2];
    #pragma unroll
    for(int i=0;i<2;i++) a[i] = ldfrag(As, w*32+i*16+fr, ks*32+kc*8);
    bf16x8 bm[8];
    #pragma unroll
    for(int cb=0;cb<8;cb++) bm[cb] = ldfrag(Bs, cb*16+fr, ks*32+kc*8);
    #pragma unroll
    for(int i=0;i<2;i++)
      #pragma unroll
      for(int cb=0;cb<8;cb++)
        acc[i][cb] = __builtin_amdgcn_mfma_f32_16x16x32_bf16(a[i], bm[cb], acc[i][cb], 0,0,0);
  }
  #pragma unroll
  for(int i=0;i<2;i++){
    #pragma unroll
    for(int r=0;r<4;r++){
      int row = m0 + w*32 + i*16 + kc*4 + r;
      #pragma unroll
      for(int cb=0;cb<8;cb++){
        int col = n0 + cb*16 + fr;
        float val = acc[i][cb][r];
        if(BIAS) val += bias[col];
        if(GELU) val = gelu_f(val);
        C[(size_t)row*N + col] = f2bu(val);
      }
    }
  }
}

// ------------ bf16-A MFMA GEMM (64x64 tile, K-loop): fp32 C + resid ------
template<bool BIAS, bool GELU, bool RES, bool OBF>
__global__ __launch_bounds__(256) void k_gemm_bf(const u16* __restrict__ A,
    const float* __restrict__ Bw, const float* __restrict__ bias,
    const float* __restrict__ resid, void* __restrict__ Cp, int N, int K){
  __shared__ u16 As[64][40];
  __shared__ u16 Bs[64][40];
  int2 tt = swz_tile();
  int n0 = tt.x*64, m0 = tt.y*64;
  int t = threadIdx.x; int wid = t>>6, lane = t&63;
  int wr = wid>>1, wc = wid&1;
  int fr = lane&15, kc = lane>>4;
  f32x4 acc[2][2] = {};
  for(int k0=0; k0<K; k0+=32){
    {
      int r = t>>2, c8 = t&3;
      *(uint4*)&As[r][c8*8] = *(const uint4*)(A + (m0+r)*K + k0 + c8*8);
    }
    {
      int n = t&63, c8 = t>>6;
      u16 tmp[8];
      #pragma unroll
      for(int j=0;j<8;j++) tmp[j] = f2bu(Bw[(k0 + c8*8 + j)*N + n0 + n]);
      *(uint4*)&Bs[n][c8*8] = *(uint4*)tmp;
    }
    __syncthreads();
    bf16x8 af[2], bf[2];
    #pragma unroll
    for(int i=0;i<2;i++) af[i] = *(const bf16x8*)&As[wr*32 + i*16 + fr][kc*8];
    #pragma unroll
    for(int j=0;j<2;j++) bf[j] = *(const bf16x8*)&Bs[wc*32 + j*16 + fr][kc*8];
    #pragma unroll
    for(int i=0;i<2;i++)
      #pragma unroll
      for(int j=0;j<2;j++)
        acc[i][j] = __builtin_amdgcn_mfma_f32_16x16x32_bf16(af[i], bf[j], acc[i][j], 0, 0, 0);
    __syncthreads();
  }
  #pragma unroll
  for(int i=0;i<2;i++){
    #pragma unroll
    for(int r=0;r<4;r++){
      int row = m0 + wr*32 + i*16 + kc*4 + r;
      #pragma unroll
      for(int j=0;j<2;j++){
        int col = n0 + wc*32 + j*16 + fr;
        float val = acc[i][j][r];
        if(BIAS) val += bias[col];
        if(GELU) val = gelu_f(val);
        if(RES)  val += resid[row*N+col];
        if(OBF) ((u16*)Cp)[row*N+col] = f2bu(val);
        else    ((float*)Cp)[row*N+col] = val;
      }
    }
  }
}

// ------------- FAVOR+ features via MFMA ----------------------------------
template<bool ISQ>
__global__ __launch_bounds__(256) void k_featm(
    const u16* xin, u16* qout, const float* __restrict__ proj, unsigned* kstab){
  __shared__ __align__(16) u16 xs[16384];
  __shared__ __align__(16) u16 ps[16384];
  __shared__ float diag_s[128];
  __shared__ unsigned hmax[8];
  int r0 = blockIdx.x*128;
  int t = threadIdx.x; int lane = t&63, w = t>>6;
  int fr = lane&15, kc = lane>>4;
  const float norm  = 0.29730177875068026f;   // 128^-0.25
  const float ratio = 0.08838834764831845f;   // 128^-0.5
  if(!ISQ && t<8) hmax[t] = 0u;
  stage_lin_bf(xs, xin + (size_t)r0*128, 128, t);
  stage_lin_f32(ps, proj, 128, t);
  { // diag: 2 threads per row, 64 elems each
    int r = t>>1, half = t&1;
    const u16* rp = xin + (size_t)(r0+r)*128 + half*64;
    float ss = 0.f;
    #pragma unroll
    for(int u4=0; u4<8; ++u4){
      u16 tmp[8]; *(uint4*)tmp = *(const uint4*)(rp + u4*8);
      #pragma unroll
      for(int u=0;u<8;u++){ float f = b2f(tmp[u]); ss += f*f; }
    }
    ss += __shfl_xor(ss, 1, 64);
    if(half==0) diag_s[r] = 0.5f*norm*norm*ss;
  }
  __syncthreads();
  f32x4 acc[2][8] = {};
  #pragma unroll
  for(int ks=0; ks<4; ++ks){
    bf16x8 a[2];
    #pragma unroll
    for(int i=0;i<2;i++) a[i] = ldfrag(xs, w*32+i*16+fr, ks*32+kc*8);
    bf16x8 bm[8];
    #pragma unroll
    for(int cb=0;cb<8;cb++) bm[cb] = ldfrag(ps, cb*16+fr, ks*32+kc*8);
    #pragma unroll
    for(int i=0;i<2;i++)
      #pragma unroll
      for(int cb=0;cb<8;cb++)
        acc[i][cb] = __builtin_amdgcn_mfma_f32_16x16x32_bf16(a[i], bm[cb], acc[i][cb], 0,0,0);
  }
  __syncthreads();   // all xs/ps reads complete before reuse
  #pragma unroll
  for(int i=0;i<2;i++){
    #pragma unroll
    for(int r=0;r<4;r++){
      int row = w*32 + i*16 + kc*4 + r;
      float dg = diag_s[row];
      float rmax = acc[i][0][r];
      #pragma unroll
      for(int cb=1;cb<8;cb++) rmax = fmaxf(rmax, acc[i][cb][r]);
      #pragma unroll
      for(int msk=1;msk<16;msk<<=1) rmax = fmaxf(rmax, __shfl_xor(rmax, msk, 64));
      if(ISQ){
        float base = -dg - norm*rmax;
        #pragma unroll
        for(int cb=0;cb<8;cb++){
          float val = ratio*(expf(fmaf(norm, acc[i][cb][r], base)) + 1e-4f);
          int byte = (row*256 + (cb*16+fr)*2) ^ ((row&7)<<4);
          *(u16*)((char*)xs + byte) = f2bu(val);
        }
      } else {
        if(fr==0) atomicMax(&hmax[row&7], fkey(norm*rmax));
        #pragma unroll
        for(int cb=0;cb<8;cb++){
          float val = expf(fmaf(norm, acc[i][cb][r], -dg));
          int byte = (row*256 + (cb*16+fr)*2) ^ ((row&7)<<4);
          *(u16*)((char*)xs + byte) = f2bu(val);
        }
      }
    }
  }
  __syncthreads();
  // coalesced copy out of the restaged tile
  #pragma unroll
  for(int it=0; it<8; ++it){
    int idx = t + it*256; int r = idx>>4, c8 = idx&15;
    int byte = (r*256 + c8*16) ^ ((r&7)<<4);
    *(uint4*)(qout + (size_t)(r0+r)*128 + c8*8) = *(uint4*)((char*)xs + byte);
  }
  if(!ISQ){
    int b = r0 >> 14;
    if(t<8) atomicMax(&kstab[b*8 + t], hmax[t]);
  }
}

// ------------- attention phase 1 (MFMA): kv = kp^T v, ksum = sum kp ------
// kp = csc*E + ratio*eps  (reconstructed at staging)
__global__ __launch_bounds__(256) void k_attn1m(const u16* __restrict__ kp,
    const u16* __restrict__ v, u16* __restrict__ kvc, float* __restrict__ ksc,
    const unsigned* __restrict__ kstab){
  __shared__ __align__(16) u16 kt[16384];
  __shared__ __align__(16) u16 vt[16384];
  int bc = blockIdx.x; int c = bc&15, bh = bc>>4, b = bh>>3, hh = bh&7;
  int t = threadIdx.x; int lane = t&63, w = t>>6;
  int fr = lane&15, kc = lane>>4;
  int s0 = c*128;
  const float ratio = 0.08838834764831845f;
  float stab = funkey(kstab[bh]);
  float csc = ratio * expf(-stab);
  float reps = ratio * 1e-4f;
  const u16* kb = kp + (size_t)((b*Ss+s0)*Hh + hh)*128;
  const u16* vb = v  + (size_t)((b*Ss+s0)*Hh + hh)*128;
  stage_tr_bf_s(kt, kb, 1024, t, csc, reps);
  stage_tr_bf(vt, vb, 1024, t);
  __syncthreads();
  f32x4 acc[2][8] = {};
  f32x4 ks[2] = {};
  bf16x8 bones;
  #pragma unroll
  for(int e=0;e<8;e++) bones[e] = (fr==0) ? (__bf16)1.0f : (__bf16)0.0f;
  #pragma unroll
  for(int js=0;js<4;js++){
    bf16x8 am[2];
    #pragma unroll
    for(int i=0;i<2;i++) am[i] = ldfrag(kt, w*32+i*16+fr, js*32+kc*8);
    bf16x8 bv[8];
    #pragma unroll
    for(int cb=0;cb<8;cb++) bv[cb] = ldfrag(vt, cb*16+fr, js*32+kc*8);
    #pragma unroll
    for(int i=0;i<2;i++){
      ks[i] = __builtin_amdgcn_mfma_f32_16x16x32_bf16(am[i], bones, ks[i], 0,0,0);
      #pragma unroll
      for(int cb=0;cb<8;cb++)
        acc[i][cb] = __builtin_amdgcn_mfma_f32_16x16x32_bf16(am[i], bv[cb], acc[i][cb], 0,0,0);
    }
  }
  u16* kvb = kvc + (size_t)bc*16384;
  #pragma unroll
  for(int i=0;i<2;i++){
    #pragma unroll
    for(int r=0;r<4;r++){
      int m = w*32 + i*16 + kc*4 + r;
      #pragma unroll
      for(int cb=0;cb<8;cb++) kvb[m*128 + cb*16 + fr] = f2bu(acc[i][cb][r]);
      if(fr==0) ksc[bc*128 + m] = ks[i][r];
    }
  }
}

// --- phase 1.5 fused: blocks 0..1023 scan kvc (bf16 pairs), 1024..1039 ksc
__global__ __launch_bounds__(256) void k_prefix2(unsigned* __restrict__ kvc,
    float* __restrict__ ksc){
  int blk = blockIdx.x;
  if(blk < 1024){
    int bh = blk >> 5; int pos = (blk & 31)*256 + threadIdx.x; // uint idx
    int base = bh*16*8192 + pos;
    float a0 = 0.f, a1 = 0.f;
    #pragma unroll
    for(int c=0;c<16;c++){
      unsigned pk = kvc[base + c*8192];
      float x0 = b2f((u16)pk), x1 = b2f((u16)(pk>>16));
      kvc[base + c*8192] = (unsigned)f2bu(a0) | ((unsigned)f2bu(a1)<<16);
      a0 += x0; a1 += x1;
    }
  } else {
    int e = (blk-1024)*256 + threadIdx.x;
    int bh = e>>7, m = e&127;
    float a = 0.f;
    #pragma unroll
    for(int c=0;c<16;c++){
      int idx = (bh*16+c)*128 + m;
      float xv = ksc[idx]; ksc[idx] = a; a += xv;
    }
  }
}

// ------------- attention phase 2 (MFMA): per-chunk output ----------------
__global__ __launch_bounds__(256) void k_attn2m(const u16* __restrict__ qp,
    const u16* __restrict__ kp, const u16* __restrict__ v,
    const u16* __restrict__ kvc, const float* __restrict__ ksc,
    u16* __restrict__ o, const unsigned* __restrict__ kstab){
  __shared__ __align__(16) u16 qs[16384];  // qp -> P
  __shared__ __align__(16) u16 bs[16384];  // kp -> v^T -> kv^T
  __shared__ float ksum_s[128];
  int bc = blockIdx.x; int c = bc&15, bh = bc>>4, b = bh>>3, hh = bh&7;
  int t = threadIdx.x; int lane = t&63, w = t>>6;
  int fr = lane&15, kc = lane>>4;
  int s0 = c*128;
  const float ratio = 0.08838834764831845f;
  float stab = funkey(kstab[bh]);
  float csc = ratio * expf(-stab);
  float reps = ratio * 1e-4f;
  const u16* qb = qp + (size_t)((b*Ss+s0)*Hh + hh)*128;
  const u16* kb = kp + (size_t)((b*Ss+s0)*Hh + hh)*128;
  const u16* vb = v  + (size_t)((b*Ss+s0)*Hh + hh)*128;
  const u16* kvb = kvc + (size_t)bc*16384;
  stage_lin_bf(qs, qb, 1024, t);
  stage_lin_bf_s(bs, kb, 1024, t, csc, reps);
  if(t<128) ksum_s[t] = ksc[bc*128 + t];
  __syncthreads();
  bf16x8 aq[2][4];
  #pragma unroll
  for(int i=0;i<2;i++)
    #pragma unroll
    for(int ks=0;ks<4;ks++)
      aq[i][ks] = ldfrag(qs, w*32+i*16+fr, ks*32+kc*8);
  // S = qp @ kp^T
  f32x4 sacc[2][8] = {};
  #pragma unroll
  for(int ks=0;ks<4;ks++){
    bf16x8 bk[8];
    #pragma unroll
    for(int cb=0;cb<8;cb++) bk[cb] = ldfrag(bs, cb*16+fr, ks*32+kc*8);
    #pragma unroll
    for(int i=0;i<2;i++)
      #pragma unroll
      for(int cb=0;cb<8;cb++)
        sacc[i][cb] = __builtin_amdgcn_mfma_f32_16x16x32_bf16(aq[i][ks], bk[cb], sacc[i][cb], 0,0,0);
  }
  __syncthreads();
  // masked P -> qs (bf16); stage v^T -> bs
  #pragma unroll
  for(int i=0;i<2;i++){
    #pragma unroll
    for(int cb=0;cb<8;cb++){
      #pragma unroll
      for(int r=0;r<4;r++){
        int prow = w*32 + i*16 + kc*4 + r;
        int pcol = cb*16 + fr;
        float pv = (pcol > prow) ? 0.f : sacc[i][cb][r];
        int byte = (prow*256 + pcol*2) ^ ((prow&7)<<4);
        *(u16*)((char*)qs + byte) = f2bu(pv);
      }
    }
  }
  stage_tr_bf(bs, vb, 1024, t);
  __syncthreads();
  // num = P @ v ; den = P @ ones
  f32x4 nacc[2][8] = {};
  f32x4 dacc[2] = {};
  bf16x8 bones;
  #pragma unroll
  for(int e=0;e<8;e++) bones[e] = (fr==0) ? (__bf16)1.0f : (__bf16)0.0f;
  #pragma unroll
  for(int js=0;js<4;js++){
    bf16x8 ap[2];
    #pragma unroll
    for(int i=0;i<2;i++) ap[i] = ldfrag(qs, w*32+i*16+fr, js*32+kc*8);
    bf16x8 bv[8];
    #pragma unroll
    for(int cb=0;cb<8;cb++) bv[cb] = ldfrag(bs, cb*16+fr, js*32+kc*8);
    #pragma unroll
    for(int i=0;i<2;i++){
      dacc[i] = __builtin_amdgcn_mfma_f32_16x16x32_bf16(ap[i], bones, dacc[i], 0,0,0);
      #pragma unroll
      for(int cb=0;cb<8;cb++)
        nacc[i][cb] = __builtin_amdgcn_mfma_f32_16x16x32_bf16(ap[i], bv[cb], nacc[i][cb], 0,0,0);
    }
  }
  __syncthreads();
  stage_tr_bf(bs, kvb, 128, t);
  __syncthreads();
  // num += qp @ kv_excl ; den += qp @ ksum_excl
  #pragma unroll
  for(int ms=0;ms<4;ms++){
    bf16x8 bkv[8];
    #pragma unroll
    for(int cb=0;cb<8;cb++) bkv[cb] = ldfrag(bs, cb*16+fr, ms*32+kc*8);
    bf16x8 bks;
    #pragma unroll
    for(int e=0;e<8;e++) bks[e] = (fr==0) ? (__bf16)ksum_s[ms*32+kc*8+e] : (__bf16)0.0f;
    #pragma unroll
    for(int i=0;i<2;i++){
      dacc[i] = __builtin_amdgcn_mfma_f32_16x16x32_bf16(aq[i][ms], bks, dacc[i], 0,0,0);
      #pragma unroll
      for(int cb=0;cb<8;cb++)
        nacc[i][cb] = __builtin_amdgcn_mfma_f32_16x16x32_bf16(aq[i][ms], bkv[cb], nacc[i][cb], 0,0,0);
    }
  }
  #pragma unroll
  for(int i=0;i<2;i++){
    #pragma unroll
    for(int r=0;r<4;r++){
      float den = __shfl(dacc[i][r], lane & 48, 64);
      float inv = 1.0f/(den + 1e-6f);
      int row = w*32 + i*16 + kc*4 + r;
      u16* ob = o + (size_t)((b*Ss+s0+row)*Hh + hh)*128;
      #pragma unroll
      for(int cb=0;cb<8;cb++)
        ob[cb*16 + fr] = f2bu(nacc[i][cb][r] * inv);
    }
  }
}

// ------------- pooling + classifier --------------------------------------
__global__ __launch_bounds__(256) void k_pool(const float* __restrict__ h,
    float* __restrict__ pw){
  __shared__ float part[256];
  int blk = blockIdx.x; int b = blk>>4, c = blk&15;
  int t = threadIdx.x; int half = t>>7;
  float s = 0.f;
  int s0 = c*128 + half*64;
  for(int si=s0; si<s0+64; ++si) s += h[(b*Ss+si)*128 + (t&127)];
  part[t] = s;
  __syncthreads();
  if(t<128) pw[blk*128 + t] = part[t] + part[t+128];
}
__global__ __launch_bounds__(128) void k_cls(const float* __restrict__ pw,
    const float* __restrict__ fw, const float* __restrict__ fb,
    float* __restrict__ out){
  __shared__ float pool_s[128];
  int b = blockIdx.x; int t = threadIdx.x;
  float s = 0.f;
  for(int c=0;c<16;c++) s += pw[(b*16+c)*128 + t];
  pool_s[t] = s * (1.0f/2048.0f);
  __syncthreads();
  if(t<10){
    float a = fb[t];
    for(int d=0; d<128; ++d) a += pool_s[d]*fw[d*10+t];
    out[b*10+t] = a;
  }
}

extern "C" void kernel_launch(void* const* d_in, const int* in_sizes, int n_in,
                              void* d_out, int out_size, void* d_ws, size_t ws_size,
                              hipStream_t stream){
  (void)in_sizes; (void)n_in; (void)out_size; (void)ws_size;
  const float* x     = (const float*)d_in[0];
  const float* lin_w = (const float*)d_in[1];
  const float* lin_b = (const float*)d_in[2];
  const float* pe    = (const float*)d_in[3];
  const float* proj  = (const float*)d_in[4];
  const float* ln1_g = (const float*)d_in[5];
  const float* ln1_b = (const float*)d_in[6];
  const float* wq    = (const float*)d_in[7];
  const float* wk    = (const float*)d_in[8];
  const float* wv    = (const float*)d_in[9];
  const float* wo    = (const float*)d_in[10];
  const float* wo_b  = (const float*)d_in[11];
  const float* ln2_g = (const float*)d_in[12];
  const float* ln2_b = (const float*)d_in[13];
  const float* ff1w  = (const float*)d_in[14];
  const float* ff1b  = (const float*)d_in[15];
  const float* ff2w  = (const float*)d_in[16];
  const float* ff2b  = (const float*)d_in[17];
  const float* finw  = (const float*)d_in[18];
  const float* finb  = (const float*)d_in[19];
  float* out = (float*)d_out;

  // workspace layout (in floats; bf16 buffers use half-float slots)
  float* ws  = (float*)d_ws;
  float* h    = ws;               // fp32 [8192][128]
  u16*  y    = (u16*)(h + 1048576);               // bf16 [8192][128]
  u16*  q    = (u16*)(h + 1048576 + 524288);      // bf16 [8192][1024]
  u16*  k    = q + 8388608;       // bf16 [8192][1024]
  u16*  v    = k + 8388608;       // bf16
  u16*  o    = v + 8388608;       // bf16
  u16*  kvc  = o + 8388608;       // bf16 [32][16][128][128]
  float* ksc  = (float*)(kvc + 8388608);  // fp32 [32][16][128]
  float* pw   = ksc + 65536;
  unsigned* kstab = (unsigned*)(pw + 8192);

  k_init<<<1,64,0,stream>>>(kstab);
  k_embed<<<4096,256,0,stream>>>(x, lin_w, lin_b, pe, h);
  for(int l=0;l<2;l++){
    const float* projl = proj + l*Mf*DHc;
    k_ln<<<2048,256,0,stream>>>(h, ln1_g + l*DIMc, ln1_b + l*DIMc, y);
    k_gemm128<true,false,false><<<dim3(24,64),256,0,stream>>>(
        y, wq + l*DIMc*INNERc, wk + l*DIMc*INNERc, wv + l*DIMc*INNERc,
        nullptr, q, k, v, INNERc);
    k_featm<true><<<512,256,0,stream>>>(q, q, projl, nullptr);
    k_featm<false><<<512,256,0,stream>>>(k, k, projl, kstab + l*32);
    k_attn1m<<<512,256,0,stream>>>(k, v, kvc, ksc, kstab + l*32);
    k_prefix2<<<1040,256,0,stream>>>((unsigned*)kvc, ksc);
    k_attn2m<<<512,256,0,stream>>>(q, k, v, kvc, ksc, o, kstab + l*32);
    k_gemm_bf<true,false,true,false><<<dim3(2,128),256,0,stream>>>(o, wo + l*INNERc*DIMc, wo_b + l*DIMc, h, h, DIMc, INNERc);
    k_ln<<<2048,256,0,stream>>>(h, ln2_g + l*DIMc, ln2_b + l*DIMc, y);
    k_gemm128<false,true,true><<<dim3(4,64),256,0,stream>>>(
        y, ff1w + l*DIMc*FFc, nullptr, nullptr, ff1b + l*FFc,
        q, nullptr, nullptr, FFc);
    k_gemm_bf<true,false,true,false><<<dim3(2,128),256,0,stream>>>(q, ff2w + l*FFc*DIMc, ff2b + l*DIMc, h, h, DIMc, FFc);
  }
  k_pool<<<64,256,0,stream>>>(h, pw);
  k_cls<<<4,128,0,stream>>>(pw, finw, finb, out);
}